// Round 10
// baseline (457.194 us; speedup 1.0000x reference)
//
#include <hip/hip_runtime.h>
#include <math.h>

#define N_NODES 20000
#define N_EDGES 320000
#define E_TOT   (N_EDGES + N_NODES)
#define HID     128
#define NEG_SLOPE 0.2f
#define MT64    313   // ceil(20000/64)

typedef __attribute__((ext_vector_type(8))) short short8;
typedef __attribute__((ext_vector_type(4))) float f32x4;

__device__ __forceinline__ unsigned short f2b(float f) {
  unsigned u = __builtin_bit_cast(unsigned, f);
  return (unsigned short)((u + 0x7fffu + ((u >> 16) & 1u)) >> 16);
}
__device__ __forceinline__ float b2f(unsigned short h) {
  unsigned u = ((unsigned)h) << 16;
  return __builtin_bit_cast(float, u);
}
__device__ __forceinline__ unsigned pk2(float a, float b) {
  return (unsigned)f2b(a) | ((unsigned)f2b(b) << 16);
}
__device__ __forceinline__ unsigned addbf2(unsigned a, unsigned b) {
  float lo = b2f((unsigned short)(a & 0xffff)) + b2f((unsigned short)(b & 0xffff));
  float hi = b2f((unsigned short)(a >> 16)) + b2f((unsigned short)(b >> 16));
  return (unsigned)f2b(lo) | ((unsigned)f2b(hi) << 16);
}
__device__ __forceinline__ float lrelu(float x) { return x > 0.f ? x : NEG_SLOPE * x; }

// ---------------- CSR build ----------------
__global__ void k_init_deg(int* __restrict__ deg) {
  int i = blockIdx.x * blockDim.x + threadIdx.x;
  if (i < N_NODES) deg[i] = 1;  // self loop
}

__global__ void k_hist(const int* __restrict__ ei, int* __restrict__ deg) {
  int e = blockIdx.x * blockDim.x + threadIdx.x;
  if (e < N_EDGES) atomicAdd(&deg[ei[N_EDGES + e]], 1);
}

__global__ __launch_bounds__(1024) void k_scan(int* __restrict__ deg,
                                               int* __restrict__ row_ptr) {
  __shared__ int sums[1024];
  int t = threadIdx.x;
  const int CH = 20;
  int begin = t * CH;
  int end = begin + CH; if (end > N_NODES) end = N_NODES;
  int loc = 0;
  for (int i = begin; i < end; ++i) loc += deg[i];
  sums[t] = loc;
  __syncthreads();
  for (int off = 1; off < 1024; off <<= 1) {
    int v = (t >= off) ? sums[t - off] : 0;
    __syncthreads();
    sums[t] += v;
    __syncthreads();
  }
  int run = (t > 0) ? sums[t - 1] : 0;
  for (int i = begin; i < end; ++i) {
    int d = deg[i];
    row_ptr[i] = run;
    run += d;
    deg[i] = 0;      // becomes the scatter cursor
  }
  if (t == 1023) row_ptr[N_NODES] = sums[1023];
}

__global__ void k_scatter(const int* __restrict__ ei, const int* __restrict__ row_ptr,
                          int* __restrict__ cursor, int* __restrict__ edge_src) {
  int t = blockIdx.x * blockDim.x + threadIdx.x;
  if (t < N_EDGES) {
    int s = ei[t], d = ei[N_EDGES + t];
    int pos = row_ptr[d] + atomicAdd(&cursor[d], 1);
    edge_src[pos] = s;
  } else if (t < E_TOT) {
    int i = t - N_EDGES;
    int pos = row_ptr[i] + atomicAdd(&cursor[i], 1);
    edge_src[pos] = i;
  }
}

// ---------------- weight prep: W [K][N] f32 -> Bt [N][K] bf16 (4 jobs) ----------------
struct WtJobs {
  const float* src[8];
  unsigned short* dst[8];
  int K[8], N[8], blk_end[8];
};

__global__ void k_wt_all(WtJobs jb) {
  int b = blockIdx.x;
  int seg = 0;
  while (b >= jb.blk_end[seg]) ++seg;
  int base = seg ? jb.blk_end[seg - 1] : 0;
  int idx = (b - base) * 256 + threadIdx.x;
  int K = jb.K[seg], N = jb.N[seg];
  if (idx < N * K) {
    int n = idx / K, k = idx - n * K;
    jb.dst[seg][idx] = f2b(jb.src[seg][(size_t)k * N + n]);
  }
}

// out-transform weights: W [128][512] -> bt_og[out_ch][h*128+kin] = W[kin][h*128+out_ch]
__global__ void k_wt_og(const float* __restrict__ vgw, const float* __restrict__ tgw,
                        unsigned short* __restrict__ bt_og) {
  int seg = blockIdx.y;               // mod*2 + L
  int mod = seg >> 1, L = seg & 1;
  const float* W = (mod ? tgw : vgw) + (size_t)L * 65536;
  int idx = blockIdx.x * 256 + threadIdx.x;   // 0..65535
  int out_ch = idx >> 9;
  int rem = idx & 511;
  int h = rem >> 7, kin = rem & 127;
  bt_og[(size_t)seg * 65536 + idx] = f2b(W[(size_t)kin * 512 + h * 128 + out_ch]);
}

// attention projection vectors: p[L,mod,sd,h][c] = sum_k W[c][h*128+k] * a[k]
__global__ __launch_bounds__(128) void k_pvec(
    const float* __restrict__ vgw, const float* __restrict__ tgw,
    const float* __restrict__ vgas, const float* __restrict__ vgad,
    const float* __restrict__ tgas, const float* __restrict__ tgad,
    float* __restrict__ pvec) {
  int lmh = blockIdx.x;               // L*8 + mod*4 + h
  int L = lmh >> 3, mod = (lmh >> 2) & 1, h = lmh & 3;
  int sd = blockIdx.y;
  int c = threadIdx.x;
  const float* W = (mod ? tgw : vgw) + (size_t)L * 65536;
  const float* a = (mod ? (sd ? tgad : tgas) : (sd ? vgad : vgas)) + L * 512 + h * 128;
  const float* wr = W + (size_t)c * 512 + h * 128;
  float s = 0.f;
  #pragma unroll 8
  for (int k = 0; k < 128; ++k) s += wr[k] * a[k];
  pvec[(size_t)(((L * 2 + mod) * 2 + sd) * 4 + h) * 128 + c] = s;
}

// ---------------- GEMM core: 64x128 tile, BK=128, 4 waves (2x2) ----------------
// ABF16: A is bf16 (else f32, converted in staging).
// MODE 0: f32 out + bias + relu (Cf).   MODE 3: bf16 out + bias + relu (Cb).
// MODE 2: bf16 in-place: Cb = bf16(elu(0.25*acc + bias)) + Cb_old.
template<int MODE, int ABF16>
__device__ __forceinline__ void gemm_core(
    const void* Aptr, int lda, int c0,
    const unsigned short* __restrict__ Bt,
    const float* __restrict__ bias,
    float* __restrict__ Cf, unsigned short* __restrict__ Cb, int ldc,
    int M, int K, int m0, int n0) {
  __shared__ unsigned short sAB[64 * 128 + 128 * 128];  // As(16KB) | Bs(32KB)
  unsigned short* As = sAB;
  unsigned short* Bs = sAB + 64 * 128;

  int t = threadIdx.x;
  int w = t >> 6, l = t & 63;
  int wr = w >> 1, wc = w & 1;
  int lr = l & 15, lhi = l >> 4;

  int arow = t >> 2, aq = t & 3;      // A: 64 rows x 4 thr/row
  int brow = t >> 1, bhalf = t & 1;   // B: 128 rows x 2 thr/row
  int agr = m0 + arow; if (agr > M - 1) agr = M - 1;
  const float* af32 = (const float*)Aptr + (size_t)agr * lda + c0 + aq * 32;
  const unsigned short* ab16 = (const unsigned short*)Aptr + (size_t)agr * lda + c0 + aq * 32;
  const unsigned short* bptr = Bt + (size_t)(n0 + brow) * K + bhalf * 64;

  f32x4 acc[2][4];
  #pragma unroll
  for (int i = 0; i < 2; ++i)
    #pragma unroll
    for (int j = 0; j < 4; ++j) acc[i][j] = (f32x4){0.f, 0.f, 0.f, 0.f};

  float4 arf[8];
  uint4  arb[4];
  uint4  br[8];
  if (ABF16) {
    #pragma unroll
    for (int p = 0; p < 4; ++p) arb[p] = ((const uint4*)ab16)[p];
  } else {
    #pragma unroll
    for (int p = 0; p < 8; ++p) arf[p] = ((const float4*)af32)[p];
  }
  #pragma unroll
  for (int p = 0; p < 8; ++p) br[p] = ((const uint4*)bptr)[p];

  for (int k0 = 0; k0 < K; k0 += 128) {
    if (ABF16) {
      #pragma unroll
      for (int p = 0; p < 4; ++p) {
        int cb = aq * 4 + p;
        *(uint4*)&As[arow * 128 + ((cb ^ (arow & 15)) << 3)] = arb[p];
      }
    } else {
      #pragma unroll
      for (int p = 0; p < 4; ++p) {
        uint4 w4;
        w4.x = pk2(arf[2 * p].x, arf[2 * p].y);
        w4.y = pk2(arf[2 * p].z, arf[2 * p].w);
        w4.z = pk2(arf[2 * p + 1].x, arf[2 * p + 1].y);
        w4.w = pk2(arf[2 * p + 1].z, arf[2 * p + 1].w);
        int cb = aq * 4 + p;
        *(uint4*)&As[arow * 128 + ((cb ^ (arow & 15)) << 3)] = w4;
      }
    }
    #pragma unroll
    for (int p = 0; p < 8; ++p) {
      int cb = bhalf * 8 + p;
      *(uint4*)&Bs[brow * 128 + ((cb ^ (brow & 15)) << 3)] = br[p];
    }
    __syncthreads();
    if (k0 + 128 < K) {
      if (ABF16) {
        #pragma unroll
        for (int p = 0; p < 4; ++p) arb[p] = ((const uint4*)(ab16 + k0 + 128))[p];
      } else {
        #pragma unroll
        for (int p = 0; p < 8; ++p) arf[p] = ((const float4*)(af32 + k0 + 128))[p];
      }
      #pragma unroll
      for (int p = 0; p < 8; ++p) br[p] = ((const uint4*)(bptr + k0 + 128))[p];
    }
    #pragma unroll
    for (int kk = 0; kk < 4; ++kk) {
      short8 af[2], bfr[4];
      int cbf = lhi + kk * 4;
      #pragma unroll
      for (int i = 0; i < 2; ++i) {
        int row = wr * 32 + i * 16 + lr;
        af[i] = *(const short8*)&As[row * 128 + ((cbf ^ (row & 15)) << 3)];
      }
      #pragma unroll
      for (int j = 0; j < 4; ++j) {
        int nn = wc * 64 + j * 16 + lr;
        bfr[j] = *(const short8*)&Bs[nn * 128 + ((cbf ^ (nn & 15)) << 3)];
      }
      #pragma unroll
      for (int i = 0; i < 2; ++i)
        #pragma unroll
        for (int j = 0; j < 4; ++j)
          acc[i][j] = __builtin_amdgcn_mfma_f32_16x16x32_bf16(af[i], bfr[j], acc[i][j], 0, 0, 0);
    }
    __syncthreads();
  }

  if (MODE == 0) {
    float* Ctf = (float*)sAB;   // [64][128] f32
    #pragma unroll
    for (int i = 0; i < 2; ++i)
      #pragma unroll
      for (int j = 0; j < 4; ++j) {
        int col = wc * 64 + j * 16 + lr;
        float bsv = bias[col];
        #pragma unroll
        for (int rr = 0; rr < 4; ++rr) {
          int row = wr * 32 + i * 16 + lhi * 4 + rr;
          Ctf[row * 128 + col] = fmaxf(acc[i][j][rr] + bsv, 0.f);
        }
      }
    __syncthreads();
    int crow = t >> 2, cq = t & 3;
    int gr = m0 + crow;
    if (gr < M) {
      float4* gdst = (float4*)(Cf + (size_t)gr * ldc + cq * 32);
      const float4* ls = (const float4*)&Ctf[crow * 128 + cq * 32];
      #pragma unroll
      for (int p = 0; p < 8; ++p) gdst[p] = ls[p];
    }
  } else {
    unsigned short* Ct = sAB;   // [64][128] bf16
    #pragma unroll
    for (int i = 0; i < 2; ++i)
      #pragma unroll
      for (int j = 0; j < 4; ++j) {
        int col = wc * 64 + j * 16 + lr;
        float bsv = bias[col];
        #pragma unroll
        for (int rr = 0; rr < 4; ++rr) {
          int row = wr * 32 + i * 16 + lhi * 4 + rr;
          float v;
          if (MODE == 3) {
            v = fmaxf(acc[i][j][rr] + bsv, 0.f);
          } else {   // MODE 2: mean + bias + elu
            v = 0.25f * acc[i][j][rr] + bsv;
            v = v > 0.f ? v : __expf(v) - 1.f;
          }
          Ct[row * 128 + col] = f2b(v);
        }
      }
    __syncthreads();
    int crow = t >> 2, cq = t & 3;
    int gr = m0 + crow;
    if (gr < M) {
      uint4* gdst = (uint4*)(Cb + (size_t)gr * ldc + cq * 32);
      const uint4* ls = (const uint4*)&Ct[crow * 128 + cq * 32];
      if (MODE == 3) {
        #pragma unroll
        for (int p = 0; p < 4; ++p) gdst[p] = ls[p];
      } else {   // MODE 2: residual add in bf16
        #pragma unroll
        for (int p = 0; p < 4; ++p) {
          uint4 cv = ls[p];
          uint4 hv = gdst[p];
          cv.x = addbf2(cv.x, hv.x); cv.y = addbf2(cv.y, hv.y);
          cv.z = addbf2(cv.z, hv.z); cv.w = addbf2(cv.w, hv.w);
          gdst[p] = cv;
        }
      }
    }
  }
}

// projections: y=0 vis (K=768), y=1 txt (K=384) -> hb bf16
__global__ __launch_bounds__(256) void k_proj(
    const float* __restrict__ x,
    const unsigned short* __restrict__ btv, const unsigned short* __restrict__ btt,
    const float* __restrict__ vb, const float* __restrict__ tb,
    unsigned short* __restrict__ hbv, unsigned short* __restrict__ hbt) {
  int m0 = blockIdx.x * 64;
  int c0, K;
  const unsigned short* Bt;
  const float* bias;
  unsigned short* Cb;
  if (blockIdx.y == 0) { c0 = 0;   K = 768; Bt = btv; bias = vb; Cb = hbv; }
  else                 { c0 = 768; K = 384; Bt = btt; bias = tb; Cb = hbt; }
  gemm_core<3, 0>(x, 1152, c0, Bt, bias, nullptr, Cb, 128, N_NODES, K, m0, 0);
}

// attention logits: als/ald[n][h] = hb[n] . pvec[h]
__global__ __launch_bounds__(256) void k_logits(
    const unsigned short* __restrict__ hbv, const unsigned short* __restrict__ hbt,
    const float* __restrict__ pv,   // layer base: pvec + L*2048
    float* __restrict__ alsv, float* __restrict__ aldv,
    float* __restrict__ alst, float* __restrict__ aldt) {
  int b = blockIdx.x;
  int mod = b >= N_NODES;
  int node = b - mod * N_NODES;
  const unsigned short* hrow = (mod ? hbt : hbv) + (size_t)node * 128;
  int w = threadIdx.x >> 6, lane = threadIdx.x & 63;
  float x0 = b2f(hrow[lane]), x1 = b2f(hrow[64 + lane]);
  const float* ps = pv + (size_t)((mod * 2 + 0) * 4 + w) * 128;
  const float* pd = pv + (size_t)((mod * 2 + 1) * 4 + w) * 128;
  float s = x0 * ps[lane] + x1 * ps[64 + lane];
  float d = x0 * pd[lane] + x1 * pd[64 + lane];
  for (int off = 32; off > 0; off >>= 1) {
    s += __shfl_down(s, off);
    d += __shfl_down(d, off);
  }
  if (lane == 0) {
    (mod ? alst : alsv)[node * 4 + w] = s;
    (mod ? aldt : aldv)[node * 4 + w] = d;
  }
}

// ---------------- GAT aggregation: agg[n][h*128+c] = inv_h * sum_e p_e,h * hb[src_e][c] ----------------
struct AggArgs {
  const unsigned short* hb[2];
  const float* als[2];
  const float* ald[2];
  unsigned short* agg[2];
};
__global__ __launch_bounds__(128) void k_agg(AggArgs ag,
                                             const int* __restrict__ row_ptr,
                                             const int* __restrict__ edge_src) {
  int b = blockIdx.x;
  int mod = b >= N_NODES;
  int node = b - mod * N_NODES;
  const unsigned short* __restrict__ hbm = ag.hb[mod];
  const float* __restrict__ als = ag.als[mod];
  const float* __restrict__ ald = ag.ald[mod];
  unsigned short* __restrict__ arow_ = ag.agg[mod] + (size_t)node * 512;

  int tid = threadIdx.x;  // 0..127
  __shared__ float sp[128][4];
  __shared__ int   ssrc[128];
  __shared__ float sredm[8], sreds[8];
  __shared__ float soutC[2][4][128];
  __shared__ float red[4 * 128];  // fallback only
  int begin = row_ptr[node], end = row_ptr[node + 1];
  int deg = end - begin;
  float4 ad4 = *(const float4*)(ald + (size_t)node * 4);
  int wv = tid >> 6;

  if (deg <= 128) {
    float e0 = -1e30f, e1 = -1e30f, e2 = -1e30f, e3 = -1e30f;
    if (tid < deg) {
      int s = edge_src[begin + tid];
      ssrc[tid] = s;
      float4 a4 = *(const float4*)(als + (size_t)s * 4);
      e0 = lrelu(a4.x + ad4.x); e1 = lrelu(a4.y + ad4.y);
      e2 = lrelu(a4.z + ad4.z); e3 = lrelu(a4.w + ad4.w);
    }
    float m0 = e0, m1 = e1, m2 = e2, m3 = e3;
    for (int off = 32; off > 0; off >>= 1) {
      m0 = fmaxf(m0, __shfl_xor(m0, off));
      m1 = fmaxf(m1, __shfl_xor(m1, off));
      m2 = fmaxf(m2, __shfl_xor(m2, off));
      m3 = fmaxf(m3, __shfl_xor(m3, off));
    }
    if ((tid & 63) == 0) {
      sredm[wv * 4 + 0] = m0; sredm[wv * 4 + 1] = m1;
      sredm[wv * 4 + 2] = m2; sredm[wv * 4 + 3] = m3;
    }
    __syncthreads();
    m0 = fmaxf(sredm[0], sredm[4]); m1 = fmaxf(sredm[1], sredm[5]);
    m2 = fmaxf(sredm[2], sredm[6]); m3 = fmaxf(sredm[3], sredm[7]);
    float p0 = 0.f, p1 = 0.f, p2 = 0.f, p3 = 0.f;
    if (tid < deg) {
      p0 = __expf(e0 - m0); p1 = __expf(e1 - m1);
      p2 = __expf(e2 - m2); p3 = __expf(e3 - m3);
    }
    *(float4*)&sp[tid][0] = make_float4(p0, p1, p2, p3);
    float s0 = p0, s1 = p1, s2 = p2, s3 = p3;
    for (int off = 32; off > 0; off >>= 1) {
      s0 += __shfl_xor(s0, off); s1 += __shfl_xor(s1, off);
      s2 += __shfl_xor(s2, off); s3 += __shfl_xor(s3, off);
    }
    if ((tid & 63) == 0) {
      sreds[wv * 4 + 0] = s0; sreds[wv * 4 + 1] = s1;
      sreds[wv * 4 + 2] = s2; sreds[wv * 4 + 3] = s3;
    }
    __syncthreads();
    float inv0 = 1.f / (sreds[0] + sreds[4] + 1e-16f);
    float inv1 = 1.f / (sreds[1] + sreds[5] + 1e-16f);
    float inv2 = 1.f / (sreds[2] + sreds[6] + 1e-16f);
    float inv3 = 1.f / (sreds[3] + sreds[7] + 1e-16f);

    // phase C: wave wv takes alternating edges; lane owns channels (2*lane, 2*lane+1)
    int lane = tid & 63;
    int c2 = lane << 1;
    const unsigned short* hb0 = hbm + c2;
    float a00 = 0.f, a01 = 0.f, a10 = 0.f, a11 = 0.f;
    float a20 = 0.f, a21 = 0.f, a30 = 0.f, a31 = 0.f;
    for (int k = wv; k < deg; k += 2) {
      int s = ssrc[k];
      float4 pk = *(const float4*)&sp[k][0];
      unsigned xv = *(const unsigned*)(hb0 + (size_t)s * 128);
      float x0 = b2f((unsigned short)(xv & 0xffff));
      float x1 = b2f((unsigned short)(xv >> 16));
      a00 += pk.x * x0; a01 += pk.x * x1;
      a10 += pk.y * x0; a11 += pk.y * x1;
      a20 += pk.z * x0; a21 += pk.z * x1;
      a30 += pk.w * x0; a31 += pk.w * x1;
    }
    *(float2*)&soutC[wv][0][c2] = make_float2(a00, a01);
    *(float2*)&soutC[wv][1][c2] = make_float2(a10, a11);
    *(float2*)&soutC[wv][2][c2] = make_float2(a20, a21);
    *(float2*)&soutC[wv][3][c2] = make_float2(a30, a31);
    __syncthreads();
    arow_[0 * 128 + tid] = f2b((soutC[0][0][tid] + soutC[1][0][tid]) * inv0);
    arow_[1 * 128 + tid] = f2b((soutC[0][1][tid] + soutC[1][1][tid]) * inv1);
    arow_[2 * 128 + tid] = f2b((soutC[0][2][tid] + soutC[1][2][tid]) * inv2);
    arow_[3 * 128 + tid] = f2b((soutC[0][3][tid] + soutC[1][3][tid]) * inv3);
    return;
  }

  // generic fallback (deg > 128)
  float lm0 = -1e30f, lm1 = -1e30f, lm2 = -1e30f, lm3 = -1e30f;
  for (int idx = begin + tid; idx < end; idx += 128) {
    int s = edge_src[idx];
    float4 a4 = *(const float4*)(als + (size_t)s * 4);
    lm0 = fmaxf(lm0, lrelu(a4.x + ad4.x));
    lm1 = fmaxf(lm1, lrelu(a4.y + ad4.y));
    lm2 = fmaxf(lm2, lrelu(a4.z + ad4.z));
    lm3 = fmaxf(lm3, lrelu(a4.w + ad4.w));
  }
  red[tid] = lm0; red[128 + tid] = lm1; red[256 + tid] = lm2; red[384 + tid] = lm3;
  __syncthreads();
  for (int off = 64; off > 0; off >>= 1) {
    if (tid < off) {
      red[tid]       = fmaxf(red[tid],       red[tid + off]);
      red[128 + tid] = fmaxf(red[128 + tid], red[128 + tid + off]);
      red[256 + tid] = fmaxf(red[256 + tid], red[256 + tid + off]);
      red[384 + tid] = fmaxf(red[384 + tid], red[384 + tid + off]);
    }
    __syncthreads();
  }
  float m0 = red[0], m1 = red[128], m2 = red[256], m3 = red[384];
  __syncthreads();
  float ls0 = 0.f, ls1 = 0.f, ls2 = 0.f, ls3 = 0.f;
  for (int idx = begin + tid; idx < end; idx += 128) {
    int s = edge_src[idx];
    float4 a4 = *(const float4*)(als + (size_t)s * 4);
    ls0 += __expf(lrelu(a4.x + ad4.x) - m0);
    ls1 += __expf(lrelu(a4.y + ad4.y) - m1);
    ls2 += __expf(lrelu(a4.z + ad4.z) - m2);
    ls3 += __expf(lrelu(a4.w + ad4.w) - m3);
  }
  red[tid] = ls0; red[128 + tid] = ls1; red[256 + tid] = ls2; red[384 + tid] = ls3;
  __syncthreads();
  for (int off = 64; off > 0; off >>= 1) {
    if (tid < off) {
      red[tid]       += red[tid + off];
      red[128 + tid] += red[128 + tid + off];
      red[256 + tid] += red[256 + tid + off];
      red[384 + tid] += red[384 + tid + off];
    }
    __syncthreads();
  }
  float inv0 = 1.f / (red[0]   + 1e-16f);
  float inv1 = 1.f / (red[128] + 1e-16f);
  float inv2 = 1.f / (red[256] + 1e-16f);
  float inv3 = 1.f / (red[384] + 1e-16f);
  float acc0 = 0.f, acc1 = 0.f, acc2 = 0.f, acc3 = 0.f;
  for (int idx = begin; idx < end; ++idx) {
    int s = edge_src[idx];
    float4 a4 = *(const float4*)(als + (size_t)s * 4);
    float al0 = __expf(lrelu(a4.x + ad4.x) - m0) * inv0;
    float al1 = __expf(lrelu(a4.y + ad4.y) - m1) * inv1;
    float al2 = __expf(lrelu(a4.z + ad4.z) - m2) * inv2;
    float al3 = __expf(lrelu(a4.w + ad4.w) - m3) * inv3;
    float xc = b2f(hbm[(size_t)s * 128 + tid]);
    acc0 += al0 * xc; acc1 += al1 * xc; acc2 += al2 * xc; acc3 += al3 * xc;
  }
  arow_[0 * 128 + tid] = f2b(acc0);
  arow_[1 * 128 + tid] = f2b(acc1);
  arow_[2 * 128 + tid] = f2b(acc2);
  arow_[3 * 128 + tid] = f2b(acc3);
}

// out-transform: hb = bf16(elu(agg @ Wstack / 4 + bias)) + hb   (grid.y = mod)
struct OutArgs {
  const unsigned short* agg[2];
  const unsigned short* btg[2];
  const float* bias[2];
  unsigned short* hb[2];
};
__global__ __launch_bounds__(256) void k_out(OutArgs oa) {
  int m0 = blockIdx.x * 64;
  int mod = blockIdx.y;
  gemm_core<2, 1>(oa.agg[mod], 512, 0, oa.btg[mod], oa.bias[mod],
                  nullptr, oa.hb[mod], 128, N_NODES, 512, m0, 0);
}

// merged head GEMMs (A = hb bf16): y=0 vision, y=1 text
__global__ __launch_bounds__(256) void k_head(
    const unsigned short* __restrict__ hbv, const unsigned short* __restrict__ hbt,
    const unsigned short* __restrict__ btvh, const unsigned short* __restrict__ btth,
    const float* __restrict__ vhb, const float* __restrict__ thb,
    float* __restrict__ out) {
  int m0 = blockIdx.x * 64;
  const unsigned short* A;
  const unsigned short* Bt;
  const float* bias;
  float* Cf;
  if (blockIdx.y == 0) { A = hbv; Bt = btvh; bias = vhb; Cf = out + 2560000; }
  else                 { A = hbt; Bt = btth; bias = thb; Cf = out + 5120000; }
  gemm_core<0, 1>(A, 128, 0, Bt, bias, Cf, nullptr, 128, N_NODES, 128, m0, 0);
}

// ---------------- modal gating (bf16 h) ----------------
__global__ __launch_bounds__(128) void k_modal(const unsigned short* __restrict__ hbv,
                                               const unsigned short* __restrict__ hbt,
                                               const float* __restrict__ mw,
                                               const float* __restrict__ mb,
                                               float* __restrict__ out) {
  int node = blockIdx.x, t = threadIdx.x;
  __shared__ float red[128];
  float a = b2f(hbv[(size_t)node * 128 + t]);
  float b = b2f(hbt[(size_t)node * 128 + t]);
  red[t] = a * mw[t] + b * mw[128 + t];
  __syncthreads();
  for (int off = 64; off > 0; off >>= 1) {
    if (t < off) red[t] += red[t + off];
    __syncthreads();
  }
  float beta = 1.f / (1.f + expf(-(red[0] + mb[0])));
  out[(size_t)node * 128 + t] = beta * a + (1.f - beta) * b;
}

extern "C" void kernel_launch(void* const* d_in, const int* in_sizes, int n_in,
                              void* d_out, int out_size, void* d_ws, size_t ws_size,
                              hipStream_t stream) {
  const float* x    = (const float*)d_in[0];
  const int*   ei   = (const int*)d_in[1];
  const float* vpw  = (const float*)d_in[2];
  const float* vpb  = (const float*)d_in[3];
  const float* tpw  = (const float*)d_in[4];
  const float* tpb  = (const float*)d_in[5];
  const float* vgw  = (const float*)d_in[6];
  const float* vgas = (const float*)d_in[7];
  const float* vgad = (const float*)d_in[8];
  const float* vgb  = (const float*)d_in[9];
  const float* tgw  = (const float*)d_in[10];
  const float* tgas = (const float*)d_in[11];
  const float* tgad = (const float*)d_in[12];
  const float* tgb  = (const float*)d_in[13];
  const float* mw   = (const float*)d_in[14];
  const float* mb   = (const float*)d_in[15];
  const float* vhw  = (const float*)d_in[16];
  const float* vhb  = (const float*)d_in[17];
  const float* thw  = (const float*)d_in[18];
  const float* thb  = (const float*)d_in[19];
  float* out = (float*)d_out;

  char* ws = (char*)d_ws;
  unsigned short* hb_v     = (unsigned short*)(ws);                //  5,120,000
  unsigned short* hb_t     = (unsigned short*)(ws + 5120000);      //  5,120,000
  unsigned short* agg_v    = (unsigned short*)(ws + 10240000);     // 20,480,000
  unsigned short* agg_t    = (unsigned short*)(ws + 30720000);     // 20,480,000
  float*          als_v    = (float*)(ws + 51200000);              //    320,000
  float*          ald_v    = (float*)(ws + 51520000);              //    320,000
  float*          als_t    = (float*)(ws + 51840000);              //    320,000
  float*          ald_t    = (float*)(ws + 52160000);              //    320,000
  int*            row_ptr  = (int*)  (ws + 52480000);              //     80,016
  int*            deg      = (int*)  (ws + 52560016);              //     80,000
  int*            edge_src = (int*)  (ws + 52640016);              //  1,360,000
  unsigned short* bt       = (unsigned short*)(ws + 54000016);     //    884,736
  float*          pvec     = (float*)(ws + 54884752);              //     16,384

  unsigned short* bt_vp = bt;            // [128][768]
  unsigned short* bt_tp = bt + 98304;    // [128][384]
  unsigned short* bt_vh = bt + 147456;   // [128][128]
  unsigned short* bt_th = bt + 163840;   // [128][128]
  unsigned short* bt_og = bt + 180224;   // 4 x [128][512] (mod*2+L)

  // weight prep
  WtJobs jb;
  jb.src[0] = vpw; jb.dst[0] = bt_vp; jb.K[0] = 768; jb.N[0] = 128;
  jb.src[1] = tpw; jb.dst[1] = bt_tp; jb.K[1] = 384; jb.N[1] = 128;
  jb.src[2] = vhw; jb.dst[2] = bt_vh; jb.K[2] = 128; jb.N[2] = 128;
  jb.src[3] = thw; jb.dst[3] = bt_th; jb.K[3] = 128; jb.N[3] = 128;
  int accb = 0;
  for (int s = 0; s < 4; ++s) { accb += (jb.K[s] * jb.N[s]) / 256; jb.blk_end[s] = accb; }
  for (int s = 4; s < 8; ++s) { jb.src[s] = vpw; jb.dst[s] = bt_vp; jb.K[s] = 1; jb.N[s] = 1; jb.blk_end[s] = accb; }
  k_wt_all<<<accb, 256, 0, stream>>>(jb);
  k_wt_og<<<dim3(256, 4), 256, 0, stream>>>(vgw, tgw, bt_og);
  k_pvec<<<dim3(16, 2), 128, 0, stream>>>(vgw, tgw, vgas, vgad, tgas, tgad, pvec);

  // CSR build
  k_init_deg<<<(N_NODES + 255) / 256, 256, 0, stream>>>(deg);
  k_hist<<<(N_EDGES + 255) / 256, 256, 0, stream>>>(ei, deg);
  k_scan<<<1, 1024, 0, stream>>>(deg, row_ptr);
  k_scatter<<<(E_TOT + 255) / 256, 256, 0, stream>>>(ei, row_ptr, deg, edge_src);

  // projections -> hb (bf16)
  k_proj<<<dim3(MT64, 2), 256, 0, stream>>>(x, bt_vp, bt_tp, vpb, tpb, hb_v, hb_t);

  // GAT layers
  for (int L = 0; L < 2; ++L) {
    k_logits<<<2 * N_NODES, 256, 0, stream>>>(hb_v, hb_t, pvec + (size_t)L * 2048,
                                              als_v, ald_v, als_t, ald_t);
    AggArgs ag;
    ag.hb[0] = hb_v;   ag.hb[1] = hb_t;
    ag.als[0] = als_v; ag.als[1] = als_t;
    ag.ald[0] = ald_v; ag.ald[1] = ald_t;
    ag.agg[0] = agg_v; ag.agg[1] = agg_t;
    k_agg<<<2 * N_NODES, 128, 0, stream>>>(ag, row_ptr, edge_src);

    OutArgs oa;
    oa.agg[0] = agg_v; oa.agg[1] = agg_t;
    oa.btg[0] = bt_og + (size_t)(0 * 2 + L) * 65536;
    oa.btg[1] = bt_og + (size_t)(1 * 2 + L) * 65536;
    oa.bias[0] = vgb + L * HID;
    oa.bias[1] = tgb + L * HID;
    oa.hb[0] = hb_v;  oa.hb[1] = hb_t;
    k_out<<<dim3(MT64, 2), 256, 0, stream>>>(oa);
  }

  // epilogue
  k_modal<<<N_NODES, 128, 0, stream>>>(hb_v, hb_t, mw, mb, out);
  k_head<<<dim3(MT64, 2), 256, 0, stream>>>(hb_v, hb_t, bt_vh, bt_th, vhb, thb, out);
}

// Round 11
// 423.527 us; speedup vs baseline: 1.0795x; 1.0795x over previous
//
#include <hip/hip_runtime.h>
#include <math.h>

#define N_NODES 20000
#define N_EDGES 320000
#define E_TOT   (N_EDGES + N_NODES)
#define HID     128
#define NEG_SLOPE 0.2f
#define MT64    313   // ceil(20000/64)

typedef __attribute__((ext_vector_type(8))) short short8;
typedef __attribute__((ext_vector_type(4))) float f32x4;

__device__ __forceinline__ unsigned short f2b(float f) {
  unsigned u = __builtin_bit_cast(unsigned, f);
  return (unsigned short)((u + 0x7fffu + ((u >> 16) & 1u)) >> 16);
}
__device__ __forceinline__ float b2f(unsigned short h) {
  unsigned u = ((unsigned)h) << 16;
  return __builtin_bit_cast(float, u);
}
__device__ __forceinline__ unsigned pk2(float a, float b) {
  return (unsigned)f2b(a) | ((unsigned)f2b(b) << 16);
}
__device__ __forceinline__ unsigned addbf2(unsigned a, unsigned b) {
  float lo = b2f((unsigned short)(a & 0xffff)) + b2f((unsigned short)(b & 0xffff));
  float hi = b2f((unsigned short)(a >> 16)) + b2f((unsigned short)(b >> 16));
  return (unsigned)f2b(lo) | ((unsigned)f2b(hi) << 16);
}
__device__ __forceinline__ float lrelu(float x) { return x > 0.f ? x : NEG_SLOPE * x; }

// ---------------- merged prep: weight transposes + out-weights + pvec ----------------
struct PrepArgs {
  const float* vpw; const float* tpw; const float* vhw; const float* thw;
  const float* vgw; const float* tgw;
  const float* vgas; const float* vgad; const float* tgas; const float* tgad;
  unsigned short* bt_vp; unsigned short* bt_tp;
  unsigned short* bt_vh; unsigned short* bt_th;
  unsigned short* bt_og; float* pvec;
};
// blocks [0,704): 4 transpose jobs; [704,1728): og; [1728,1744): pvec
__global__ void k_prep(PrepArgs pa) {
  int b = blockIdx.x, t = threadIdx.x;
  if (b < 704) {
    const float* src; unsigned short* dst; int K, N, base;
    if (b < 384)      { src = pa.vpw; dst = pa.bt_vp; K = 768; N = 128; base = 0; }
    else if (b < 576) { src = pa.tpw; dst = pa.bt_tp; K = 384; N = 128; base = 384; }
    else if (b < 640) { src = pa.vhw; dst = pa.bt_vh; K = 128; N = 128; base = 576; }
    else              { src = pa.thw; dst = pa.bt_th; K = 128; N = 128; base = 640; }
    int idx = (b - base) * 256 + t;
    if (idx < N * K) {
      int n = idx / K, k = idx - n * K;
      dst[idx] = f2b(src[(size_t)k * N + n]);
    }
  } else if (b < 1728) {
    int bo = b - 704;
    int seg = bo >> 8;                  // mod*2 + L
    int mod = seg >> 1, L = seg & 1;
    const float* W = (mod ? pa.tgw : pa.vgw) + (size_t)L * 65536;
    int idx = (bo & 255) * 256 + t;     // 0..65535
    int out_ch = idx >> 9;
    int rem = idx & 511;
    int h = rem >> 7, kin = rem & 127;
    pa.bt_og[(size_t)seg * 65536 + idx] = f2b(W[(size_t)kin * 512 + h * 128 + out_ch]);
  } else {
    int idx = (b - 1728) * 256 + t;     // 0..4095
    int c = idx & 127, sd = (idx >> 7) & 1, lmh = idx >> 8;
    int L = lmh >> 3, mod = (lmh >> 2) & 1, h = lmh & 3;
    const float* W = (mod ? pa.tgw : pa.vgw) + (size_t)L * 65536;
    const float* a = (mod ? (sd ? pa.tgad : pa.tgas) : (sd ? pa.vgad : pa.vgas)) + L * 512 + h * 128;
    const float* wr = W + (size_t)c * 512 + h * 128;
    float s = 0.f;
    #pragma unroll 8
    for (int k = 0; k < 128; ++k) s += wr[k] * a[k];
    pa.pvec[(size_t)(((L * 2 + mod) * 2 + sd) * 4 + h) * 128 + c] = s;
  }
}

// ---------------- CSR build (deg zeroed by memsetAsync; +1 self loop in scan) ----------------
__global__ void k_hist(const int* __restrict__ ei, int* __restrict__ deg) {
  int e = blockIdx.x * blockDim.x + threadIdx.x;
  if (e < N_EDGES) atomicAdd(&deg[ei[N_EDGES + e]], 1);
}

__global__ __launch_bounds__(1024) void k_scan(int* __restrict__ deg,
                                               int* __restrict__ row_ptr) {
  __shared__ int sums[1024];
  int t = threadIdx.x;
  const int CH = 20;
  int begin = t * CH;
  int end = begin + CH; if (end > N_NODES) end = N_NODES;
  int loc = 0;
  for (int i = begin; i < end; ++i) loc += deg[i] + 1;
  sums[t] = loc;
  __syncthreads();
  for (int off = 1; off < 1024; off <<= 1) {
    int v = (t >= off) ? sums[t - off] : 0;
    __syncthreads();
    sums[t] += v;
    __syncthreads();
  }
  int run = (t > 0) ? sums[t - 1] : 0;
  for (int i = begin; i < end; ++i) {
    int d = deg[i] + 1;
    row_ptr[i] = run;
    run += d;
    deg[i] = 0;      // becomes the scatter cursor
  }
  if (t == 1023) row_ptr[N_NODES] = sums[1023];
}

__global__ void k_scatter(const int* __restrict__ ei, const int* __restrict__ row_ptr,
                          int* __restrict__ cursor, int* __restrict__ edge_src) {
  int t = blockIdx.x * blockDim.x + threadIdx.x;
  if (t < N_EDGES) {
    int s = ei[t], d = ei[N_EDGES + t];
    int pos = row_ptr[d] + atomicAdd(&cursor[d], 1);
    edge_src[pos] = s;
  } else if (t < E_TOT) {
    int i = t - N_EDGES;
    int pos = row_ptr[i] + atomicAdd(&cursor[i], 1);
    edge_src[pos] = i;
  }
}

// ---------------- GEMM core: 64x128 tile, BK=128, 4 waves (2x2) ----------------
// ABF16: A bf16 (else f32, converted in staging).
// MODE 0: f32 out + bias + relu (Cf); optional fused modal gate (mw != null).
// MODE 3: bf16 out + bias + relu (Cb); optional fused attn logits (pvg != null).
// MODE 2: bf16 in-place: Cb = bf16(elu(0.25*acc + bias)) + Cb_old; optional logits.
// Epilogue readback is chunk-linear (ci = p*256+t): bank-floor LDS + coalesced global.
template<int MODE, int ABF16>
__device__ __forceinline__ void gemm_core(
    const void* Aptr, int lda, int c0,
    const unsigned short* __restrict__ Bt,
    const float* __restrict__ bias,
    float* __restrict__ Cf, unsigned short* __restrict__ Cb, int ldc,
    int M, int K, int m0, int n0,
    const float* __restrict__ pvg, float* __restrict__ als, float* __restrict__ ald,
    const unsigned short* __restrict__ mhv, const unsigned short* __restrict__ mht,
    const float* __restrict__ mw, const float* __restrict__ mb,
    float* __restrict__ out1) {
  __shared__ unsigned short sAB[64 * 128 + 128 * 128];  // As(16KB) | Bs(32KB)
  unsigned short* As = sAB;
  unsigned short* Bs = sAB + 64 * 128;

  int t = threadIdx.x;
  int w = t >> 6, l = t & 63;
  int wr = w >> 1, wc = w & 1;
  int lr = l & 15, lhi = l >> 4;

  int arow = t >> 2, aq = t & 3;
  int brow = t >> 1, bhalf = t & 1;
  int agr = m0 + arow; if (agr > M - 1) agr = M - 1;
  const float* af32 = (const float*)Aptr + (size_t)agr * lda + c0 + aq * 32;
  const unsigned short* ab16 = (const unsigned short*)Aptr + (size_t)agr * lda + c0 + aq * 32;
  const unsigned short* bptr = Bt + (size_t)(n0 + brow) * K + bhalf * 64;

  f32x4 acc[2][4];
  #pragma unroll
  for (int i = 0; i < 2; ++i)
    #pragma unroll
    for (int j = 0; j < 4; ++j) acc[i][j] = (f32x4){0.f, 0.f, 0.f, 0.f};

  float4 arf[8];
  uint4  arb[4];
  uint4  br[8];
  if (ABF16) {
    #pragma unroll
    for (int p = 0; p < 4; ++p) arb[p] = ((const uint4*)ab16)[p];
  } else {
    #pragma unroll
    for (int p = 0; p < 8; ++p) arf[p] = ((const float4*)af32)[p];
  }
  #pragma unroll
  for (int p = 0; p < 8; ++p) br[p] = ((const uint4*)bptr)[p];

  for (int k0 = 0; k0 < K; k0 += 128) {
    if (ABF16) {
      #pragma unroll
      for (int p = 0; p < 4; ++p) {
        int cb = aq * 4 + p;
        *(uint4*)&As[arow * 128 + ((cb ^ (arow & 15)) << 3)] = arb[p];
      }
    } else {
      #pragma unroll
      for (int p = 0; p < 4; ++p) {
        uint4 w4;
        w4.x = pk2(arf[2 * p].x, arf[2 * p].y);
        w4.y = pk2(arf[2 * p].z, arf[2 * p].w);
        w4.z = pk2(arf[2 * p + 1].x, arf[2 * p + 1].y);
        w4.w = pk2(arf[2 * p + 1].z, arf[2 * p + 1].w);
        int cb = aq * 4 + p;
        *(uint4*)&As[arow * 128 + ((cb ^ (arow & 15)) << 3)] = w4;
      }
    }
    #pragma unroll
    for (int p = 0; p < 8; ++p) {
      int cb = bhalf * 8 + p;
      *(uint4*)&Bs[brow * 128 + ((cb ^ (brow & 15)) << 3)] = br[p];
    }
    __syncthreads();
    if (k0 + 128 < K) {
      if (ABF16) {
        #pragma unroll
        for (int p = 0; p < 4; ++p) arb[p] = ((const uint4*)(ab16 + k0 + 128))[p];
      } else {
        #pragma unroll
        for (int p = 0; p < 8; ++p) arf[p] = ((const float4*)(af32 + k0 + 128))[p];
      }
      #pragma unroll
      for (int p = 0; p < 8; ++p) br[p] = ((const uint4*)(bptr + k0 + 128))[p];
    }
    #pragma unroll
    for (int kk = 0; kk < 4; ++kk) {
      short8 af[2], bfr[4];
      int cbf = lhi + kk * 4;
      #pragma unroll
      for (int i = 0; i < 2; ++i) {
        int row = wr * 32 + i * 16 + lr;
        af[i] = *(const short8*)&As[row * 128 + ((cbf ^ (row & 15)) << 3)];
      }
      #pragma unroll
      for (int j = 0; j < 4; ++j) {
        int nn = wc * 64 + j * 16 + lr;
        bfr[j] = *(const short8*)&Bs[nn * 128 + ((cbf ^ (nn & 15)) << 3)];
      }
      #pragma unroll
      for (int i = 0; i < 2; ++i)
        #pragma unroll
        for (int j = 0; j < 4; ++j)
          acc[i][j] = __builtin_amdgcn_mfma_f32_16x16x32_bf16(af[i], bfr[j], acc[i][j], 0, 0, 0);
    }
    __syncthreads();
  }

  if (MODE == 0) {
    float* Ctf = (float*)sAB;   // [64][128] f32
    #pragma unroll
    for (int i = 0; i < 2; ++i)
      #pragma unroll
      for (int j = 0; j < 4; ++j) {
        int col = wc * 64 + j * 16 + lr;
        float bsv = bias[col];
        #pragma unroll
        for (int rr = 0; rr < 4; ++rr) {
          int row = wr * 32 + i * 16 + lhi * 4 + rr;
          Ctf[row * 128 + col] = fmaxf(acc[i][j][rr] + bsv, 0.f);
        }
      }
    __syncthreads();
    float mb0 = mw ? mb[0] : 0.f;
    #pragma unroll
    for (int p = 0; p < 8; ++p) {
      int ci = (p << 8) + t;
      int row = ci >> 5, ch = ci & 31;
      int gr = m0 + row;
      int cg = gr < M ? gr : M - 1;
      float4 v = *(const float4*)&Ctf[row * 128 + (ch << 2)];
      if (gr < M) ((float4*)(Cf + (size_t)gr * ldc))[ch] = v;
      if (mw) {
        uint2 a2 = *(const uint2*)&mhv[(size_t)cg * 128 + (ch << 2)];
        uint2 b2 = *(const uint2*)&mht[(size_t)cg * 128 + (ch << 2)];
        float4 wv = ((const float4*)mw)[ch];
        float4 wt = ((const float4*)(mw + 128))[ch];
        float a0 = b2f((unsigned short)(a2.x & 0xffff)), a1 = b2f((unsigned short)(a2.x >> 16));
        float a2f = b2f((unsigned short)(a2.y & 0xffff)), a3 = b2f((unsigned short)(a2.y >> 16));
        float b0 = b2f((unsigned short)(b2.x & 0xffff)), b1 = b2f((unsigned short)(b2.x >> 16));
        float b2v = b2f((unsigned short)(b2.y & 0xffff)), b3 = b2f((unsigned short)(b2.y >> 16));
        float ps = a0 * wv.x + a1 * wv.y + a2f * wv.z + a3 * wv.w
                 + b0 * wt.x + b1 * wt.y + b2v * wt.z + b3 * wt.w;
        #pragma unroll
        for (int off = 1; off < 32; off <<= 1) ps += __shfl_xor(ps, off);
        float beta = 1.f / (1.f + __expf(-(ps + mb0)));
        float4 o;
        o.x = beta * a0 + (1.f - beta) * b0;
        o.y = beta * a1 + (1.f - beta) * b1;
        o.z = beta * a2f + (1.f - beta) * b2v;
        o.w = beta * a3 + (1.f - beta) * b3;
        if (gr < M) ((float4*)(out1 + (size_t)gr * 128))[ch] = o;
      }
    }
  } else {
    unsigned short* Ct = sAB;   // [64][128] bf16 (16 KB)
    float* pvL = (float*)(sAB + 8192);  // 4 KB, dead Bs region
    #pragma unroll
    for (int i = 0; i < 2; ++i)
      #pragma unroll
      for (int j = 0; j < 4; ++j) {
        int col = wc * 64 + j * 16 + lr;
        float bsv = bias[col];
        #pragma unroll
        for (int rr = 0; rr < 4; ++rr) {
          int row = wr * 32 + i * 16 + lhi * 4 + rr;
          float v;
          if (MODE == 3) {
            v = fmaxf(acc[i][j][rr] + bsv, 0.f);
          } else {
            v = 0.25f * acc[i][j][rr] + bsv;
            v = v > 0.f ? v : __expf(v) - 1.f;
          }
          Ct[row * 128 + col] = f2b(v);
        }
      }
    __syncthreads();
    if (pvg) ((float4*)pvL)[t] = ((const float4*)pvg)[t];   // 1024 floats
    __syncthreads();
    #pragma unroll
    for (int p = 0; p < 4; ++p) {
      int ci = (p << 8) + t;
      int row = ci >> 4, ch = ci & 15;
      int gr = m0 + row;
      int cg = gr < M ? gr : M - 1;
      uint4 cv = *(const uint4*)&Ct[row * 128 + (ch << 3)];
      uint4* gptr = (uint4*)(Cb + (size_t)cg * ldc) + ch;
      if (MODE == 2) {
        uint4 hv = *gptr;
        cv.x = addbf2(cv.x, hv.x); cv.y = addbf2(cv.y, hv.y);
        cv.z = addbf2(cv.z, hv.z); cv.w = addbf2(cv.w, hv.w);
      }
      if (gr < M) *gptr = cv;
      if (pvg) {
        float v0 = b2f((unsigned short)(cv.x & 0xffff)), v1 = b2f((unsigned short)(cv.x >> 16));
        float v2 = b2f((unsigned short)(cv.y & 0xffff)), v3 = b2f((unsigned short)(cv.y >> 16));
        float v4 = b2f((unsigned short)(cv.z & 0xffff)), v5 = b2f((unsigned short)(cv.z >> 16));
        float v6 = b2f((unsigned short)(cv.w & 0xffff)), v7 = b2f((unsigned short)(cv.w >> 16));
        float s0, s1, s2, s3, s4, s5, s6, s7;
        {
          const float4* pr;
          pr = (const float4*)&pvL[0 * 128 + (ch << 3)];
          s0 = v0*pr[0].x + v1*pr[0].y + v2*pr[0].z + v3*pr[0].w + v4*pr[1].x + v5*pr[1].y + v6*pr[1].z + v7*pr[1].w;
          pr = (const float4*)&pvL[1 * 128 + (ch << 3)];
          s1 = v0*pr[0].x + v1*pr[0].y + v2*pr[0].z + v3*pr[0].w + v4*pr[1].x + v5*pr[1].y + v6*pr[1].z + v7*pr[1].w;
          pr = (const float4*)&pvL[2 * 128 + (ch << 3)];
          s2 = v0*pr[0].x + v1*pr[0].y + v2*pr[0].z + v3*pr[0].w + v4*pr[1].x + v5*pr[1].y + v6*pr[1].z + v7*pr[1].w;
          pr = (const float4*)&pvL[3 * 128 + (ch << 3)];
          s3 = v0*pr[0].x + v1*pr[0].y + v2*pr[0].z + v3*pr[0].w + v4*pr[1].x + v5*pr[1].y + v6*pr[1].z + v7*pr[1].w;
          pr = (const float4*)&pvL[4 * 128 + (ch << 3)];
          s4 = v0*pr[0].x + v1*pr[0].y + v2*pr[0].z + v3*pr[0].w + v4*pr[1].x + v5*pr[1].y + v6*pr[1].z + v7*pr[1].w;
          pr = (const float4*)&pvL[5 * 128 + (ch << 3)];
          s5 = v0*pr[0].x + v1*pr[0].y + v2*pr[0].z + v3*pr[0].w + v4*pr[1].x + v5*pr[1].y + v6*pr[1].z + v7*pr[1].w;
          pr = (const float4*)&pvL[6 * 128 + (ch << 3)];
          s6 = v0*pr[0].x + v1*pr[0].y + v2*pr[0].z + v3*pr[0].w + v4*pr[1].x + v5*pr[1].y + v6*pr[1].z + v7*pr[1].w;
          pr = (const float4*)&pvL[7 * 128 + (ch << 3)];
          s7 = v0*pr[0].x + v1*pr[0].y + v2*pr[0].z + v3*pr[0].w + v4*pr[1].x + v5*pr[1].y + v6*pr[1].z + v7*pr[1].w;
        }
        #pragma unroll
        for (int off = 1; off < 16; off <<= 1) {
          s0 += __shfl_xor(s0, off); s1 += __shfl_xor(s1, off);
          s2 += __shfl_xor(s2, off); s3 += __shfl_xor(s3, off);
          s4 += __shfl_xor(s4, off); s5 += __shfl_xor(s5, off);
          s6 += __shfl_xor(s6, off); s7 += __shfl_xor(s7, off);
        }
        if ((t & 15) == 0 && gr < M) {
          als[gr * 4 + 0] = s0; als[gr * 4 + 1] = s1;
          als[gr * 4 + 2] = s2; als[gr * 4 + 3] = s3;
          ald[gr * 4 + 0] = s4; ald[gr * 4 + 1] = s5;
          ald[gr * 4 + 2] = s6; ald[gr * 4 + 3] = s7;
        }
      }
    }
  }
}

// projections + fused L0 logits: y = modality
__global__ __launch_bounds__(256) void k_proj(
    const float* __restrict__ x,
    const unsigned short* __restrict__ btv, const unsigned short* __restrict__ btt,
    const float* __restrict__ vb, const float* __restrict__ tb,
    unsigned short* __restrict__ hbv, unsigned short* __restrict__ hbt,
    const float* __restrict__ pvec,
    float* __restrict__ alsv, float* __restrict__ aldv,
    float* __restrict__ alst, float* __restrict__ aldt) {
  int m0 = blockIdx.x * 64;
  int mod = blockIdx.y;
  int c0, K;
  const unsigned short* Bt;
  const float* bias;
  unsigned short* Cb;
  if (mod == 0) { c0 = 0;   K = 768; Bt = btv; bias = vb; Cb = hbv; }
  else          { c0 = 768; K = 384; Bt = btt; bias = tb; Cb = hbt; }
  gemm_core<3, 0>(x, 1152, c0, Bt, bias, nullptr, Cb, 128, N_NODES, K, m0, 0,
                  pvec + (size_t)mod * 1024,
                  mod ? alst : alsv, mod ? aldt : aldv,
                  nullptr, nullptr, nullptr, nullptr, nullptr);
}

// ---------------- GAT aggregation ----------------
struct AggArgs {
  const unsigned short* hb[2];
  const float* als[2];
  const float* ald[2];
  unsigned short* agg[2];
};
__global__ __launch_bounds__(128) void k_agg(AggArgs ag,
                                             const int* __restrict__ row_ptr,
                                             const int* __restrict__ edge_src) {
  int b = blockIdx.x;
  int mod = b >= N_NODES;
  int node = b - mod * N_NODES;
  const unsigned short* __restrict__ hbm = ag.hb[mod];
  const float* __restrict__ als = ag.als[mod];
  const float* __restrict__ ald = ag.ald[mod];
  unsigned short* __restrict__ arow_ = ag.agg[mod] + (size_t)node * 512;

  int tid = threadIdx.x;
  __shared__ float sp[128][4];
  __shared__ int   ssrc[128];
  __shared__ float sredm[8], sreds[8];
  __shared__ float soutC[2][4][128];
  __shared__ float red[4 * 128];
  int begin = row_ptr[node], end = row_ptr[node + 1];
  int deg = end - begin;
  float4 ad4 = *(const float4*)(ald + (size_t)node * 4);
  int wv = tid >> 6;

  if (deg <= 128) {
    float e0 = -1e30f, e1 = -1e30f, e2 = -1e30f, e3 = -1e30f;
    if (tid < deg) {
      int s = edge_src[begin + tid];
      ssrc[tid] = s;
      float4 a4 = *(const float4*)(als + (size_t)s * 4);
      e0 = lrelu(a4.x + ad4.x); e1 = lrelu(a4.y + ad4.y);
      e2 = lrelu(a4.z + ad4.z); e3 = lrelu(a4.w + ad4.w);
    }
    float m0 = e0, m1 = e1, m2 = e2, m3 = e3;
    for (int off = 32; off > 0; off >>= 1) {
      m0 = fmaxf(m0, __shfl_xor(m0, off));
      m1 = fmaxf(m1, __shfl_xor(m1, off));
      m2 = fmaxf(m2, __shfl_xor(m2, off));
      m3 = fmaxf(m3, __shfl_xor(m3, off));
    }
    if ((tid & 63) == 0) {
      sredm[wv * 4 + 0] = m0; sredm[wv * 4 + 1] = m1;
      sredm[wv * 4 + 2] = m2; sredm[wv * 4 + 3] = m3;
    }
    __syncthreads();
    m0 = fmaxf(sredm[0], sredm[4]); m1 = fmaxf(sredm[1], sredm[5]);
    m2 = fmaxf(sredm[2], sredm[6]); m3 = fmaxf(sredm[3], sredm[7]);
    float p0 = 0.f, p1 = 0.f, p2 = 0.f, p3 = 0.f;
    if (tid < deg) {
      p0 = __expf(e0 - m0); p1 = __expf(e1 - m1);
      p2 = __expf(e2 - m2); p3 = __expf(e3 - m3);
    }
    *(float4*)&sp[tid][0] = make_float4(p0, p1, p2, p3);
    float s0 = p0, s1 = p1, s2 = p2, s3 = p3;
    for (int off = 32; off > 0; off >>= 1) {
      s0 += __shfl_xor(s0, off); s1 += __shfl_xor(s1, off);
      s2 += __shfl_xor(s2, off); s3 += __shfl_xor(s3, off);
    }
    if ((tid & 63) == 0) {
      sreds[wv * 4 + 0] = s0; sreds[wv * 4 + 1] = s1;
      sreds[wv * 4 + 2] = s2; sreds[wv * 4 + 3] = s3;
    }
    __syncthreads();
    float inv0 = 1.f / (sreds[0] + sreds[4] + 1e-16f);
    float inv1 = 1.f / (sreds[1] + sreds[5] + 1e-16f);
    float inv2 = 1.f / (sreds[2] + sreds[6] + 1e-16f);
    float inv3 = 1.f / (sreds[3] + sreds[7] + 1e-16f);

    int lane = tid & 63;
    int c2 = lane << 1;
    const unsigned short* hb0 = hbm + c2;
    float a00 = 0.f, a01 = 0.f, a10 = 0.f, a11 = 0.f;
    float a20 = 0.f, a21 = 0.f, a30 = 0.f, a31 = 0.f;
    for (int k = wv; k < deg; k += 2) {
      int s = ssrc[k];
      float4 pk = *(const float4*)&sp[k][0];
      unsigned xv = *(const unsigned*)(hb0 + (size_t)s * 128);
      float x0 = b2f((unsigned short)(xv & 0xffff));
      float x1 = b2f((unsigned short)(xv >> 16));
      a00 += pk.x * x0; a01 += pk.x * x1;
      a10 += pk.y * x0; a11 += pk.y * x1;
      a20 += pk.z * x0; a21 += pk.z * x1;
      a30 += pk.w * x0; a31 += pk.w * x1;
    }
    *(float2*)&soutC[wv][0][c2] = make_float2(a00, a01);
    *(float2*)&soutC[wv][1][c2] = make_float2(a10, a11);
    *(float2*)&soutC[wv][2][c2] = make_float2(a20, a21);
    *(float2*)&soutC[wv][3][c2] = make_float2(a30, a31);
    __syncthreads();
    arow_[0 * 128 + tid] = f2b((soutC[0][0][tid] + soutC[1][0][tid]) * inv0);
    arow_[1 * 128 + tid] = f2b((soutC[0][1][tid] + soutC[1][1][tid]) * inv1);
    arow_[2 * 128 + tid] = f2b((soutC[0][2][tid] + soutC[1][2][tid]) * inv2);
    arow_[3 * 128 + tid] = f2b((soutC[0][3][tid] + soutC[1][3][tid]) * inv3);
    return;
  }

  // generic fallback (deg > 128)
  float lm0 = -1e30f, lm1 = -1e30f, lm2 = -1e30f, lm3 = -1e30f;
  for (int idx = begin + tid; idx < end; idx += 128) {
    int s = edge_src[idx];
    float4 a4 = *(const float4*)(als + (size_t)s * 4);
    lm0 = fmaxf(lm0, lrelu(a4.x + ad4.x));
    lm1 = fmaxf(lm1, lrelu(a4.y + ad4.y));
    lm2 = fmaxf(lm2, lrelu(a4.z + ad4.z));
    lm3 = fmaxf(lm3, lrelu(a4.w + ad4.w));
  }
  red[tid] = lm0; red[128 + tid] = lm1; red[256 + tid] = lm2; red[384 + tid] = lm3;
  __syncthreads();
  for (int off = 64; off > 0; off >>= 1) {
    if (tid < off) {
      red[tid]       = fmaxf(red[tid],       red[tid + off]);
      red[128 + tid] = fmaxf(red[128 + tid], red[128 + tid + off]);
      red[256 + tid] = fmaxf(red[256 + tid], red[256 + tid + off]);
      red[384 + tid] = fmaxf(red[384 + tid], red[384 + tid + off]);
    }
    __syncthreads();
  }
  float m0 = red[0], m1 = red[128], m2 = red[256], m3 = red[384];
  __syncthreads();
  float ls0 = 0.f, ls1 = 0.f, ls2 = 0.f, ls3 = 0.f;
  for (int idx = begin + tid; idx < end; idx += 128) {
    int s = edge_src[idx];
    float4 a4 = *(const float4*)(als + (size_t)s * 4);
    ls0 += __expf(lrelu(a4.x + ad4.x) - m0);
    ls1 += __expf(lrelu(a4.y + ad4.y) - m1);
    ls2 += __expf(lrelu(a4.z + ad4.z) - m2);
    ls3 += __expf(lrelu(a4.w + ad4.w) - m3);
  }
  red[tid] = ls0; red[128 + tid] = ls1; red[256 + tid] = ls2; red[384 + tid] = ls3;
  __syncthreads();
  for (int off = 64; off > 0; off >>= 1) {
    if (tid < off) {
      red[tid]       += red[tid + off];
      red[128 + tid] += red[128 + tid + off];
      red[256 + tid] += red[256 + tid + off];
      red[384 + tid] += red[384 + tid + off];
    }
    __syncthreads();
  }
  float inv0 = 1.f / (red[0]   + 1e-16f);
  float inv1 = 1.f / (red[128] + 1e-16f);
  float inv2 = 1.f / (red[256] + 1e-16f);
  float inv3 = 1.f / (red[384] + 1e-16f);
  float acc0 = 0.f, acc1 = 0.f, acc2 = 0.f, acc3 = 0.f;
  for (int idx = begin; idx < end; ++idx) {
    int s = edge_src[idx];
    float4 a4 = *(const float4*)(als + (size_t)s * 4);
    float al0 = __expf(lrelu(a4.x + ad4.x) - m0) * inv0;
    float al1 = __expf(lrelu(a4.y + ad4.y) - m1) * inv1;
    float al2 = __expf(lrelu(a4.z + ad4.z) - m2) * inv2;
    float al3 = __expf(lrelu(a4.w + ad4.w) - m3) * inv3;
    float xc = b2f(hbm[(size_t)s * 128 + tid]);
    acc0 += al0 * xc; acc1 += al1 * xc; acc2 += al2 * xc; acc3 += al3 * xc;
  }
  arow_[0 * 128 + tid] = f2b(acc0);
  arow_[1 * 128 + tid] = f2b(acc1);
  arow_[2 * 128 + tid] = f2b(acc2);
  arow_[3 * 128 + tid] = f2b(acc3);
}

// out-transform + residual + optional fused next-layer logits
struct OutArgs {
  const unsigned short* agg[2];
  const unsigned short* btg[2];
  const float* bias[2];
  unsigned short* hb[2];
  const float* pv[2];   // next layer pvec base (or null)
  float* als[2];
  float* ald[2];
};
__global__ __launch_bounds__(256) void k_out(OutArgs oa) {
  int m0 = blockIdx.x * 64;
  int mod = blockIdx.y;
  gemm_core<2, 1>(oa.agg[mod], 512, 0, oa.btg[mod], oa.bias[mod],
                  nullptr, oa.hb[mod], 128, N_NODES, 512, m0, 0,
                  oa.pv[mod], oa.als[mod], oa.ald[mod],
                  nullptr, nullptr, nullptr, nullptr, nullptr);
}

// head GEMMs + fused modal (y=0 computes final_emb too)
__global__ __launch_bounds__(256) void k_head(
    const unsigned short* __restrict__ hbv, const unsigned short* __restrict__ hbt,
    const unsigned short* __restrict__ btvh, const unsigned short* __restrict__ btth,
    const float* __restrict__ vhb, const float* __restrict__ thb,
    const float* __restrict__ mw, const float* __restrict__ mb,
    float* __restrict__ out) {
  int m0 = blockIdx.x * 64;
  if (blockIdx.y == 0) {
    gemm_core<0, 1>(hbv, 128, 0, btvh, vhb, out + 2560000, nullptr, 128,
                    N_NODES, 128, m0, 0,
                    nullptr, nullptr, nullptr, hbv, hbt, mw, mb, out);
  } else {
    gemm_core<0, 1>(hbt, 128, 0, btth, thb, out + 5120000, nullptr, 128,
                    N_NODES, 128, m0, 0,
                    nullptr, nullptr, nullptr, nullptr, nullptr, nullptr, nullptr, nullptr);
  }
}

extern "C" void kernel_launch(void* const* d_in, const int* in_sizes, int n_in,
                              void* d_out, int out_size, void* d_ws, size_t ws_size,
                              hipStream_t stream) {
  const float* x    = (const float*)d_in[0];
  const int*   ei   = (const int*)d_in[1];
  const float* vpw  = (const float*)d_in[2];
  const float* vpb  = (const float*)d_in[3];
  const float* tpw  = (const float*)d_in[4];
  const float* tpb  = (const float*)d_in[5];
  const float* vgw  = (const float*)d_in[6];
  const float* vgas = (const float*)d_in[7];
  const float* vgad = (const float*)d_in[8];
  const float* vgb  = (const float*)d_in[9];
  const float* tgw  = (const float*)d_in[10];
  const float* tgas = (const float*)d_in[11];
  const float* tgad = (const float*)d_in[12];
  const float* tgb  = (const float*)d_in[13];
  const float* mw   = (const float*)d_in[14];
  const float* mb   = (const float*)d_in[15];
  const float* vhw  = (const float*)d_in[16];
  const float* vhb  = (const float*)d_in[17];
  const float* thw  = (const float*)d_in[18];
  const float* thb  = (const float*)d_in[19];
  float* out = (float*)d_out;

  char* ws = (char*)d_ws;
  unsigned short* hb_v     = (unsigned short*)(ws);                //  5,120,000
  unsigned short* hb_t     = (unsigned short*)(ws + 5120000);      //  5,120,000
  unsigned short* agg_v    = (unsigned short*)(ws + 10240000);     // 20,480,000
  unsigned short* agg_t    = (unsigned short*)(ws + 30720000);     // 20,480,000
  float*          als_v    = (float*)(ws + 51200000);              //    320,000
  float*          ald_v    = (float*)(ws + 51520000);              //    320,000
  float*          als_t    = (float*)(ws + 51840000);              //    320,000
  float*          ald_t    = (float*)(ws + 52160000);              //    320,000
  int*            row_ptr  = (int*)  (ws + 52480000);              //     80,016
  int*            deg      = (int*)  (ws + 52560016);              //     80,000
  int*            edge_src = (int*)  (ws + 52640016);              //  1,360,000
  unsigned short* bt       = (unsigned short*)(ws + 54000016);     //    884,736
  float*          pvec     = (float*)(ws + 54884752);              //     16,384

  unsigned short* bt_vp = bt;            // [128][768]
  unsigned short* bt_tp = bt + 98304;    // [128][384]
  unsigned short* bt_vh = bt + 147456;   // [128][128]
  unsigned short* bt_th = bt + 163840;   // [128][128]
  unsigned short* bt_og = bt + 180224;   // 4 x [128][512] (mod*2+L)

  hipMemsetAsync(deg, 0, N_NODES * sizeof(int), stream);

  PrepArgs pa;
  pa.vpw = vpw; pa.tpw = tpw; pa.vhw = vhw; pa.thw = thw;
  pa.vgw = vgw; pa.tgw = tgw;
  pa.vgas = vgas; pa.vgad = vgad; pa.tgas = tgas; pa.tgad = tgad;
  pa.bt_vp = bt_vp; pa.bt_tp = bt_tp; pa.bt_vh = bt_vh; pa.bt_th = bt_th;
  pa.bt_og = bt_og; pa.pvec = pvec;
  k_prep<<<1744, 256, 0, stream>>>(pa);

  k_hist<<<(N_EDGES + 255) / 256, 256, 0, stream>>>(ei, deg);
  k_scan<<<1, 1024, 0, stream>>>(deg, row_ptr);
  k_scatter<<<(E_TOT + 255) / 256, 256, 0, stream>>>(ei, row_ptr, deg, edge_src);

  // projections + L0 logits
  k_proj<<<dim3(MT64, 2), 256, 0, stream>>>(x, bt_vp, bt_tp, vpb, tpb, hb_v, hb_t,
                                            pvec, als_v, ald_v, als_t, ald_t);

  // GAT layers
  for (int L = 0; L < 2; ++L) {
    AggArgs ag;
    ag.hb[0] = hb_v;   ag.hb[1] = hb_t;
    ag.als[0] = als_v; ag.als[1] = als_t;
    ag.ald[0] = ald_v; ag.ald[1] = ald_t;
    ag.agg[0] = agg_v; ag.agg[1] = agg_t;
    k_agg<<<2 * N_NODES, 128, 0, stream>>>(ag, row_ptr, edge_src);

    OutArgs oa;
    oa.agg[0] = agg_v; oa.agg[1] = agg_t;
    oa.btg[0] = bt_og + (size_t)(0 * 2 + L) * 65536;
    oa.btg[1] = bt_og + (size_t)(1 * 2 + L) * 65536;
    oa.bias[0] = vgb + L * HID;
    oa.bias[1] = tgb + L * HID;
    oa.hb[0] = hb_v;  oa.hb[1] = hb_t;
    if (L == 0) {
      oa.pv[0] = pvec + 2 * 1024;   // (L=1, mod=0)
      oa.pv[1] = pvec + 3 * 1024;   // (L=1, mod=1)
    } else {
      oa.pv[0] = nullptr; oa.pv[1] = nullptr;
    }
    oa.als[0] = als_v; oa.als[1] = als_t;
    oa.ald[0] = ald_v; oa.ald[1] = ald_t;
    k_out<<<dim3(MT64, 2), 256, 0, stream>>>(oa);
  }

  // head GEMMs + fused modal
  k_head<<<dim3(MT64, 2), 256, 0, stream>>>(hb_v, hb_t, bt_vh, bt_th, vhb, thb,
                                            mw, mb, out);
}

// Round 13
// 415.860 us; speedup vs baseline: 1.0994x; 1.0184x over previous
//
#include <hip/hip_runtime.h>
#include <math.h>

#define N_NODES 20000
#define N_EDGES 320000
#define E_TOT   (N_EDGES + N_NODES)
#define HID     128
#define NEG_SLOPE 0.2f
#define MT64    313   // ceil(20000/64)

typedef __attribute__((ext_vector_type(8))) short short8;
typedef __attribute__((ext_vector_type(4))) float f32x4;

__device__ __forceinline__ unsigned short f2b(float f) {
  unsigned u = __builtin_bit_cast(unsigned, f);
  return (unsigned short)((u + 0x7fffu + ((u >> 16) & 1u)) >> 16);
}
__device__ __forceinline__ float b2f(unsigned short h) {
  unsigned u = ((unsigned)h) << 16;
  return __builtin_bit_cast(float, u);
}
__device__ __forceinline__ unsigned pk2(float a, float b) {
  return (unsigned)f2b(a) | ((unsigned)f2b(b) << 16);
}
__device__ __forceinline__ unsigned addbf2(unsigned a, unsigned b) {
  float lo = b2f((unsigned short)(a & 0xffff)) + b2f((unsigned short)(b & 0xffff));
  float hi = b2f((unsigned short)(a >> 16)) + b2f((unsigned short)(b >> 16));
  return (unsigned)f2b(lo) | ((unsigned)f2b(hi) << 16);
}
__device__ __forceinline__ float lrelu(float x) { return x > 0.f ? x : NEG_SLOPE * x; }

// ---------------- merged prep: weight transposes + out-weights + pvec ----------------
struct PrepArgs {
  const float* vpw; const float* tpw; const float* vhw; const float* thw;
  const float* vgw; const float* tgw;
  const float* vgas; const float* vgad; const float* tgas; const float* tgad;
  unsigned short* bt_vp; unsigned short* bt_tp;
  unsigned short* bt_vh; unsigned short* bt_th;
  unsigned short* bt_og; float* pvec;
};
// blocks [0,704): 4 transpose jobs; [704,1728): og; [1728,1744): pvec
__global__ void k_prep(PrepArgs pa) {
  int b = blockIdx.x, t = threadIdx.x;
  if (b < 704) {
    const float* src; unsigned short* dst; int K, N, base;
    if (b < 384)      { src = pa.vpw; dst = pa.bt_vp; K = 768; N = 128; base = 0; }
    else if (b < 576) { src = pa.tpw; dst = pa.bt_tp; K = 384; N = 128; base = 384; }
    else if (b < 640) { src = pa.vhw; dst = pa.bt_vh; K = 128; N = 128; base = 576; }
    else              { src = pa.thw; dst = pa.bt_th; K = 128; N = 128; base = 640; }
    int idx = (b - base) * 256 + t;
    if (idx < N * K) {
      int n = idx / K, k = idx - n * K;
      dst[idx] = f2b(src[(size_t)k * N + n]);
    }
  } else if (b < 1728) {
    int bo = b - 704;
    int seg = bo >> 8;                  // mod*2 + L
    int mod = seg >> 1, L = seg & 1;
    const float* W = (mod ? pa.tgw : pa.vgw) + (size_t)L * 65536;
    int idx = (bo & 255) * 256 + t;     // 0..65535
    int out_ch = idx >> 9;
    int rem = idx & 511;
    int h = rem >> 7, kin = rem & 127;
    pa.bt_og[(size_t)seg * 65536 + idx] = f2b(W[(size_t)kin * 512 + h * 128 + out_ch]);
  } else {
    int idx = (b - 1728) * 256 + t;     // 0..4095
    int c = idx & 127, sd = (idx >> 7) & 1, lmh = idx >> 8;
    int L = lmh >> 3, mod = (lmh >> 2) & 1, h = lmh & 3;
    const float* W = (mod ? pa.tgw : pa.vgw) + (size_t)L * 65536;
    const float* a = (mod ? (sd ? pa.tgad : pa.tgas) : (sd ? pa.vgad : pa.vgas)) + L * 512 + h * 128;
    const float* wr = W + (size_t)c * 512 + h * 128;
    float s = 0.f;
    #pragma unroll 8
    for (int k = 0; k < 128; ++k) s += wr[k] * a[k];
    pa.pvec[(size_t)(((L * 2 + mod) * 2 + sd) * 4 + h) * 128 + c] = s;
  }
}

// ---------------- CSR build (deg zeroed by memsetAsync; +1 self loop in scan) ----------------
__global__ void k_hist(const int* __restrict__ ei, int* __restrict__ deg) {
  int e = blockIdx.x * blockDim.x + threadIdx.x;
  if (e < N_EDGES) atomicAdd(&deg[ei[N_EDGES + e]], 1);
}

__global__ __launch_bounds__(1024) void k_scan(int* __restrict__ deg,
                                               int* __restrict__ row_ptr) {
  __shared__ int sums[1024];
  int t = threadIdx.x;
  const int CH = 20;
  int begin = t * CH;
  int end = begin + CH; if (end > N_NODES) end = N_NODES;
  int loc = 0;
  for (int i = begin; i < end; ++i) loc += deg[i] + 1;
  sums[t] = loc;
  __syncthreads();
  for (int off = 1; off < 1024; off <<= 1) {
    int v = (t >= off) ? sums[t - off] : 0;
    __syncthreads();
    sums[t] += v;
    __syncthreads();
  }
  int run = (t > 0) ? sums[t - 1] : 0;
  for (int i = begin; i < end; ++i) {
    int d = deg[i] + 1;
    row_ptr[i] = run;
    run += d;
    deg[i] = 0;      // becomes the scatter cursor
  }
  if (t == 1023) row_ptr[N_NODES] = sums[1023];
}

__global__ void k_scatter(const int* __restrict__ ei, const int* __restrict__ row_ptr,
                          int* __restrict__ cursor, int* __restrict__ edge_src) {
  int t = blockIdx.x * blockDim.x + threadIdx.x;
  if (t < N_EDGES) {
    int s = ei[t], d = ei[N_EDGES + t];
    int pos = row_ptr[d] + atomicAdd(&cursor[d], 1);
    edge_src[pos] = s;
  } else if (t < E_TOT) {
    int i = t - N_EDGES;
    int pos = row_ptr[i] + atomicAdd(&cursor[i], 1);
    edge_src[pos] = i;
  }
}

// ---------------- GEMM core: 64x128 tile, BK=128, 4 waves (2x2) ----------------
// ABF16: A bf16 (else f32, converted in staging).
// MODE 0: f32 out + bias + relu (Cf); optional fused modal gate (mw != null).
// MODE 3: bf16 out + bias + relu (Cb); optional fused attn logits (pvg != null).
// MODE 2: bf16 in-place: Cb = bf16(elu(0.25*acc + bias)) + Cb_old; optional logits.
// NOTE: callers declare __launch_bounds__(256, 2) -> VGPR cap 128 so the
// 16-deep load buffers (ar/br = 64 VGPRs) + acc (32) stay in registers.
template<int MODE, int ABF16>
__device__ __forceinline__ void gemm_core(
    const void* Aptr, int lda, int c0,
    const unsigned short* __restrict__ Bt,
    const float* __restrict__ bias,
    float* __restrict__ Cf, unsigned short* __restrict__ Cb, int ldc,
    int M, int K, int m0, int n0,
    const float* __restrict__ pvg, float* __restrict__ als, float* __restrict__ ald,
    const unsigned short* __restrict__ mhv, const unsigned short* __restrict__ mht,
    const float* __restrict__ mw, const float* __restrict__ mb,
    float* __restrict__ out1) {
  __shared__ unsigned short sAB[64 * 128 + 128 * 128];  // As(16KB) | Bs(32KB)
  unsigned short* As = sAB;
  unsigned short* Bs = sAB + 64 * 128;

  int t = threadIdx.x;
  int w = t >> 6, l = t & 63;
  int wr = w >> 1, wc = w & 1;
  int lr = l & 15, lhi = l >> 4;

  int arow = t >> 2, aq = t & 3;
  int brow = t >> 1, bhalf = t & 1;
  int agr = m0 + arow; if (agr > M - 1) agr = M - 1;
  const float* af32 = (const float*)Aptr + (size_t)agr * lda + c0 + aq * 32;
  const unsigned short* ab16 = (const unsigned short*)Aptr + (size_t)agr * lda + c0 + aq * 32;
  const unsigned short* bptr = Bt + (size_t)(n0 + brow) * K + bhalf * 64;

  f32x4 acc[2][4];
  #pragma unroll
  for (int i = 0; i < 2; ++i)
    #pragma unroll
    for (int j = 0; j < 4; ++j) acc[i][j] = (f32x4){0.f, 0.f, 0.f, 0.f};

  float4 arf[8];
  uint4  arb[4];
  uint4  br[8];
  if (ABF16) {
    #pragma unroll
    for (int p = 0; p < 4; ++p) arb[p] = ((const uint4*)ab16)[p];
  } else {
    #pragma unroll
    for (int p = 0; p < 8; ++p) arf[p] = ((const float4*)af32)[p];
  }
  #pragma unroll
  for (int p = 0; p < 8; ++p) br[p] = ((const uint4*)bptr)[p];

  for (int k0 = 0; k0 < K; k0 += 128) {
    if (ABF16) {
      #pragma unroll
      for (int p = 0; p < 4; ++p) {
        int cb = aq * 4 + p;
        *(uint4*)&As[arow * 128 + ((cb ^ (arow & 15)) << 3)] = arb[p];
      }
    } else {
      #pragma unroll
      for (int p = 0; p < 4; ++p) {
        uint4 w4;
        w4.x = pk2(arf[2 * p].x, arf[2 * p].y);
        w4.y = pk2(arf[2 * p].z, arf[2 * p].w);
        w4.z = pk2(arf[2 * p + 1].x, arf[2 * p + 1].y);
        w4.w = pk2(arf[2 * p + 1].z, arf[2 * p + 1].w);
        int cb = aq * 4 + p;
        *(uint4*)&As[arow * 128 + ((cb ^ (arow & 15)) << 3)] = w4;
      }
    }
    #pragma unroll
    for (int p = 0; p < 8; ++p) {
      int cb = bhalf * 8 + p;
      *(uint4*)&Bs[brow * 128 + ((cb ^ (brow & 15)) << 3)] = br[p];
    }
    __syncthreads();
    if (k0 + 128 < K) {
      if (ABF16) {
        #pragma unroll
        for (int p = 0; p < 4; ++p) arb[p] = ((const uint4*)(ab16 + k0 + 128))[p];
      } else {
        #pragma unroll
        for (int p = 0; p < 8; ++p) arf[p] = ((const float4*)(af32 + k0 + 128))[p];
      }
      #pragma unroll
      for (int p = 0; p < 8; ++p) br[p] = ((const uint4*)(bptr + k0 + 128))[p];
    }
    #pragma unroll
    for (int kk = 0; kk < 4; ++kk) {
      short8 af[2], bfr[4];
      int cbf = lhi + kk * 4;
      #pragma unroll
      for (int i = 0; i < 2; ++i) {
        int row = wr * 32 + i * 16 + lr;
        af[i] = *(const short8*)&As[row * 128 + ((cbf ^ (row & 15)) << 3)];
      }
      #pragma unroll
      for (int j = 0; j < 4; ++j) {
        int nn = wc * 64 + j * 16 + lr;
        bfr[j] = *(const short8*)&Bs[nn * 128 + ((cbf ^ (nn & 15)) << 3)];
      }
      #pragma unroll
      for (int i = 0; i < 2; ++i)
        #pragma unroll
        for (int j = 0; j < 4; ++j)
          acc[i][j] = __builtin_amdgcn_mfma_f32_16x16x32_bf16(af[i], bfr[j], acc[i][j], 0, 0, 0);
    }
    __syncthreads();
  }

  if (MODE == 0) {
    float* Ctf = (float*)sAB;   // [64][128] f32
    #pragma unroll
    for (int i = 0; i < 2; ++i)
      #pragma unroll
      for (int j = 0; j < 4; ++j) {
        int col = wc * 64 + j * 16 + lr;
        float bsv = bias[col];
        #pragma unroll
        for (int rr = 0; rr < 4; ++rr) {
          int row = wr * 32 + i * 16 + lhi * 4 + rr;
          Ctf[row * 128 + col] = fmaxf(acc[i][j][rr] + bsv, 0.f);
        }
      }
    __syncthreads();
    float mb0 = mw ? mb[0] : 0.f;
    #pragma unroll
    for (int p = 0; p < 8; ++p) {
      int ci = (p << 8) + t;
      int row = ci >> 5, ch = ci & 31;
      int gr = m0 + row;
      int cg = gr < M ? gr : M - 1;
      float4 v = *(const float4*)&Ctf[row * 128 + (ch << 2)];
      if (gr < M) ((float4*)(Cf + (size_t)gr * ldc))[ch] = v;
      if (mw) {
        uint2 a2 = *(const uint2*)&mhv[(size_t)cg * 128 + (ch << 2)];
        uint2 b2 = *(const uint2*)&mht[(size_t)cg * 128 + (ch << 2)];
        float4 wv = ((const float4*)mw)[ch];
        float4 wt = ((const float4*)(mw + 128))[ch];
        float a0 = b2f((unsigned short)(a2.x & 0xffff)), a1 = b2f((unsigned short)(a2.x >> 16));
        float a2f = b2f((unsigned short)(a2.y & 0xffff)), a3 = b2f((unsigned short)(a2.y >> 16));
        float b0 = b2f((unsigned short)(b2.x & 0xffff)), b1 = b2f((unsigned short)(b2.x >> 16));
        float b2v = b2f((unsigned short)(b2.y & 0xffff)), b3 = b2f((unsigned short)(b2.y >> 16));
        float ps = a0 * wv.x + a1 * wv.y + a2f * wv.z + a3 * wv.w
                 + b0 * wt.x + b1 * wt.y + b2v * wt.z + b3 * wt.w;
        #pragma unroll
        for (int off = 1; off < 32; off <<= 1) ps += __shfl_xor(ps, off);
        float beta = 1.f / (1.f + __expf(-(ps + mb0)));
        float4 o;
        o.x = beta * a0 + (1.f - beta) * b0;
        o.y = beta * a1 + (1.f - beta) * b1;
        o.z = beta * a2f + (1.f - beta) * b2v;
        o.w = beta * a3 + (1.f - beta) * b3;
        if (gr < M) ((float4*)(out1 + (size_t)gr * 128))[ch] = o;
      }
    }
  } else {
    unsigned short* Ct = sAB;   // [64][128] bf16 (16 KB)
    float* pvL = (float*)(sAB + 8192);  // 4 KB, dead Bs region
    #pragma unroll
    for (int i = 0; i < 2; ++i)
      #pragma unroll
      for (int j = 0; j < 4; ++j) {
        int col = wc * 64 + j * 16 + lr;
        float bsv = bias[col];
        #pragma unroll
        for (int rr = 0; rr < 4; ++rr) {
          int row = wr * 32 + i * 16 + lhi * 4 + rr;
          float v;
          if (MODE == 3) {
            v = fmaxf(acc[i][j][rr] + bsv, 0.f);
          } else {
            v = 0.25f * acc[i][j][rr] + bsv;
            v = v > 0.f ? v : __expf(v) - 1.f;
          }
          Ct[row * 128 + col] = f2b(v);
        }
      }
    __syncthreads();
    if (pvg) ((float4*)pvL)[t] = ((const float4*)pvg)[t];   // 1024 floats
    __syncthreads();
    #pragma unroll
    for (int p = 0; p < 4; ++p) {
      int ci = (p << 8) + t;
      int row = ci >> 4, ch = ci & 15;
      int gr = m0 + row;
      int cg = gr < M ? gr : M - 1;
      uint4 cv = *(const uint4*)&Ct[row * 128 + (ch << 3)];
      uint4* gptr = (uint4*)(Cb + (size_t)cg * ldc) + ch;
      if (MODE == 2) {
        uint4 hv = *gptr;
        cv.x = addbf2(cv.x, hv.x); cv.y = addbf2(cv.y, hv.y);
        cv.z = addbf2(cv.z, hv.z); cv.w = addbf2(cv.w, hv.w);
      }
      if (gr < M) *gptr = cv;
      if (pvg) {
        float v0 = b2f((unsigned short)(cv.x & 0xffff)), v1 = b2f((unsigned short)(cv.x >> 16));
        float v2 = b2f((unsigned short)(cv.y & 0xffff)), v3 = b2f((unsigned short)(cv.y >> 16));
        float v4 = b2f((unsigned short)(cv.z & 0xffff)), v5 = b2f((unsigned short)(cv.z >> 16));
        float v6 = b2f((unsigned short)(cv.w & 0xffff)), v7 = b2f((unsigned short)(cv.w >> 16));
        float s0, s1, s2, s3, s4, s5, s6, s7;
        {
          const float4* pr;
          pr = (const float4*)&pvL[0 * 128 + (ch << 3)];
          s0 = v0*pr[0].x + v1*pr[0].y + v2*pr[0].z + v3*pr[0].w + v4*pr[1].x + v5*pr[1].y + v6*pr[1].z + v7*pr[1].w;
          pr = (const float4*)&pvL[1 * 128 + (ch << 3)];
          s1 = v0*pr[0].x + v1*pr[0].y + v2*pr[0].z + v3*pr[0].w + v4*pr[1].x + v5*pr[1].y + v6*pr[1].z + v7*pr[1].w;
          pr = (const float4*)&pvL[2 * 128 + (ch << 3)];
          s2 = v0*pr[0].x + v1*pr[0].y + v2*pr[0].z + v3*pr[0].w + v4*pr[1].x + v5*pr[1].y + v6*pr[1].z + v7*pr[1].w;
          pr = (const float4*)&pvL[3 * 128 + (ch << 3)];
          s3 = v0*pr[0].x + v1*pr[0].y + v2*pr[0].z + v3*pr[0].w + v4*pr[1].x + v5*pr[1].y + v6*pr[1].z + v7*pr[1].w;
          pr = (const float4*)&pvL[4 * 128 + (ch << 3)];
          s4 = v0*pr[0].x + v1*pr[0].y + v2*pr[0].z + v3*pr[0].w + v4*pr[1].x + v5*pr[1].y + v6*pr[1].z + v7*pr[1].w;
          pr = (const float4*)&pvL[5 * 128 + (ch << 3)];
          s5 = v0*pr[0].x + v1*pr[0].y + v2*pr[0].z + v3*pr[0].w + v4*pr[1].x + v5*pr[1].y + v6*pr[1].z + v7*pr[1].w;
          pr = (const float4*)&pvL[6 * 128 + (ch << 3)];
          s6 = v0*pr[0].x + v1*pr[0].y + v2*pr[0].z + v3*pr[0].w + v4*pr[1].x + v5*pr[1].y + v6*pr[1].z + v7*pr[1].w;
          pr = (const float4*)&pvL[7 * 128 + (ch << 3)];
          s7 = v0*pr[0].x + v1*pr[0].y + v2*pr[0].z + v3*pr[0].w + v4*pr[1].x + v5*pr[1].y + v6*pr[1].z + v7*pr[1].w;
        }
        #pragma unroll
        for (int off = 1; off < 16; off <<= 1) {
          s0 += __shfl_xor(s0, off); s1 += __shfl_xor(s1, off);
          s2 += __shfl_xor(s2, off); s3 += __shfl_xor(s3, off);
          s4 += __shfl_xor(s4, off); s5 += __shfl_xor(s5, off);
          s6 += __shfl_xor(s6, off); s7 += __shfl_xor(s7, off);
        }
        if ((t & 15) == 0 && gr < M) {
          als[gr * 4 + 0] = s0; als[gr * 4 + 1] = s1;
          als[gr * 4 + 2] = s2; als[gr * 4 + 3] = s3;
          ald[gr * 4 + 0] = s4; ald[gr * 4 + 1] = s5;
          ald[gr * 4 + 2] = s6; ald[gr * 4 + 3] = s7;
        }
      }
    }
  }
}

// projections + fused L0 logits: y = modality
__global__ __launch_bounds__(256, 2) void k_proj(
    const float* __restrict__ x,
    const unsigned short* __restrict__ btv, const unsigned short* __restrict__ btt,
    const float* __restrict__ vb, const float* __restrict__ tb,
    unsigned short* __restrict__ hbv, unsigned short* __restrict__ hbt,
    const float* __restrict__ pvec,
    float* __restrict__ alsv, float* __restrict__ aldv,
    float* __restrict__ alst, float* __restrict__ aldt) {
  int m0 = blockIdx.x * 64;
  int mod = blockIdx.y;
  int c0, K;
  const unsigned short* Bt;
  const float* bias;
  unsigned short* Cb;
  if (mod == 0) { c0 = 0;   K = 768; Bt = btv; bias = vb; Cb = hbv; }
  else          { c0 = 768; K = 384; Bt = btt; bias = tb; Cb = hbt; }
  gemm_core<3, 0>(x, 1152, c0, Bt, bias, nullptr, Cb, 128, N_NODES, K, m0, 0,
                  pvec + (size_t)mod * 1024,
                  mod ? alst : alsv, mod ? aldt : aldv,
                  nullptr, nullptr, nullptr, nullptr, nullptr);
}

// ---------------- GAT aggregation ----------------
struct AggArgs {
  const unsigned short* hb[2];
  const float* als[2];
  const float* ald[2];
  unsigned short* agg[2];
};
__global__ __launch_bounds__(128) void k_agg(AggArgs ag,
                                             const int* __restrict__ row_ptr,
                                             const int* __restrict__ edge_src) {
  int b = blockIdx.x;
  int mod = b >= N_NODES;
  int node = b - mod * N_NODES;
  const unsigned short* __restrict__ hbm = ag.hb[mod];
  const float* __restrict__ als = ag.als[mod];
  const float* __restrict__ ald = ag.ald[mod];
  unsigned short* __restrict__ arow_ = ag.agg[mod] + (size_t)node * 512;

  int tid = threadIdx.x;
  __shared__ float sp[128][4];
  __shared__ int   ssrc[128];
  __shared__ float sredm[8], sreds[8];
  __shared__ float soutC[2][4][128];
  __shared__ float red[4 * 128];
  int begin = row_ptr[node], end = row_ptr[node + 1];
  int deg = end - begin;
  float4 ad4 = *(const float4*)(ald + (size_t)node * 4);
  int wv = tid >> 6;

  if (deg <= 128) {
    float e0 = -1e30f, e1 = -1e30f, e2 = -1e30f, e3 = -1e30f;
    if (tid < deg) {
      int s = edge_src[begin + tid];
      ssrc[tid] = s;
      float4 a4 = *(const float4*)(als + (size_t)s * 4);
      e0 = lrelu(a4.x + ad4.x); e1 = lrelu(a4.y + ad4.y);
      e2 = lrelu(a4.z + ad4.z); e3 = lrelu(a4.w + ad4.w);
    }
    float m0 = e0, m1 = e1, m2 = e2, m3 = e3;
    for (int off = 32; off > 0; off >>= 1) {
      m0 = fmaxf(m0, __shfl_xor(m0, off));
      m1 = fmaxf(m1, __shfl_xor(m1, off));
      m2 = fmaxf(m2, __shfl_xor(m2, off));
      m3 = fmaxf(m3, __shfl_xor(m3, off));
    }
    if ((tid & 63) == 0) {
      sredm[wv * 4 + 0] = m0; sredm[wv * 4 + 1] = m1;
      sredm[wv * 4 + 2] = m2; sredm[wv * 4 + 3] = m3;
    }
    __syncthreads();
    m0 = fmaxf(sredm[0], sredm[4]); m1 = fmaxf(sredm[1], sredm[5]);
    m2 = fmaxf(sredm[2], sredm[6]); m3 = fmaxf(sredm[3], sredm[7]);
    float p0 = 0.f, p1 = 0.f, p2 = 0.f, p3 = 0.f;
    if (tid < deg) {
      p0 = __expf(e0 - m0); p1 = __expf(e1 - m1);
      p2 = __expf(e2 - m2); p3 = __expf(e3 - m3);
    }
    *(float4*)&sp[tid][0] = make_float4(p0, p1, p2, p3);
    float s0 = p0, s1 = p1, s2 = p2, s3 = p3;
    for (int off = 32; off > 0; off >>= 1) {
      s0 += __shfl_xor(s0, off); s1 += __shfl_xor(s1, off);
      s2 += __shfl_xor(s2, off); s3 += __shfl_xor(s3, off);
    }
    if ((tid & 63) == 0) {
      sreds[wv * 4 + 0] = s0; sreds[wv * 4 + 1] = s1;
      sreds[wv * 4 + 2] = s2; sreds[wv * 4 + 3] = s3;
    }
    __syncthreads();
    float inv0 = 1.f / (sreds[0] + sreds[4] + 1e-16f);
    float inv1 = 1.f / (sreds[1] + sreds[5] + 1e-16f);
    float inv2 = 1.f / (sreds[2] + sreds[6] + 1e-16f);
    float inv3 = 1.f / (sreds[3] + sreds[7] + 1e-16f);

    int lane = tid & 63;
    int c2 = lane << 1;
    const unsigned short* hb0 = hbm + c2;
    float a00 = 0.f, a01 = 0.f, a10 = 0.f, a11 = 0.f;
    float a20 = 0.f, a21 = 0.f, a30 = 0.f, a31 = 0.f;
    for (int k = wv; k < deg; k += 2) {
      int s = ssrc[k];
      float4 pk = *(const float4*)&sp[k][0];
      unsigned xv = *(const unsigned*)(hb0 + (size_t)s * 128);
      float x0 = b2f((unsigned short)(xv & 0xffff));
      float x1 = b2f((unsigned short)(xv >> 16));
      a00 += pk.x * x0; a01 += pk.x * x1;
      a10 += pk.y * x0; a11 += pk.y * x1;
      a20 += pk.z * x0; a21 += pk.z * x1;
      a30 += pk.w * x0; a31 += pk.w * x1;
    }
    *(float2*)&soutC[wv][0][c2] = make_float2(a00, a01);
    *(float2*)&soutC[wv][1][c2] = make_float2(a10, a11);
    *(float2*)&soutC[wv][2][c2] = make_float2(a20, a21);
    *(float2*)&soutC[wv][3][c2] = make_float2(a30, a31);
    __syncthreads();
    arow_[0 * 128 + tid] = f2b((soutC[0][0][tid] + soutC[1][0][tid]) * inv0);
    arow_[1 * 128 + tid] = f2b((soutC[0][1][tid] + soutC[1][1][tid]) * inv1);
    arow_[2 * 128 + tid] = f2b((soutC[0][2][tid] + soutC[1][2][tid]) * inv2);
    arow_[3 * 128 + tid] = f2b((soutC[0][3][tid] + soutC[1][3][tid]) * inv3);
    return;
  }

  // generic fallback (deg > 128)
  float lm0 = -1e30f, lm1 = -1e30f, lm2 = -1e30f, lm3 = -1e30f;
  for (int idx = begin + tid; idx < end; idx += 128) {
    int s = edge_src[idx];
    float4 a4 = *(const float4*)(als + (size_t)s * 4);
    lm0 = fmaxf(lm0, lrelu(a4.x + ad4.x));
    lm1 = fmaxf(lm1, lrelu(a4.y + ad4.y));
    lm2 = fmaxf(lm2, lrelu(a4.z + ad4.z));
    lm3 = fmaxf(lm3, lrelu(a4.w + ad4.w));
  }
  red[tid] = lm0; red[128 + tid] = lm1; red[256 + tid] = lm2; red[384 + tid] = lm3;
  __syncthreads();
  for (int off = 64; off > 0; off >>= 1) {
    if (tid < off) {
      red[tid]       = fmaxf(red[tid],       red[tid + off]);
      red[128 + tid] = fmaxf(red[128 + tid], red[128 + tid + off]);
      red[256 + tid] = fmaxf(red[256 + tid], red[256 + tid + off]);
      red[384 + tid] = fmaxf(red[384 + tid], red[384 + tid + off]);
    }
    __syncthreads();
  }
  float m0 = red[0], m1 = red[128], m2 = red[256], m3 = red[384];
  __syncthreads();
  float ls0 = 0.f, ls1 = 0.f, ls2 = 0.f, ls3 = 0.f;
  for (int idx = begin + tid; idx < end; idx += 128) {
    int s = edge_src[idx];
    float4 a4 = *(const float4*)(als + (size_t)s * 4);
    ls0 += __expf(lrelu(a4.x + ad4.x) - m0);
    ls1 += __expf(lrelu(a4.y + ad4.y) - m1);
    ls2 += __expf(lrelu(a4.z + ad4.z) - m2);
    ls3 += __expf(lrelu(a4.w + ad4.w) - m3);
  }
  red[tid] = ls0; red[128 + tid] = ls1; red[256 + tid] = ls2; red[384 + tid] = ls3;
  __syncthreads();
  for (int off = 64; off > 0; off >>= 1) {
    if (tid < off) {
      red[tid]       += red[tid + off];
      red[128 + tid] += red[128 + tid + off];
      red[256 + tid] += red[256 + tid + off];
      red[384 + tid] += red[384 + tid + off];
    }
    __syncthreads();
  }
  float inv0 = 1.f / (red[0]   + 1e-16f);
  float inv1 = 1.f / (red[128] + 1e-16f);
  float inv2 = 1.f / (red[256] + 1e-16f);
  float inv3 = 1.f / (red[384] + 1e-16f);
  float acc0 = 0.f, acc1 = 0.f, acc2 = 0.f, acc3 = 0.f;
  for (int idx = begin; idx < end; ++idx) {
    int s = edge_src[idx];
    float4 a4 = *(const float4*)(als + (size_t)s * 4);
    float al0 = __expf(lrelu(a4.x + ad4.x) - m0) * inv0;
    float al1 = __expf(lrelu(a4.y + ad4.y) - m1) * inv1;
    float al2 = __expf(lrelu(a4.z + ad4.z) - m2) * inv2;
    float al3 = __expf(lrelu(a4.w + ad4.w) - m3) * inv3;
    float xc = b2f(hbm[(size_t)s * 128 + tid]);
    acc0 += al0 * xc; acc1 += al1 * xc; acc2 += al2 * xc; acc3 += al3 * xc;
  }
  arow_[0 * 128 + tid] = f2b(acc0);
  arow_[1 * 128 + tid] = f2b(acc1);
  arow_[2 * 128 + tid] = f2b(acc2);
  arow_[3 * 128 + tid] = f2b(acc3);
}

// out-transform + residual + optional fused next-layer logits
struct OutArgs {
  const unsigned short* agg[2];
  const unsigned short* btg[2];
  const float* bias[2];
  unsigned short* hb[2];
  const float* pv[2];   // next layer pvec base (or null)
  float* als[2];
  float* ald[2];
};
__global__ __launch_bounds__(256, 2) void k_out(OutArgs oa) {
  int m0 = blockIdx.x * 64;
  int mod = blockIdx.y;
  gemm_core<2, 1>(oa.agg[mod], 512, 0, oa.btg[mod], oa.bias[mod],
                  nullptr, oa.hb[mod], 128, N_NODES, 512, m0, 0,
                  oa.pv[mod], oa.als[mod], oa.ald[mod],
                  nullptr, nullptr, nullptr, nullptr, nullptr);
}

// head GEMMs + fused modal (y=0 computes final_emb too)
__global__ __launch_bounds__(256, 2) void k_head(
    const unsigned short* __restrict__ hbv, const unsigned short* __restrict__ hbt,
    const unsigned short* __restrict__ btvh, const unsigned short* __restrict__ btth,
    const float* __restrict__ vhb, const float* __restrict__ thb,
    const float* __restrict__ mw, const float* __restrict__ mb,
    float* __restrict__ out) {
  int m0 = blockIdx.x * 64;
  if (blockIdx.y == 0) {
    gemm_core<0, 1>(hbv, 128, 0, btvh, vhb, out + 2560000, nullptr, 128,
                    N_NODES, 128, m0, 0,
                    nullptr, nullptr, nullptr, hbv, hbt, mw, mb, out);
  } else {
    gemm_core<0, 1>(hbt, 128, 0, btth, thb, out + 5120000, nullptr, 128,
                    N_NODES, 128, m0, 0,
                    nullptr, nullptr, nullptr, nullptr, nullptr, nullptr, nullptr, nullptr);
  }
}

extern "C" void kernel_launch(void* const* d_in, const int* in_sizes, int n_in,
                              void* d_out, int out_size, void* d_ws, size_t ws_size,
                              hipStream_t stream) {
  const float* x    = (const float*)d_in[0];
  const int*   ei   = (const int*)d_in[1];
  const float* vpw  = (const float*)d_in[2];
  const float* vpb  = (const float*)d_in[3];
  const float* tpw  = (const float*)d_in[4];
  const float* tpb  = (const float*)d_in[5];
  const float* vgw  = (const float*)d_in[6];
  const float* vgas = (const float*)d_in[7];
  const float* vgad = (const float*)d_in[8];
  const float* vgb  = (const float*)d_in[9];
  const float* tgw  = (const float*)d_in[10];
  const float* tgas = (const float*)d_in[11];
  const float* tgad = (const float*)d_in[12];
  const float* tgb  = (const float*)d_in[13];
  const float* mw   = (const float*)d_in[14];
  const float* mb   = (const float*)d_in[15];
  const float* vhw  = (const float*)d_in[16];
  const float* vhb  = (const float*)d_in[17];
  const float* thw  = (const float*)d_in[18];
  const float* thb  = (const float*)d_in[19];
  float* out = (float*)d_out;

  char* ws = (char*)d_ws;
  unsigned short* hb_v     = (unsigned short*)(ws);                //  5,120,000
  unsigned short* hb_t     = (unsigned short*)(ws + 5120000);      //  5,120,000
  unsigned short* agg_v    = (unsigned short*)(ws + 10240000);     // 20,480,000
  unsigned short* agg_t    = (unsigned short*)(ws + 30720000);     // 20,480,000
  float*          als_v    = (float*)(ws + 51200000);              //    320,000
  float*          ald_v    = (float*)(ws + 51520000);              //    320,000
  float*          als_t    = (float*)(ws + 51840000);              //    320,000
  float*          ald_t    = (float*)(ws + 52160000);              //    320,000
  int*            row_ptr  = (int*)  (ws + 52480000);              //     80,016
  int*            deg      = (int*)  (ws + 52560016);              //     80,000
  int*            edge_src = (int*)  (ws + 52640016);              //  1,360,000
  unsigned short* bt       = (unsigned short*)(ws + 54000016);     //    884,736
  float*          pvec     = (float*)(ws + 54884752);              //     16,384

  unsigned short* bt_vp = bt;            // [128][768]
  unsigned short* bt_tp = bt + 98304;    // [128][384]
  unsigned short* bt_vh = bt + 147456;   // [128][128]
  unsigned short* bt_th = bt + 163840;   // [128][128]
  unsigned short* bt_og = bt + 180224;   // 4 x [128][512] (mod*2+L)

  hipMemsetAsync(deg, 0, N_NODES * sizeof(int), stream);

  PrepArgs pa;
  pa.vpw = vpw; pa.tpw = tpw; pa.vhw = vhw; pa.thw = thw;
  pa.vgw = vgw; pa.tgw = tgw;
  pa.vgas = vgas; pa.vgad = vgad; pa.tgas = tgas; pa.tgad = tgad;
  pa.bt_vp = bt_vp; pa.bt_tp = bt_tp; pa.bt_vh = bt_vh; pa.bt_th = bt_th;
  pa.bt_og = bt_og; pa.pvec = pvec;
  k_prep<<<1744, 256, 0, stream>>>(pa);

  k_hist<<<(N_EDGES + 255) / 256, 256, 0, stream>>>(ei, deg);
  k_scan<<<1, 1024, 0, stream>>>(deg, row_ptr);
  k_scatter<<<(E_TOT + 255) / 256, 256, 0, stream>>>(ei, row_ptr, deg, edge_src);

  // projections + L0 logits
  k_proj<<<dim3(MT64, 2), 256, 0, stream>>>(x, bt_vp, bt_tp, vpb, tpb, hb_v, hb_t,
                                            pvec, als_v, ald_v, als_t, ald_t);

  // GAT layers
  for (int L = 0; L < 2; ++L) {
    AggArgs ag;
    ag.hb[0] = hb_v;   ag.hb[1] = hb_t;
    ag.als[0] = als_v; ag.als[1] = als_t;
    ag.ald[0] = ald_v; ag.ald[1] = ald_t;
    ag.agg[0] = agg_v; ag.agg[1] = agg_t;
    k_agg<<<2 * N_NODES, 128, 0, stream>>>(ag, row_ptr, edge_src);

    OutArgs oa;
    oa.agg[0] = agg_v; oa.agg[1] = agg_t;
    oa.btg[0] = bt_og + (size_t)(0 * 2 + L) * 65536;
    oa.btg[1] = bt_og + (size_t)(1 * 2 + L) * 65536;
    oa.bias[0] = vgb + L * HID;
    oa.bias[1] = tgb + L * HID;
    oa.hb[0] = hb_v;  oa.hb[1] = hb_t;
    if (L == 0) {
      oa.pv[0] = pvec + 2 * 1024;   // (L=1, mod=0)
      oa.pv[1] = pvec + 3 * 1024;   // (L=1, mod=1)
    } else {
      oa.pv[0] = nullptr; oa.pv[1] = nullptr;
    }
    oa.als[0] = als_v; oa.als[1] = als_t;
    oa.ald[0] = ald_v; oa.ald[1] = ald_t;
    k_out<<<dim3(MT64, 2), 256, 0, stream>>>(oa);
  }

  // head GEMMs + fused modal
  k_head<<<dim3(MT64, 2), 256, 0, stream>>>(hb_v, hb_t, bt_vh, bt_th, vhb, thb,
                                            mw, mb, out);
}

// Round 15
// 328.185 us; speedup vs baseline: 1.3931x; 1.2672x over previous
//
#include <hip/hip_runtime.h>
#include <math.h>

#define N_NODES 20000
#define N_EDGES 320000
#define E_TOT   (N_EDGES + N_NODES)
#define HID     128
#define NEG_SLOPE 0.2f
#define MT64    313   // ceil(20000/64)

typedef __attribute__((ext_vector_type(8))) short short8;
typedef __attribute__((ext_vector_type(4))) float f32x4;

__device__ __forceinline__ unsigned short f2b(float f) {
  unsigned u = __builtin_bit_cast(unsigned, f);
  return (unsigned short)((u + 0x7fffu + ((u >> 16) & 1u)) >> 16);
}
__device__ __forceinline__ float b2f(unsigned short h) {
  unsigned u = ((unsigned)h) << 16;
  return __builtin_bit_cast(float, u);
}
__device__ __forceinline__ unsigned pk2(float a, float b) {
  return (unsigned)f2b(a) | ((unsigned)f2b(b) << 16);
}
__device__ __forceinline__ unsigned addbf2(unsigned a, unsigned b) {
  float lo = b2f((unsigned short)(a & 0xffff)) + b2f((unsigned short)(b & 0xffff));
  float hi = b2f((unsigned short)(a >> 16)) + b2f((unsigned short)(b >> 16));
  return (unsigned)f2b(lo) | ((unsigned)f2b(hi) << 16);
}
__device__ __forceinline__ float lrelu(float x) { return x > 0.f ? x : NEG_SLOPE * x; }

// async global->LDS, 16B per lane; dst is wave-uniform base, src per-lane.
__device__ __forceinline__ void gload16(const unsigned short* g, unsigned short* l) {
  __builtin_amdgcn_global_load_lds(
      (const __attribute__((address_space(1))) unsigned int*)(const void*)g,
      (__attribute__((address_space(3))) unsigned int*)(void*)l,
      16, 0, 0);
}

// ---------------- x -> bf16 conversion (streaming) ----------------
__global__ void k_xcvt(const float* __restrict__ x, unsigned short* __restrict__ xb) {
  const int TOT = N_NODES * 1152 / 8;   // 2,880,000 groups of 8
  for (int i = blockIdx.x * blockDim.x + threadIdx.x; i < TOT;
       i += gridDim.x * blockDim.x) {
    float4 v0 = ((const float4*)x)[i * 2];
    float4 v1 = ((const float4*)x)[i * 2 + 1];
    uint4 o;
    o.x = pk2(v0.x, v0.y); o.y = pk2(v0.z, v0.w);
    o.z = pk2(v1.x, v1.y); o.w = pk2(v1.z, v1.w);
    ((uint4*)xb)[i] = o;
  }
}

// ---------------- merged prep: weight transposes + out-weights + pvec ----------------
struct PrepArgs {
  const float* vpw; const float* tpw; const float* vhw; const float* thw;
  const float* vgw; const float* tgw;
  const float* vgas; const float* vgad; const float* tgas; const float* tgad;
  unsigned short* bt_vp; unsigned short* bt_tp;
  unsigned short* bt_vh; unsigned short* bt_th;
  unsigned short* bt_og; float* pvec;
};
// blocks [0,704): 4 transpose jobs; [704,1728): og; [1728,1744): pvec
__global__ void k_prep(PrepArgs pa) {
  int b = blockIdx.x, t = threadIdx.x;
  if (b < 704) {
    const float* src; unsigned short* dst; int K, N, base;
    if (b < 384)      { src = pa.vpw; dst = pa.bt_vp; K = 768; N = 128; base = 0; }
    else if (b < 576) { src = pa.tpw; dst = pa.bt_tp; K = 384; N = 128; base = 384; }
    else if (b < 640) { src = pa.vhw; dst = pa.bt_vh; K = 128; N = 128; base = 576; }
    else              { src = pa.thw; dst = pa.bt_th; K = 128; N = 128; base = 640; }
    int idx = (b - base) * 256 + t;
    if (idx < N * K) {
      int n = idx / K, k = idx - n * K;
      dst[idx] = f2b(src[(size_t)k * N + n]);
    }
  } else if (b < 1728) {
    int bo = b - 704;
    int seg = bo >> 8;                  // mod*2 + L
    int mod = seg >> 1, L = seg & 1;
    const float* W = (mod ? pa.tgw : pa.vgw) + (size_t)L * 65536;
    int idx = (bo & 255) * 256 + t;     // 0..65535
    int out_ch = idx >> 9;
    int rem = idx & 511;
    int h = rem >> 7, kin = rem & 127;
    pa.bt_og[(size_t)seg * 65536 + idx] = f2b(W[(size_t)kin * 512 + h * 128 + out_ch]);
  } else {
    int idx = (b - 1728) * 256 + t;     // 0..4095
    int c = idx & 127, sd = (idx >> 7) & 1, lmh = idx >> 8;
    int L = lmh >> 3, mod = (lmh >> 2) & 1, h = lmh & 3;
    const float* W = (mod ? pa.tgw : pa.vgw) + (size_t)L * 65536;
    const float* a = (mod ? (sd ? pa.tgad : pa.tgas) : (sd ? pa.vgad : pa.vgas)) + L * 512 + h * 128;
    const float* wr = W + (size_t)c * 512 + h * 128;
    float s = 0.f;
    #pragma unroll 8
    for (int k = 0; k < 128; ++k) s += wr[k] * a[k];
    pa.pvec[(size_t)(((L * 2 + mod) * 2 + sd) * 4 + h) * 128 + c] = s;
  }
}

// ---------------- CSR build ----------------
__global__ void k_hist(const int* __restrict__ ei, int* __restrict__ deg) {
  int e = blockIdx.x * blockDim.x + threadIdx.x;
  if (e < N_EDGES) atomicAdd(&deg[ei[N_EDGES + e]], 1);
}

__global__ __launch_bounds__(1024) void k_scan(int* __restrict__ deg,
                                               int* __restrict__ row_ptr) {
  __shared__ int sums[1024];
  int t = threadIdx.x;
  const int CH = 20;
  int begin = t * CH;
  int end = begin + CH; if (end > N_NODES) end = N_NODES;
  int loc = 0;
  for (int i = begin; i < end; ++i) loc += deg[i] + 1;
  sums[t] = loc;
  __syncthreads();
  for (int off = 1; off < 1024; off <<= 1) {
    int v = (t >= off) ? sums[t - off] : 0;
    __syncthreads();
    sums[t] += v;
    __syncthreads();
  }
  int run = (t > 0) ? sums[t - 1] : 0;
  for (int i = begin; i < end; ++i) {
    int d = deg[i] + 1;
    row_ptr[i] = run;
    run += d;
    deg[i] = 0;      // becomes the scatter cursor
  }
  if (t == 1023) row_ptr[N_NODES] = sums[1023];
}

__global__ void k_scatter(const int* __restrict__ ei, const int* __restrict__ row_ptr,
                          int* __restrict__ cursor, int* __restrict__ edge_src) {
  int t = blockIdx.x * blockDim.x + threadIdx.x;
  if (t < N_EDGES) {
    int s = ei[t], d = ei[N_EDGES + t];
    int pos = row_ptr[d] + atomicAdd(&cursor[d], 1);
    edge_src[pos] = s;
  } else if (t < E_TOT) {
    int i = t - N_EDGES;
    int pos = row_ptr[i] + atomicAdd(&cursor[i], 1);
    edge_src[pos] = i;
  }
}

// ---------------- GEMM core: 64x128 tile, BK=128, 4 waves (2x2) ----------------
// A bf16 [M x lda]; staging via global_load_lds with pre-swizzled global source:
// LDS slot (row, cb') holds global chunk cb'^(row&15); fragment reads use the
// same XOR so behavior matches the previous swizzled layout.
// MODE 0: f32 out + bias + relu (Cf); optional fused modal gate (mw != null).
// MODE 3: bf16 out + bias + relu (Cb); optional fused attn logits (pvg != null).
// MODE 2: bf16 in-place: Cb = bf16(elu(0.25*acc + bias)) + Cb_old; optional logits.
template<int MODE>
__device__ __forceinline__ void gemm_core(
    const unsigned short* __restrict__ Ab, int lda, int c0,
    const unsigned short* __restrict__ Bt,
    const float* __restrict__ bias,
    float* __restrict__ Cf, unsigned short* __restrict__ Cb, int ldc,
    int M, int K, int m0, int n0,
    const float* __restrict__ pvg, float* __restrict__ als, float* __restrict__ ald,
    const unsigned short* __restrict__ mhv, const unsigned short* __restrict__ mht,
    const float* __restrict__ mw, const float* __restrict__ mb,
    float* __restrict__ out1) {
  __shared__ unsigned short sAB[64 * 128 + 128 * 128];  // As(16KB) | Bs(32KB)
  unsigned short* As = sAB;
  unsigned short* Bs = sAB + 64 * 128;

  int t = threadIdx.x;
  int w = t >> 6, l = t & 63;
  int wr = w >> 1, wc = w & 1;
  int lr = l & 15, lhi = l >> 4;

  // staging descriptors (per-thread constant across K-steps)
  const unsigned short* agp[4];
  unsigned short* alp[4];
  #pragma unroll
  for (int i = 0; i < 4; ++i) {
    int slot = (w * 4 + i) * 64 + l;        // chunk index in A tile [0,1024)
    int row = slot >> 4, cbp = slot & 15;
    int cb = cbp ^ (row & 15);
    int gm = m0 + row; if (gm > M - 1) gm = M - 1;
    agp[i] = Ab + (size_t)gm * lda + c0 + cb * 8;
    alp[i] = As + (w * 4 + i) * 512;        // wave-uniform LDS base (1KB)
  }
  const unsigned short* bgp[8];
  unsigned short* blp[8];
  #pragma unroll
  for (int i = 0; i < 8; ++i) {
    int slot = (w * 8 + i) * 64 + l;        // chunk index in B tile [0,2048)
    int row = slot >> 4, cbp = slot & 15;
    int cb = cbp ^ (row & 15);
    bgp[i] = Bt + (size_t)(n0 + row) * K + cb * 8;
    blp[i] = Bs + (w * 8 + i) * 512;
  }

  f32x4 acc[2][4];
  #pragma unroll
  for (int i = 0; i < 2; ++i)
    #pragma unroll
    for (int j = 0; j < 4; ++j) acc[i][j] = (f32x4){0.f, 0.f, 0.f, 0.f};

  for (int k0 = 0; k0 < K; k0 += 128) {
    #pragma unroll
    for (int i = 0; i < 4; ++i) gload16(agp[i] + k0, alp[i]);
    #pragma unroll
    for (int i = 0; i < 8; ++i) gload16(bgp[i] + k0, blp[i]);
    __syncthreads();   // drains vmcnt -> LDS writes complete
    #pragma unroll
    for (int kk = 0; kk < 4; ++kk) {
      short8 af[2], bfr[4];
      int cbf = lhi + kk * 4;
      #pragma unroll
      for (int i = 0; i < 2; ++i) {
        int row = wr * 32 + i * 16 + lr;
        af[i] = *(const short8*)&As[row * 128 + ((cbf ^ (row & 15)) << 3)];
      }
      #pragma unroll
      for (int j = 0; j < 4; ++j) {
        int nn = wc * 64 + j * 16 + lr;
        bfr[j] = *(const short8*)&Bs[nn * 128 + ((cbf ^ (nn & 15)) << 3)];
      }
      #pragma unroll
      for (int i = 0; i < 2; ++i)
        #pragma unroll
        for (int j = 0; j < 4; ++j)
          acc[i][j] = __builtin_amdgcn_mfma_f32_16x16x32_bf16(af[i], bfr[j], acc[i][j], 0, 0, 0);
    }
    __syncthreads();
  }

  if (MODE == 0) {
    float* Ctf = (float*)sAB;   // [64][128] f32
    #pragma unroll
    for (int i = 0; i < 2; ++i)
      #pragma unroll
      for (int j = 0; j < 4; ++j) {
        int col = wc * 64 + j * 16 + lr;
        float bsv = bias[col];
        #pragma unroll
        for (int rr = 0; rr < 4; ++rr) {
          int row = wr * 32 + i * 16 + lhi * 4 + rr;
          Ctf[row * 128 + col] = fmaxf(acc[i][j][rr] + bsv, 0.f);
        }
      }
    __syncthreads();
    float mb0 = mw ? mb[0] : 0.f;
    #pragma unroll
    for (int p = 0; p < 8; ++p) {
      int ci = (p << 8) + t;
      int row = ci >> 5, ch = ci & 31;
      int gr = m0 + row;
      int cg = gr < M ? gr : M - 1;
      float4 v = *(const float4*)&Ctf[row * 128 + (ch << 2)];
      if (gr < M) ((float4*)(Cf + (size_t)gr * ldc))[ch] = v;
      if (mw) {
        uint2 a2 = *(const uint2*)&mhv[(size_t)cg * 128 + (ch << 2)];
        uint2 b2 = *(const uint2*)&mht[(size_t)cg * 128 + (ch << 2)];
        float4 wv = ((const float4*)mw)[ch];
        float4 wt = ((const float4*)(mw + 128))[ch];
        float a0 = b2f((unsigned short)(a2.x & 0xffff)), a1 = b2f((unsigned short)(a2.x >> 16));
        float a2f = b2f((unsigned short)(a2.y & 0xffff)), a3 = b2f((unsigned short)(a2.y >> 16));
        float b0 = b2f((unsigned short)(b2.x & 0xffff)), b1 = b2f((unsigned short)(b2.x >> 16));
        float b2v = b2f((unsigned short)(b2.y & 0xffff)), b3 = b2f((unsigned short)(b2.y >> 16));
        float ps = a0 * wv.x + a1 * wv.y + a2f * wv.z + a3 * wv.w
                 + b0 * wt.x + b1 * wt.y + b2v * wt.z + b3 * wt.w;
        #pragma unroll
        for (int off = 1; off < 32; off <<= 1) ps += __shfl_xor(ps, off);
        float beta = 1.f / (1.f + __expf(-(ps + mb0)));
        float4 o;
        o.x = beta * a0 + (1.f - beta) * b0;
        o.y = beta * a1 + (1.f - beta) * b1;
        o.z = beta * a2f + (1.f - beta) * b2v;
        o.w = beta * a3 + (1.f - beta) * b3;
        if (gr < M) ((float4*)(out1 + (size_t)gr * 128))[ch] = o;
      }
    }
  } else {
    unsigned short* Ct = sAB;   // [64][128] bf16 (16 KB)
    float* pvL = (float*)(sAB + 8192);  // 4 KB at byte 16K (dead Bs region)
    #pragma unroll
    for (int i = 0; i < 2; ++i)
      #pragma unroll
      for (int j = 0; j < 4; ++j) {
        int col = wc * 64 + j * 16 + lr;
        float bsv = bias[col];
        #pragma unroll
        for (int rr = 0; rr < 4; ++rr) {
          int row = wr * 32 + i * 16 + lhi * 4 + rr;
          float v;
          if (MODE == 3) {
            v = fmaxf(acc[i][j][rr] + bsv, 0.f);
          } else {
            v = 0.25f * acc[i][j][rr] + bsv;
            v = v > 0.f ? v : __expf(v) - 1.f;
          }
          Ct[row * 128 + col] = f2b(v);
        }
      }
    __syncthreads();
    if (pvg) ((float4*)pvL)[t] = ((const float4*)pvg)[t];   // 1024 floats
    __syncthreads();
    #pragma unroll
    for (int p = 0; p < 4; ++p) {
      int ci = (p << 8) + t;
      int row = ci >> 4, ch = ci & 15;
      int gr = m0 + row;
      int cg = gr < M ? gr : M - 1;
      uint4 cv = *(const uint4*)&Ct[row * 128 + (ch << 3)];
      uint4* gptr = (uint4*)(Cb + (size_t)cg * ldc) + ch;
      if (MODE == 2) {
        uint4 hv = *gptr;
        cv.x = addbf2(cv.x, hv.x); cv.y = addbf2(cv.y, hv.y);
        cv.z = addbf2(cv.z, hv.z); cv.w = addbf2(cv.w, hv.w);
      }
      if (gr < M) *gptr = cv;
      if (pvg) {
        float v0 = b2f((unsigned short)(cv.x & 0xffff)), v1 = b2f((unsigned short)(cv.x >> 16));
        float v2 = b2f((unsigned short)(cv.y & 0xffff)), v3 = b2f((unsigned short)(cv.y >> 16));
        float v4 = b2f((unsigned short)(cv.z & 0xffff)), v5 = b2f((unsigned short)(cv.z >> 16));
        float v6 = b2f((unsigned short)(cv.w & 0xffff)), v7 = b2f((unsigned short)(cv.w >> 16));
        float s0, s1, s2, s3, s4, s5, s6, s7;
        {
          const float4* pr;
          pr = (const float4*)&pvL[0 * 128 + (ch << 3)];
          s0 = v0*pr[0].x + v1*pr[0].y + v2*pr[0].z + v3*pr[0].w + v4*pr[1].x + v5*pr[1].y + v6*pr[1].z + v7*pr[1].w;
          pr = (const float4*)&pvL[1 * 128 + (ch << 3)];
          s1 = v0*pr[0].x + v1*pr[0].y + v2*pr[0].z + v3*pr[0].w + v4*pr[1].x + v5*pr[1].y + v6*pr[1].z + v7*pr[1].w;
          pr = (const float4*)&pvL[2 * 128 + (ch << 3)];
          s2 = v0*pr[0].x + v1*pr[0].y + v2*pr[0].z + v3*pr[0].w + v4*pr[1].x + v5*pr[1].y + v6*pr[1].z + v7*pr[1].w;
          pr = (const float4*)&pvL[3 * 128 + (ch << 3)];
          s3 = v0*pr[0].x + v1*pr[0].y + v2*pr[0].z + v3*pr[0].w + v4*pr[1].x + v5*pr[1].y + v6*pr[1].z + v7*pr[1].w;
          pr = (const float4*)&pvL[4 * 128 + (ch << 3)];
          s4 = v0*pr[0].x + v1*pr[0].y + v2*pr[0].z + v3*pr[0].w + v4*pr[1].x + v5*pr[1].y + v6*pr[1].z + v7*pr[1].w;
          pr = (const float4*)&pvL[5 * 128 + (ch << 3)];
          s5 = v0*pr[0].x + v1*pr[0].y + v2*pr[0].z + v3*pr[0].w + v4*pr[1].x + v5*pr[1].y + v6*pr[1].z + v7*pr[1].w;
          pr = (const float4*)&pvL[6 * 128 + (ch << 3)];
          s6 = v0*pr[0].x + v1*pr[0].y + v2*pr[0].z + v3*pr[0].w + v4*pr[1].x + v5*pr[1].y + v6*pr[1].z + v7*pr[1].w;
          pr = (const float4*)&pvL[7 * 128 + (ch << 3)];
          s7 = v0*pr[0].x + v1*pr[0].y + v2*pr[0].z + v3*pr[0].w + v4*pr[1].x + v5*pr[1].y + v6*pr[1].z + v7*pr[1].w;
        }
        #pragma unroll
        for (int off = 1; off < 16; off <<= 1) {
          s0 += __shfl_xor(s0, off); s1 += __shfl_xor(s1, off);
          s2 += __shfl_xor(s2, off); s3 += __shfl_xor(s3, off);
          s4 += __shfl_xor(s4, off); s5 += __shfl_xor(s5, off);
          s6 += __shfl_xor(s6, off); s7 += __shfl_xor(s7, off);
        }
        if ((t & 15) == 0 && gr < M) {
          als[gr * 4 + 0] = s0; als[gr * 4 + 1] = s1;
          als[gr * 4 + 2] = s2; als[gr * 4 + 3] = s3;
          ald[gr * 4 + 0] = s4; ald[gr * 4 + 1] = s5;
          ald[gr * 4 + 2] = s6; ald[gr * 4 + 3] = s7;
        }
      }
    }
  }
}

// projections + fused L0 logits: y = modality; A = xb (bf16)
__global__ __launch_bounds__(256) void k_proj(
    const unsigned short* __restrict__ xb,
    const unsigned short* __restrict__ btv, const unsigned short* __restrict__ btt,
    const float* __restrict__ vb, const float* __restrict__ tb,
    unsigned short* __restrict__ hbv, unsigned short* __restrict__ hbt,
    const float* __restrict__ pvec,
    float* __restrict__ alsv, float* __restrict__ aldv,
    float* __restrict__ alst, float* __restrict__ aldt) {
  int m0 = blockIdx.x * 64;
  int mod = blockIdx.y;
  int c0, K;
  const unsigned short* Bt;
  const float* bias;
  unsigned short* Cb;
  if (mod == 0) { c0 = 0;   K = 768; Bt = btv; bias = vb; Cb = hbv; }
  else          { c0 = 768; K = 384; Bt = btt; bias = tb; Cb = hbt; }
  gemm_core<3>(xb, 1152, c0, Bt, bias, nullptr, Cb, 128, N_NODES, K, m0, 0,
               pvec + (size_t)mod * 1024,
               mod ? alst : alsv, mod ? aldt : aldv,
               nullptr, nullptr, nullptr, nullptr, nullptr);
}

// ---------------- GAT aggregation ----------------
struct AggArgs {
  const unsigned short* hb[2];
  const float* als[2];
  const float* ald[2];
  unsigned short* agg[2];
};
__global__ __launch_bounds__(128) void k_agg(AggArgs ag,
                                             const int* __restrict__ row_ptr,
                                             const int* __restrict__ edge_src) {
  int b = blockIdx.x;
  int mod = b >= N_NODES;
  int node = b - mod * N_NODES;
  const unsigned short* __restrict__ hbm = ag.hb[mod];
  const float* __restrict__ als = ag.als[mod];
  const float* __restrict__ ald = ag.ald[mod];
  unsigned short* __restrict__ arow_ = ag.agg[mod] + (size_t)node * 512;

  int tid = threadIdx.x;
  __shared__ float sp[128][4];
  __shared__ int   ssrc[128];
  __shared__ float sredm[8], sreds[8];
  __shared__ float soutC[2][4][128];
  __shared__ float red[4 * 128];
  int begin = row_ptr[node], end = row_ptr[node + 1];
  int deg = end - begin;
  float4 ad4 = *(const float4*)(ald + (size_t)node * 4);
  int wv = tid >> 6;

  if (deg <= 128) {
    float e0 = -1e30f, e1 = -1e30f, e2 = -1e30f, e3 = -1e30f;
    if (tid < deg) {
      int s = edge_src[begin + tid];
      ssrc[tid] = s;
      float4 a4 = *(const float4*)(als + (size_t)s * 4);
      e0 = lrelu(a4.x + ad4.x); e1 = lrelu(a4.y + ad4.y);
      e2 = lrelu(a4.z + ad4.z); e3 = lrelu(a4.w + ad4.w);
    }
    float m0 = e0, m1 = e1, m2 = e2, m3 = e3;
    for (int off = 32; off > 0; off >>= 1) {
      m0 = fmaxf(m0, __shfl_xor(m0, off));
      m1 = fmaxf(m1, __shfl_xor(m1, off));
      m2 = fmaxf(m2, __shfl_xor(m2, off));
      m3 = fmaxf(m3, __shfl_xor(m3, off));
    }
    if ((tid & 63) == 0) {
      sredm[wv * 4 + 0] = m0; sredm[wv * 4 + 1] = m1;
      sredm[wv * 4 + 2] = m2; sredm[wv * 4 + 3] = m3;
    }
    __syncthreads();
    m0 = fmaxf(sredm[0], sredm[4]); m1 = fmaxf(sredm[1], sredm[5]);
    m2 = fmaxf(sredm[2], sredm[6]); m3 = fmaxf(sredm[3], sredm[7]);
    float p0 = 0.f, p1 = 0.f, p2 = 0.f, p3 = 0.f;
    if (tid < deg) {
      p0 = __expf(e0 - m0); p1 = __expf(e1 - m1);
      p2 = __expf(e2 - m2); p3 = __expf(e3 - m3);
    }
    *(float4*)&sp[tid][0] = make_float4(p0, p1, p2, p3);
    float s0 = p0, s1 = p1, s2 = p2, s3 = p3;
    for (int off = 32; off > 0; off >>= 1) {
      s0 += __shfl_xor(s0, off); s1 += __shfl_xor(s1, off);
      s2 += __shfl_xor(s2, off); s3 += __shfl_xor(s3, off);
    }
    if ((tid & 63) == 0) {
      sreds[wv * 4 + 0] = s0; sreds[wv * 4 + 1] = s1;
      sreds[wv * 4 + 2] = s2; sreds[wv * 4 + 3] = s3;
    }
    __syncthreads();
    float inv0 = 1.f / (sreds[0] + sreds[4] + 1e-16f);
    float inv1 = 1.f / (sreds[1] + sreds[5] + 1e-16f);
    float inv2 = 1.f / (sreds[2] + sreds[6] + 1e-16f);
    float inv3 = 1.f / (sreds[3] + sreds[7] + 1e-16f);

    int lane = tid & 63;
    int c2 = lane << 1;
    const unsigned short* hb0 = hbm + c2;
    float a00 = 0.f, a01 = 0.f, a10 = 0.f, a11 = 0.f;
    float a20 = 0.f, a21 = 0.f, a30 = 0.f, a31 = 0.f;
    for (int k = wv; k < deg; k += 2) {
      int s = ssrc[k];
      float4 pk = *(const float4*)&sp[k][0];
      unsigned xv = *(const unsigned*)(hb0 + (size_t)s * 128);
      float x0 = b2f((unsigned short)(xv & 0xffff));
      float x1 = b2f((unsigned short)(xv >> 16));
      a00 += pk.x * x0; a01 += pk.x * x1;
      a10 += pk.y * x0; a11 += pk.y * x1;
      a20 += pk.z * x0; a21 += pk.z * x1;
      a30 += pk.w * x0; a31 += pk.w * x1;
    }
    *(float2*)&soutC[wv][0][c2] = make_float2(a00, a01);
    *(float2*)&soutC[wv][1][c2] = make_float2(a10, a11);
    *(float2*)&soutC[wv][2][c2] = make_float2(a20, a21);
    *(float2*)&soutC[wv][3][c2] = make_float2(a30, a31);
    __syncthreads();
    arow_[0 * 128 + tid] = f2b((soutC[0][0][tid] + soutC[1][0][tid]) * inv0);
    arow_[1 * 128 + tid] = f2b((soutC[0][1][tid] + soutC[1][1][tid]) * inv1);
    arow_[2 * 128 + tid] = f2b((soutC[0][2][tid] + soutC[1][2][tid]) * inv2);
    arow_[3 * 128 + tid] = f2b((soutC[0][3][tid] + soutC[1][3][tid]) * inv3);
    return;
  }

  // generic fallback (deg > 128)
  float lm0 = -1e30f, lm1 = -1e30f, lm2 = -1e30f, lm3 = -1e30f;
  for (int idx = begin + tid; idx < end; idx += 128) {
    int s = edge_src[idx];
    float4 a4 = *(const float4*)(als + (size_t)s * 4);
    lm0 = fmaxf(lm0, lrelu(a4.x + ad4.x));
    lm1 = fmaxf(lm1, lrelu(a4.y + ad4.y));
    lm2 = fmaxf(lm2, lrelu(a4.z + ad4.z));
    lm3 = fmaxf(lm3, lrelu(a4.w + ad4.w));
  }
  red[tid] = lm0; red[128 + tid] = lm1; red[256 + tid] = lm2; red[384 + tid] = lm3;
  __syncthreads();
  for (int off = 64; off > 0; off >>= 1) {
    if (tid < off) {
      red[tid]       = fmaxf(red[tid],       red[tid + off]);
      red[128 + tid] = fmaxf(red[128 + tid], red[128 + tid + off]);
      red[256 + tid] = fmaxf(red[256 + tid], red[256 + tid + off]);
      red[384 + tid] = fmaxf(red[384 + tid], red[384 + tid + off]);
    }
    __syncthreads();
  }
  float m0 = red[0], m1 = red[128], m2 = red[256], m3 = red[384];
  __syncthreads();
  float ls0 = 0.f, ls1 = 0.f, ls2 = 0.f, ls3 = 0.f;
  for (int idx = begin + tid; idx < end; idx += 128) {
    int s = edge_src[idx];
    float4 a4 = *(const float4*)(als + (size_t)s * 4);
    ls0 += __expf(lrelu(a4.x + ad4.x) - m0);
    ls1 += __expf(lrelu(a4.y + ad4.y) - m1);
    ls2 += __expf(lrelu(a4.z + ad4.z) - m2);
    ls3 += __expf(lrelu(a4.w + ad4.w) - m3);
  }
  red[tid] = ls0; red[128 + tid] = ls1; red[256 + tid] = ls2; red[384 + tid] = ls3;
  __syncthreads();
  for (int off = 64; off > 0; off >>= 1) {
    if (tid < off) {
      red[tid]       += red[tid + off];
      red[128 + tid] += red[128 + tid + off];
      red[256 + tid] += red[256 + tid + off];
      red[384 + tid] += red[384 + tid + off];
    }
    __syncthreads();
  }
  float inv0 = 1.f / (red[0]   + 1e-16f);
  float inv1 = 1.f / (red[128] + 1e-16f);
  float inv2 = 1.f / (red[256] + 1e-16f);
  float inv3 = 1.f / (red[384] + 1e-16f);
  float acc0 = 0.f, acc1 = 0.f, acc2 = 0.f, acc3 = 0.f;
  for (int idx = begin; idx < end; ++idx) {
    int s = edge_src[idx];
    float4 a4 = *(const float4*)(als + (size_t)s * 4);
    float al0 = __expf(lrelu(a4.x + ad4.x) - m0) * inv0;
    float al1 = __expf(lrelu(a4.y + ad4.y) - m1) * inv1;
    float al2 = __expf(lrelu(a4.z + ad4.z) - m2) * inv2;
    float al3 = __expf(lrelu(a4.w + ad4.w) - m3) * inv3;
    float xc = b2f(hbm[(size_t)s * 128 + tid]);
    acc0 += al0 * xc; acc1 += al1 * xc; acc2 += al2 * xc; acc3 += al3 * xc;
  }
  arow_[0 * 128 + tid] = f2b(acc0);
  arow_[1 * 128 + tid] = f2b(acc1);
  arow_[2 * 128 + tid] = f2b(acc2);
  arow_[3 * 128 + tid] = f2b(acc3);
}

// out-transform + residual + optional fused next-layer logits
struct OutArgs {
  const unsigned short* agg[2];
  const unsigned short* btg[2];
  const float* bias[2];
  unsigned short* hb[2];
  const float* pv[2];
  float* als[2];
  float* ald[2];
};
__global__ __launch_bounds__(256) void k_out(OutArgs oa) {
  int m0 = blockIdx.x * 64;
  int mod = blockIdx.y;
  gemm_core<2>(oa.agg[mod], 512, 0, oa.btg[mod], oa.bias[mod],
               nullptr, oa.hb[mod], 128, N_NODES, 512, m0, 0,
               oa.pv[mod], oa.als[mod], oa.ald[mod],
               nullptr, nullptr, nullptr, nullptr, nullptr);
}

// head GEMMs + fused modal (y=0 computes final_emb too)
__global__ __launch_bounds__(256) void k_head(
    const unsigned short* __restrict__ hbv, const unsigned short* __restrict__ hbt,
    const unsigned short* __restrict__ btvh, const unsigned short* __restrict__ btth,
    const float* __restrict__ vhb, const float* __restrict__ thb,
    const float* __restrict__ mw, const float* __restrict__ mb,
    float* __restrict__ out) {
  int m0 = blockIdx.x * 64;
  if (blockIdx.y == 0) {
    gemm_core<0>(hbv, 128, 0, btvh, vhb, out + 2560000, nullptr, 128,
                 N_NODES, 128, m0, 0,
                 nullptr, nullptr, nullptr, hbv, hbt, mw, mb, out);
  } else {
    gemm_core<0>(hbt, 128, 0, btth, thb, out + 5120000, nullptr, 128,
                 N_NODES, 128, m0, 0,
                 nullptr, nullptr, nullptr, nullptr, nullptr, nullptr, nullptr, nullptr);
  }
}

extern "C" void kernel_launch(void* const* d_in, const int* in_sizes, int n_in,
                              void* d_out, int out_size, void* d_ws, size_t ws_size,
                              hipStream_t stream) {
  const float* x    = (const float*)d_in[0];
  const int*   ei   = (const int*)d_in[1];
  const float* vpw  = (const float*)d_in[2];
  const float* vpb  = (const float*)d_in[3];
  const float* tpw  = (const float*)d_in[4];
  const float* tpb  = (const float*)d_in[5];
  const float* vgw  = (const float*)d_in[6];
  const float* vgas = (const float*)d_in[7];
  const float* vgad = (const float*)d_in[8];
  const float* vgb  = (const float*)d_in[9];
  const float* tgw  = (const float*)d_in[10];
  const float* tgas = (const float*)d_in[11];
  const float* tgad = (const float*)d_in[12];
  const float* tgb  = (const float*)d_in[13];
  const float* mw   = (const float*)d_in[14];
  const float* mb   = (const float*)d_in[15];
  const float* vhw  = (const float*)d_in[16];
  const float* vhb  = (const float*)d_in[17];
  const float* thw  = (const float*)d_in[18];
  const float* thb  = (const float*)d_in[19];
  float* out = (float*)d_out;

  char* ws = (char*)d_ws;
  float*          als_v    = (float*)(ws);                         //    320,000
  float*          ald_v    = (float*)(ws + 320000);                //    320,000
  float*          als_t    = (float*)(ws + 640000);                //    320,000
  float*          ald_t    = (float*)(ws + 960000);                //    320,000
  int*            row_ptr  = (int*)  (ws + 1280000);               //     80,016
  int*            deg      = (int*)  (ws + 1360016);               //     80,000
  int*            edge_src = (int*)  (ws + 1440016);               //  1,360,000
  unsigned short* bt       = (unsigned short*)(ws + 2800016);      //    884,736
  float*          pvec     = (float*)(ws + 3684752);               //     16,384
  unsigned short* hb_v     = (unsigned short*)(ws + 3701136);      //  5,120,000
  unsigned short* hb_t     = (unsigned short*)(ws + 8821136);      //  5,120,000
  // xb (46,080,000) time-shares with agg_v+agg_t (2 x 20,480,000):
  // xb dead after k_proj; agg written by k_agg afterwards.
  unsigned short* xb       = (unsigned short*)(ws + 13941136);
  unsigned short* agg_v    = (unsigned short*)(ws + 13941136);
  unsigned short* agg_t    = (unsigned short*)(ws + 34421136);

  unsigned short* bt_vp = bt;            // [128][768]
  unsigned short* bt_tp = bt + 98304;    // [128][384]
  unsigned short* bt_vh = bt + 147456;   // [128][128]
  unsigned short* bt_th = bt + 163840;   // [128][128]
  unsigned short* bt_og = bt + 180224;   // 4 x [128][512] (mod*2+L)

  hipMemsetAsync(deg, 0, N_NODES * sizeof(int), stream);

  k_xcvt<<<2048, 256, 0, stream>>>(x, xb);

  PrepArgs pa;
  pa.vpw = vpw; pa.tpw = tpw; pa.vhw = vhw; pa.thw = thw;
  pa.vgw = vgw; pa.tgw = tgw;
  pa.vgas = vgas; pa.vgad = vgad; pa.tgas = tgas; pa.tgad = tgad;
  pa.bt_vp = bt_vp; pa.bt_tp = bt_tp; pa.bt_vh = bt_vh; pa.bt_th = bt_th;
  pa.bt_og = bt_og; pa.pvec = pvec;
  k_prep<<<1744, 256, 0, stream>>>(pa);

  k_hist<<<(N_EDGES + 255) / 256, 256, 0, stream>>>(ei, deg);
  k_scan<<<1, 1024, 0, stream>>>(deg, row_ptr);
  k_scatter<<<(E_TOT + 255) / 256, 256, 0, stream>>>(ei, row_ptr, deg, edge_src);

  // projections + L0 logits (A = xb bf16, via global_load_lds)
  k_proj<<<dim3(MT64, 2), 256, 0, stream>>>(xb, bt_vp, bt_tp, vpb, tpb, hb_v, hb_t,
                                            pvec, als_v, ald_v, als_t, ald_t);

  // GAT layers
  for (int L = 0; L < 2; ++L) {
    AggArgs ag;
    ag.hb[0] = hb_v;   ag.hb[1] = hb_t;
    ag.als[0] = als_v; ag.als[1] = als_t;
    ag.ald[0] = ald_v; ag.ald[1] = ald_t;
    ag.agg[0] = agg_v; ag.agg[1] = agg_t;
    k_agg<<<2 * N_NODES, 128, 0, stream>>>(ag, row_ptr, edge_src);

    OutArgs oa;
    oa.agg[0] = agg_v; oa.agg[1] = agg_t;
    oa.btg[0] = bt_og + (size_t)(0 * 2 + L) * 65536;
    oa.btg[1] = bt_og + (size_t)(1 * 2 + L) * 65536;
    oa.bias[0] = vgb + L * HID;
    oa.bias[1] = tgb + L * HID;
    oa.hb[0] = hb_v;  oa.hb[1] = hb_t;
    if (L == 0) {
      oa.pv[0] = pvec + 2 * 1024;
      oa.pv[1] = pvec + 3 * 1024;
    } else {
      oa.pv[0] = nullptr; oa.pv[1] = nullptr;
    }
    oa.als[0] = als_v; oa.als[1] = als_t;
    oa.ald[0] = ald_v; oa.ald[1] = ald_t;
    k_out<<<dim3(MT64, 2), 256, 0, stream>>>(oa);
  }

  // head GEMMs + fused modal
  k_head<<<dim3(MT64, 2), 256, 0, stream>>>(hb_v, hb_t, bt_vh, bt_th, vhb, thb,
                                            mw, mb, out);
}

// Round 16
// 263.701 us; speedup vs baseline: 1.7338x; 1.2445x over previous
//
#include <hip/hip_runtime.h>
#include <math.h>

#define N_NODES 20000
#define N_EDGES 320000
#define E_TOT   (N_EDGES + N_NODES)
#define HID     128
#define NEG_SLOPE 0.2f
#define MT64    313   // ceil(20000/64)

typedef __attribute__((ext_vector_type(8))) short short8;
typedef __attribute__((ext_vector_type(4))) float f32x4;

__device__ __forceinline__ unsigned short f2b(float f) {
  unsigned u = __builtin_bit_cast(unsigned, f);
  return (unsigned short)((u + 0x7fffu + ((u >> 16) & 1u)) >> 16);
}
__device__ __forceinline__ float b2f(unsigned short h) {
  unsigned u = ((unsigned)h) << 16;
  return __builtin_bit_cast(float, u);
}
__device__ __forceinline__ unsigned pk2(float a, float b) {
  return (unsigned)f2b(a) | ((unsigned)f2b(b) << 16);
}
__device__ __forceinline__ unsigned addbf2(unsigned a, unsigned b) {
  float lo = b2f((unsigned short)(a & 0xffff)) + b2f((unsigned short)(b & 0xffff));
  float hi = b2f((unsigned short)(a >> 16)) + b2f((unsigned short)(b >> 16));
  return (unsigned)f2b(lo) | ((unsigned)f2b(hi) << 16);
}
__device__ __forceinline__ float lrelu(float x) { return x > 0.f ? x : NEG_SLOPE * x; }

// async global->LDS, 16B per lane; dst is wave-uniform base, src per-lane.
__device__ __forceinline__ void gload16(const unsigned short* g, unsigned short* l) {
  __builtin_amdgcn_global_load_lds(
      (const __attribute__((address_space(1))) unsigned int*)(const void*)g,
      (__attribute__((address_space(3))) unsigned int*)(void*)l,
      16, 0, 0);
}

// ---------------- x -> bf16 conversion (streaming) ----------------
__global__ void k_xcvt(const float* __restrict__ x, unsigned short* __restrict__ xb) {
  const int TOT = N_NODES * 1152 / 8;   // 2,880,000 groups of 8
  for (int i = blockIdx.x * blockDim.x + threadIdx.x; i < TOT;
       i += gridDim.x * blockDim.x) {
    float4 v0 = ((const float4*)x)[i * 2];
    float4 v1 = ((const float4*)x)[i * 2 + 1];
    uint4 o;
    o.x = pk2(v0.x, v0.y); o.y = pk2(v0.z, v0.w);
    o.z = pk2(v1.x, v1.y); o.w = pk2(v1.z, v1.w);
    ((uint4*)xb)[i] = o;
  }
}

// ---------------- merged prep: weight transposes + out-weights + pvec ----------------
struct PrepArgs {
  const float* vpw; const float* tpw; const float* vhw; const float* thw;
  const float* vgw; const float* tgw;
  const float* vgas; const float* vgad; const float* tgas; const float* tgad;
  unsigned short* bt_vp; unsigned short* bt_tp;
  unsigned short* bt_vh; unsigned short* bt_th;
  unsigned short* bt_og; float* pvec;
};
// blocks [0,704): 4 transpose jobs; [704,1728): og; [1728,1744): pvec
__global__ void k_prep(PrepArgs pa) {
  int b = blockIdx.x, t = threadIdx.x;
  if (b < 704) {
    const float* src; unsigned short* dst; int K, N, base;
    if (b < 384)      { src = pa.vpw; dst = pa.bt_vp; K = 768; N = 128; base = 0; }
    else if (b < 576) { src = pa.tpw; dst = pa.bt_tp; K = 384; N = 128; base = 384; }
    else if (b < 640) { src = pa.vhw; dst = pa.bt_vh; K = 128; N = 128; base = 576; }
    else              { src = pa.thw; dst = pa.bt_th; K = 128; N = 128; base = 640; }
    int idx = (b - base) * 256 + t;
    if (idx < N * K) {
      int n = idx / K, k = idx - n * K;
      dst[idx] = f2b(src[(size_t)k * N + n]);
    }
  } else if (b < 1728) {
    int bo = b - 704;
    int seg = bo >> 8;                  // mod*2 + L
    int mod = seg >> 1, L = seg & 1;
    const float* W = (mod ? pa.tgw : pa.vgw) + (size_t)L * 65536;
    int idx = (bo & 255) * 256 + t;     // 0..65535
    int out_ch = idx >> 9;
    int rem = idx & 511;
    int h = rem >> 7, kin = rem & 127;
    pa.bt_og[(size_t)seg * 65536 + idx] = f2b(W[(size_t)kin * 512 + h * 128 + out_ch]);
  } else {
    int idx = (b - 1728) * 256 + t;     // 0..4095
    int c = idx & 127, sd = (idx >> 7) & 1, lmh = idx >> 8;
    int L = lmh >> 3, mod = (lmh >> 2) & 1, h = lmh & 3;
    const float* W = (mod ? pa.tgw : pa.vgw) + (size_t)L * 65536;
    const float* a = (mod ? (sd ? pa.tgad : pa.tgas) : (sd ? pa.vgad : pa.vgas)) + L * 512 + h * 128;
    const float* wr = W + (size_t)c * 512 + h * 128;
    float s = 0.f;
    #pragma unroll 8
    for (int k = 0; k < 128; ++k) s += wr[k] * a[k];
    pa.pvec[(size_t)(((L * 2 + mod) * 2 + sd) * 4 + h) * 128 + c] = s;
  }
}

// ---------------- CSR build ----------------
__global__ void k_hist(const int* __restrict__ ei, int* __restrict__ deg) {
  int e = blockIdx.x * blockDim.x + threadIdx.x;
  if (e < N_EDGES) atomicAdd(&deg[ei[N_EDGES + e]], 1);
}

__global__ __launch_bounds__(1024) void k_scan(int* __restrict__ deg,
                                               int* __restrict__ row_ptr) {
  __shared__ int sums[1024];
  int t = threadIdx.x;
  const int CH = 20;
  int begin = t * CH;
  int end = begin + CH; if (end > N_NODES) end = N_NODES;
  int loc = 0;
  for (int i = begin; i < end; ++i) loc += deg[i] + 1;
  sums[t] = loc;
  __syncthreads();
  for (int off = 1; off < 1024; off <<= 1) {
    int v = (t >= off) ? sums[t - off] : 0;
    __syncthreads();
    sums[t] += v;
    __syncthreads();
  }
  int run = (t > 0) ? sums[t - 1] : 0;
  for (int i = begin; i < end; ++i) {
    int d = deg[i] + 1;
    row_ptr[i] = run;
    run += d;
    deg[i] = 0;      // becomes the scatter cursor
  }
  if (t == 1023) row_ptr[N_NODES] = sums[1023];
}

__global__ void k_scatter(const int* __restrict__ ei, const int* __restrict__ row_ptr,
                          int* __restrict__ cursor, int* __restrict__ edge_src) {
  int t = blockIdx.x * blockDim.x + threadIdx.x;
  if (t < N_EDGES) {
    int s = ei[t], d = ei[N_EDGES + t];
    int pos = row_ptr[d] + atomicAdd(&cursor[d], 1);
    edge_src[pos] = s;
  } else if (t < E_TOT) {
    int i = t - N_EDGES;
    int pos = row_ptr[i] + atomicAdd(&cursor[i], 1);
    edge_src[pos] = i;
  }
}

// ---------------- GEMM core: 64x128 tile, BK=128, 4 waves (2x2) ----------------
// A bf16 [M x lda]; staging via global_load_lds with pre-swizzled global source.
// MODE 0: f32 out + bias + relu (Cf); optional fused modal gate (mw != null).
// MODE 3: bf16 out + bias + relu (Cb); optional fused attn logits (pvg != null).
// MODE 2: bf16 in-place: Cb = bf16(elu(0.25*acc + bias)) + Cb_old; optional logits.
template<int MODE>
__device__ __forceinline__ void gemm_core(
    const unsigned short* __restrict__ Ab, int lda, int c0,
    const unsigned short* __restrict__ Bt,
    const float* __restrict__ bias,
    float* __restrict__ Cf, unsigned short* __restrict__ Cb, int ldc,
    int M, int K, int m0, int n0,
    const float* __restrict__ pvg, float* __restrict__ als, float* __restrict__ ald,
    const unsigned short* __restrict__ mhv, const unsigned short* __restrict__ mht,
    const float* __restrict__ mw, const float* __restrict__ mb,
    float* __restrict__ out1) {
  __shared__ unsigned short sAB[64 * 128 + 128 * 128];  // As(16KB) | Bs(32KB)
  unsigned short* As = sAB;
  unsigned short* Bs = sAB + 64 * 128;

  int t = threadIdx.x;
  int w = t >> 6, l = t & 63;
  int wr = w >> 1, wc = w & 1;
  int lr = l & 15, lhi = l >> 4;

  const unsigned short* agp[4];
  unsigned short* alp[4];
  #pragma unroll
  for (int i = 0; i < 4; ++i) {
    int slot = (w * 4 + i) * 64 + l;
    int row = slot >> 4, cbp = slot & 15;
    int cb = cbp ^ (row & 15);
    int gm = m0 + row; if (gm > M - 1) gm = M - 1;
    agp[i] = Ab + (size_t)gm * lda + c0 + cb * 8;
    alp[i] = As + (w * 4 + i) * 512;
  }
  const unsigned short* bgp[8];
  unsigned short* blp[8];
  #pragma unroll
  for (int i = 0; i < 8; ++i) {
    int slot = (w * 8 + i) * 64 + l;
    int row = slot >> 4, cbp = slot & 15;
    int cb = cbp ^ (row & 15);
    bgp[i] = Bt + (size_t)(n0 + row) * K + cb * 8;
    blp[i] = Bs + (w * 8 + i) * 512;
  }

  f32x4 acc[2][4];
  #pragma unroll
  for (int i = 0; i < 2; ++i)
    #pragma unroll
    for (int j = 0; j < 4; ++j) acc[i][j] = (f32x4){0.f, 0.f, 0.f, 0.f};

  for (int k0 = 0; k0 < K; k0 += 128) {
    #pragma unroll
    for (int i = 0; i < 4; ++i) gload16(agp[i] + k0, alp[i]);
    #pragma unroll
    for (int i = 0; i < 8; ++i) gload16(bgp[i] + k0, blp[i]);
    __syncthreads();
    #pragma unroll
    for (int kk = 0; kk < 4; ++kk) {
      short8 af[2], bfr[4];
      int cbf = lhi + kk * 4;
      #pragma unroll
      for (int i = 0; i < 2; ++i) {
        int row = wr * 32 + i * 16 + lr;
        af[i] = *(const short8*)&As[row * 128 + ((cbf ^ (row & 15)) << 3)];
      }
      #pragma unroll
      for (int j = 0; j < 4; ++j) {
        int nn = wc * 64 + j * 16 + lr;
        bfr[j] = *(const short8*)&Bs[nn * 128 + ((cbf ^ (nn & 15)) << 3)];
      }
      #pragma unroll
      for (int i = 0; i < 2; ++i)
        #pragma unroll
        for (int j = 0; j < 4; ++j)
          acc[i][j] = __builtin_amdgcn_mfma_f32_16x16x32_bf16(af[i], bfr[j], acc[i][j], 0, 0, 0);
    }
    __syncthreads();
  }

  if (MODE == 0) {
    float* Ctf = (float*)sAB;   // [64][128] f32
    #pragma unroll
    for (int i = 0; i < 2; ++i)
      #pragma unroll
      for (int j = 0; j < 4; ++j) {
        int col = wc * 64 + j * 16 + lr;
        float bsv = bias[col];
        #pragma unroll
        for (int rr = 0; rr < 4; ++rr) {
          int row = wr * 32 + i * 16 + lhi * 4 + rr;
          Ctf[row * 128 + col] = fmaxf(acc[i][j][rr] + bsv, 0.f);
        }
      }
    __syncthreads();
    float mb0 = mw ? mb[0] : 0.f;
    #pragma unroll
    for (int p = 0; p < 8; ++p) {
      int ci = (p << 8) + t;
      int row = ci >> 5, ch = ci & 31;
      int gr = m0 + row;
      int cg = gr < M ? gr : M - 1;
      float4 v = *(const float4*)&Ctf[row * 128 + (ch << 2)];
      if (gr < M) ((float4*)(Cf + (size_t)gr * ldc))[ch] = v;
      if (mw) {
        uint2 a2 = *(const uint2*)&mhv[(size_t)cg * 128 + (ch << 2)];
        uint2 b2 = *(const uint2*)&mht[(size_t)cg * 128 + (ch << 2)];
        float4 wv = ((const float4*)mw)[ch];
        float4 wt = ((const float4*)(mw + 128))[ch];
        float a0 = b2f((unsigned short)(a2.x & 0xffff)), a1 = b2f((unsigned short)(a2.x >> 16));
        float a2f = b2f((unsigned short)(a2.y & 0xffff)), a3 = b2f((unsigned short)(a2.y >> 16));
        float b0 = b2f((unsigned short)(b2.x & 0xffff)), b1 = b2f((unsigned short)(b2.x >> 16));
        float b2v = b2f((unsigned short)(b2.y & 0xffff)), b3 = b2f((unsigned short)(b2.y >> 16));
        float ps = a0 * wv.x + a1 * wv.y + a2f * wv.z + a3 * wv.w
                 + b0 * wt.x + b1 * wt.y + b2v * wt.z + b3 * wt.w;
        #pragma unroll
        for (int off = 1; off < 32; off <<= 1) ps += __shfl_xor(ps, off);
        float beta = 1.f / (1.f + __expf(-(ps + mb0)));
        float4 o;
        o.x = beta * a0 + (1.f - beta) * b0;
        o.y = beta * a1 + (1.f - beta) * b1;
        o.z = beta * a2f + (1.f - beta) * b2v;
        o.w = beta * a3 + (1.f - beta) * b3;
        if (gr < M) ((float4*)(out1 + (size_t)gr * 128))[ch] = o;
      }
    }
  } else {
    unsigned short* Ct = sAB;   // [64][128] bf16 (16 KB)
    float* pvL = (float*)(sAB + 8192);  // 4 KB, dead Bs region
    #pragma unroll
    for (int i = 0; i < 2; ++i)
      #pragma unroll
      for (int j = 0; j < 4; ++j) {
        int col = wc * 64 + j * 16 + lr;
        float bsv = bias[col];
        #pragma unroll
        for (int rr = 0; rr < 4; ++rr) {
          int row = wr * 32 + i * 16 + lhi * 4 + rr;
          float v;
          if (MODE == 3) {
            v = fmaxf(acc[i][j][rr] + bsv, 0.f);
          } else {
            v = 0.25f * acc[i][j][rr] + bsv;
            v = v > 0.f ? v : __expf(v) - 1.f;
          }
          Ct[row * 128 + col] = f2b(v);
        }
      }
    __syncthreads();
    if (pvg) ((float4*)pvL)[t] = ((const float4*)pvg)[t];   // 1024 floats
    __syncthreads();
    #pragma unroll
    for (int p = 0; p < 4; ++p) {
      int ci = (p << 8) + t;
      int row = ci >> 4, ch = ci & 15;
      int gr = m0 + row;
      int cg = gr < M ? gr : M - 1;
      uint4 cv = *(const uint4*)&Ct[row * 128 + (ch << 3)];
      uint4* gptr = (uint4*)(Cb + (size_t)cg * ldc) + ch;
      if (MODE == 2) {
        uint4 hv = *gptr;
        cv.x = addbf2(cv.x, hv.x); cv.y = addbf2(cv.y, hv.y);
        cv.z = addbf2(cv.z, hv.z); cv.w = addbf2(cv.w, hv.w);
      }
      if (gr < M) *gptr = cv;
      if (pvg) {
        float v0 = b2f((unsigned short)(cv.x & 0xffff)), v1 = b2f((unsigned short)(cv.x >> 16));
        float v2 = b2f((unsigned short)(cv.y & 0xffff)), v3 = b2f((unsigned short)(cv.y >> 16));
        float v4 = b2f((unsigned short)(cv.z & 0xffff)), v5 = b2f((unsigned short)(cv.z >> 16));
        float v6 = b2f((unsigned short)(cv.w & 0xffff)), v7 = b2f((unsigned short)(cv.w >> 16));
        float s0, s1, s2, s3, s4, s5, s6, s7;
        {
          const float4* pr;
          pr = (const float4*)&pvL[0 * 128 + (ch << 3)];
          s0 = v0*pr[0].x + v1*pr[0].y + v2*pr[0].z + v3*pr[0].w + v4*pr[1].x + v5*pr[1].y + v6*pr[1].z + v7*pr[1].w;
          pr = (const float4*)&pvL[1 * 128 + (ch << 3)];
          s1 = v0*pr[0].x + v1*pr[0].y + v2*pr[0].z + v3*pr[0].w + v4*pr[1].x + v5*pr[1].y + v6*pr[1].z + v7*pr[1].w;
          pr = (const float4*)&pvL[2 * 128 + (ch << 3)];
          s2 = v0*pr[0].x + v1*pr[0].y + v2*pr[0].z + v3*pr[0].w + v4*pr[1].x + v5*pr[1].y + v6*pr[1].z + v7*pr[1].w;
          pr = (const float4*)&pvL[3 * 128 + (ch << 3)];
          s3 = v0*pr[0].x + v1*pr[0].y + v2*pr[0].z + v3*pr[0].w + v4*pr[1].x + v5*pr[1].y + v6*pr[1].z + v7*pr[1].w;
          pr = (const float4*)&pvL[4 * 128 + (ch << 3)];
          s4 = v0*pr[0].x + v1*pr[0].y + v2*pr[0].z + v3*pr[0].w + v4*pr[1].x + v5*pr[1].y + v6*pr[1].z + v7*pr[1].w;
          pr = (const float4*)&pvL[5 * 128 + (ch << 3)];
          s5 = v0*pr[0].x + v1*pr[0].y + v2*pr[0].z + v3*pr[0].w + v4*pr[1].x + v5*pr[1].y + v6*pr[1].z + v7*pr[1].w;
          pr = (const float4*)&pvL[6 * 128 + (ch << 3)];
          s6 = v0*pr[0].x + v1*pr[0].y + v2*pr[0].z + v3*pr[0].w + v4*pr[1].x + v5*pr[1].y + v6*pr[1].z + v7*pr[1].w;
          pr = (const float4*)&pvL[7 * 128 + (ch << 3)];
          s7 = v0*pr[0].x + v1*pr[0].y + v2*pr[0].z + v3*pr[0].w + v4*pr[1].x + v5*pr[1].y + v6*pr[1].z + v7*pr[1].w;
        }
        #pragma unroll
        for (int off = 1; off < 16; off <<= 1) {
          s0 += __shfl_xor(s0, off); s1 += __shfl_xor(s1, off);
          s2 += __shfl_xor(s2, off); s3 += __shfl_xor(s3, off);
          s4 += __shfl_xor(s4, off); s5 += __shfl_xor(s5, off);
          s6 += __shfl_xor(s6, off); s7 += __shfl_xor(s7, off);
        }
        if ((t & 15) == 0 && gr < M) {
          als[gr * 4 + 0] = s0; als[gr * 4 + 1] = s1;
          als[gr * 4 + 2] = s2; als[gr * 4 + 3] = s3;
          ald[gr * 4 + 0] = s4; ald[gr * 4 + 1] = s5;
          ald[gr * 4 + 2] = s6; ald[gr * 4 + 3] = s7;
        }
      }
    }
  }
}

// projections + fused L0 logits: y = modality; A = xb (bf16)
__global__ __launch_bounds__(256) void k_proj(
    const unsigned short* __restrict__ xb,
    const unsigned short* __restrict__ btv, const unsigned short* __restrict__ btt,
    const float* __restrict__ vb, const float* __restrict__ tb,
    unsigned short* __restrict__ hbv, unsigned short* __restrict__ hbt,
    const float* __restrict__ pvec,
    float* __restrict__ alsv, float* __restrict__ aldv,
    float* __restrict__ alst, float* __restrict__ aldt) {
  int m0 = blockIdx.x * 64;
  int mod = blockIdx.y;
  int c0, K;
  const unsigned short* Bt;
  const float* bias;
  unsigned short* Cb;
  if (mod == 0) { c0 = 0;   K = 768; Bt = btv; bias = vb; Cb = hbv; }
  else          { c0 = 768; K = 384; Bt = btt; bias = tb; Cb = hbt; }
  gemm_core<3>(xb, 1152, c0, Bt, bias, nullptr, Cb, 128, N_NODES, K, m0, 0,
               pvec + (size_t)mod * 1024,
               mod ? alst : alsv, mod ? aldt : aldv,
               nullptr, nullptr, nullptr, nullptr, nullptr);
}

// ---------------- GAT aggregation: ONE WAVE per node ----------------
struct AggArgs {
  const unsigned short* hb[2];
  const float* als[2];
  const float* ald[2];
  unsigned short* agg[2];
};
__global__ __launch_bounds__(64) void k_agg(AggArgs ag,
                                            const int* __restrict__ row_ptr,
                                            const int* __restrict__ edge_src) {
  int b = blockIdx.x;
  int mod = b >= N_NODES;
  int node = b - mod * N_NODES;
  const unsigned short* __restrict__ hbm = ag.hb[mod];
  const float* __restrict__ als = ag.als[mod];
  const float* __restrict__ ald = ag.ald[mod];
  unsigned* __restrict__ arow_ = (unsigned*)(ag.agg[mod] + (size_t)node * 512);

  int lane = threadIdx.x;   // 0..63
  __shared__ float sp[128][4];
  __shared__ int   ssrc[128];
  int begin = row_ptr[node], end = row_ptr[node + 1];
  int deg = end - begin;
  float4 ad4 = *(const float4*)(ald + (size_t)node * 4);

  if (deg <= 128) {
    // up to 2 edges per lane (edge lane and lane+64)
    float eA0 = -1e30f, eA1 = -1e30f, eA2 = -1e30f, eA3 = -1e30f;
    float eB0 = -1e30f, eB1 = -1e30f, eB2 = -1e30f, eB3 = -1e30f;
    if (lane < deg) {
      int s = edge_src[begin + lane];
      ssrc[lane] = s;
      float4 a4 = *(const float4*)(als + (size_t)s * 4);
      eA0 = lrelu(a4.x + ad4.x); eA1 = lrelu(a4.y + ad4.y);
      eA2 = lrelu(a4.z + ad4.z); eA3 = lrelu(a4.w + ad4.w);
    }
    if (lane + 64 < deg) {
      int s = edge_src[begin + lane + 64];
      ssrc[lane + 64] = s;
      float4 a4 = *(const float4*)(als + (size_t)s * 4);
      eB0 = lrelu(a4.x + ad4.x); eB1 = lrelu(a4.y + ad4.y);
      eB2 = lrelu(a4.z + ad4.z); eB3 = lrelu(a4.w + ad4.w);
    }
    float m0 = fmaxf(eA0, eB0), m1 = fmaxf(eA1, eB1);
    float m2 = fmaxf(eA2, eB2), m3 = fmaxf(eA3, eB3);
    #pragma unroll
    for (int off = 32; off > 0; off >>= 1) {
      m0 = fmaxf(m0, __shfl_xor(m0, off));
      m1 = fmaxf(m1, __shfl_xor(m1, off));
      m2 = fmaxf(m2, __shfl_xor(m2, off));
      m3 = fmaxf(m3, __shfl_xor(m3, off));
    }
    float pA0 = 0.f, pA1 = 0.f, pA2 = 0.f, pA3 = 0.f;
    float pB0 = 0.f, pB1 = 0.f, pB2 = 0.f, pB3 = 0.f;
    if (lane < deg) {
      pA0 = __expf(eA0 - m0); pA1 = __expf(eA1 - m1);
      pA2 = __expf(eA2 - m2); pA3 = __expf(eA3 - m3);
      *(float4*)&sp[lane][0] = make_float4(pA0, pA1, pA2, pA3);
    }
    if (lane + 64 < deg) {
      pB0 = __expf(eB0 - m0); pB1 = __expf(eB1 - m1);
      pB2 = __expf(eB2 - m2); pB3 = __expf(eB3 - m3);
      *(float4*)&sp[lane + 64][0] = make_float4(pB0, pB1, pB2, pB3);
    }
    float s0 = pA0 + pB0, s1 = pA1 + pB1, s2 = pA2 + pB2, s3 = pA3 + pB3;
    #pragma unroll
    for (int off = 32; off > 0; off >>= 1) {
      s0 += __shfl_xor(s0, off); s1 += __shfl_xor(s1, off);
      s2 += __shfl_xor(s2, off); s3 += __shfl_xor(s3, off);
    }
    float inv0 = 1.f / (s0 + 1e-16f);
    float inv1 = 1.f / (s1 + 1e-16f);
    float inv2 = 1.f / (s2 + 1e-16f);
    float inv3 = 1.f / (s3 + 1e-16f);
    __syncthreads();   // sp/ssrc visible (single wave: cheap)

    // phase C: lane owns 2 channels (c2, c2+1), all 4 heads
    int c2 = lane << 1;
    const unsigned short* hb0 = hbm + c2;
    float a00 = 0.f, a01 = 0.f, a10 = 0.f, a11 = 0.f;
    float a20 = 0.f, a21 = 0.f, a30 = 0.f, a31 = 0.f;
    for (int k = 0; k < deg; ++k) {
      int s = ssrc[k];
      float4 pk = *(const float4*)&sp[k][0];
      unsigned xv = *(const unsigned*)(hb0 + (size_t)s * 128);
      float x0 = b2f((unsigned short)(xv & 0xffff));
      float x1 = b2f((unsigned short)(xv >> 16));
      a00 += pk.x * x0; a01 += pk.x * x1;
      a10 += pk.y * x0; a11 += pk.y * x1;
      a20 += pk.z * x0; a21 += pk.z * x1;
      a30 += pk.w * x0; a31 += pk.w * x1;
    }
    arow_[0 * 64 + lane] = pk2(a00 * inv0, a01 * inv0);
    arow_[1 * 64 + lane] = pk2(a10 * inv1, a11 * inv1);
    arow_[2 * 64 + lane] = pk2(a20 * inv2, a21 * inv2);
    arow_[3 * 64 + lane] = pk2(a30 * inv3, a31 * inv3);
    return;
  }

  // ---- generic fallback (deg > 128; statistically never) ----
  float lm0 = -1e30f, lm1 = -1e30f, lm2 = -1e30f, lm3 = -1e30f;
  for (int idx = begin + lane; idx < end; idx += 64) {
    int s = edge_src[idx];
    float4 a4 = *(const float4*)(als + (size_t)s * 4);
    lm0 = fmaxf(lm0, lrelu(a4.x + ad4.x));
    lm1 = fmaxf(lm1, lrelu(a4.y + ad4.y));
    lm2 = fmaxf(lm2, lrelu(a4.z + ad4.z));
    lm3 = fmaxf(lm3, lrelu(a4.w + ad4.w));
  }
  #pragma unroll
  for (int off = 32; off > 0; off >>= 1) {
    lm0 = fmaxf(lm0, __shfl_xor(lm0, off));
    lm1 = fmaxf(lm1, __shfl_xor(lm1, off));
    lm2 = fmaxf(lm2, __shfl_xor(lm2, off));
    lm3 = fmaxf(lm3, __shfl_xor(lm3, off));
  }
  float ls0 = 0.f, ls1 = 0.f, ls2 = 0.f, ls3 = 0.f;
  for (int idx = begin + lane; idx < end; idx += 64) {
    int s = edge_src[idx];
    float4 a4 = *(const float4*)(als + (size_t)s * 4);
    ls0 += __expf(lrelu(a4.x + ad4.x) - lm0);
    ls1 += __expf(lrelu(a4.y + ad4.y) - lm1);
    ls2 += __expf(lrelu(a4.z + ad4.z) - lm2);
    ls3 += __expf(lrelu(a4.w + ad4.w) - lm3);
  }
  #pragma unroll
  for (int off = 32; off > 0; off >>= 1) {
    ls0 += __shfl_xor(ls0, off); ls1 += __shfl_xor(ls1, off);
    ls2 += __shfl_xor(ls2, off); ls3 += __shfl_xor(ls3, off);
  }
  float inv0 = 1.f / (ls0 + 1e-16f);
  float inv1 = 1.f / (ls1 + 1e-16f);
  float inv2 = 1.f / (ls2 + 1e-16f);
  float inv3 = 1.f / (ls3 + 1e-16f);
  int c2 = lane << 1;
  const unsigned short* hb0 = hbm + c2;
  float a00 = 0.f, a01 = 0.f, a10 = 0.f, a11 = 0.f;
  float a20 = 0.f, a21 = 0.f, a30 = 0.f, a31 = 0.f;
  for (int idx = begin; idx < end; ++idx) {
    int s = edge_src[idx];
    float4 a4 = *(const float4*)(als + (size_t)s * 4);
    float al0 = __expf(lrelu(a4.x + ad4.x) - lm0);
    float al1 = __expf(lrelu(a4.y + ad4.y) - lm1);
    float al2 = __expf(lrelu(a4.z + ad4.z) - lm2);
    float al3 = __expf(lrelu(a4.w + ad4.w) - lm3);
    unsigned xv = *(const unsigned*)(hb0 + (size_t)s * 128);
    float x0 = b2f((unsigned short)(xv & 0xffff));
    float x1 = b2f((unsigned short)(xv >> 16));
    a00 += al0 * x0; a01 += al0 * x1;
    a10 += al1 * x0; a11 += al1 * x1;
    a20 += al2 * x0; a21 += al2 * x1;
    a30 += al3 * x0; a31 += al3 * x1;
  }
  arow_[0 * 64 + lane] = pk2(a00 * inv0, a01 * inv0);
  arow_[1 * 64 + lane] = pk2(a10 * inv1, a11 * inv1);
  arow_[2 * 64 + lane] = pk2(a20 * inv2, a21 * inv2);
  arow_[3 * 64 + lane] = pk2(a30 * inv3, a31 * inv3);
}

// out-transform + residual + optional fused next-layer logits
struct OutArgs {
  const unsigned short* agg[2];
  const unsigned short* btg[2];
  const float* bias[2];
  unsigned short* hb[2];
  const float* pv[2];
  float* als[2];
  float* ald[2];
};
__global__ __launch_bounds__(256) void k_out(OutArgs oa) {
  int m0 = blockIdx.x * 64;
  int mod = blockIdx.y;
  gemm_core<2>(oa.agg[mod], 512, 0, oa.btg[mod], oa.bias[mod],
               nullptr, oa.hb[mod], 128, N_NODES, 512, m0, 0,
               oa.pv[mod], oa.als[mod], oa.ald[mod],
               nullptr, nullptr, nullptr, nullptr, nullptr);
}

// head GEMMs + fused modal (y=0 computes final_emb too)
__global__ __launch_bounds__(256) void k_head(
    const unsigned short* __restrict__ hbv, const unsigned short* __restrict__ hbt,
    const unsigned short* __restrict__ btvh, const unsigned short* __restrict__ btth,
    const float* __restrict__ vhb, const float* __restrict__ thb,
    const float* __restrict__ mw, const float* __restrict__ mb,
    float* __restrict__ out) {
  int m0 = blockIdx.x * 64;
  if (blockIdx.y == 0) {
    gemm_core<0>(hbv, 128, 0, btvh, vhb, out + 2560000, nullptr, 128,
                 N_NODES, 128, m0, 0,
                 nullptr, nullptr, nullptr, hbv, hbt, mw, mb, out);
  } else {
    gemm_core<0>(hbt, 128, 0, btth, thb, out + 5120000, nullptr, 128,
                 N_NODES, 128, m0, 0,
                 nullptr, nullptr, nullptr, nullptr, nullptr, nullptr, nullptr, nullptr);
  }
}

extern "C" void kernel_launch(void* const* d_in, const int* in_sizes, int n_in,
                              void* d_out, int out_size, void* d_ws, size_t ws_size,
                              hipStream_t stream) {
  const float* x    = (const float*)d_in[0];
  const int*   ei   = (const int*)d_in[1];
  const float* vpw  = (const float*)d_in[2];
  const float* vpb  = (const float*)d_in[3];
  const float* tpw  = (const float*)d_in[4];
  const float* tpb  = (const float*)d_in[5];
  const float* vgw  = (const float*)d_in[6];
  const float* vgas = (const float*)d_in[7];
  const float* vgad = (const float*)d_in[8];
  const float* vgb  = (const float*)d_in[9];
  const float* tgw  = (const float*)d_in[10];
  const float* tgas = (const float*)d_in[11];
  const float* tgad = (const float*)d_in[12];
  const float* tgb  = (const float*)d_in[13];
  const float* mw   = (const float*)d_in[14];
  const float* mb   = (const float*)d_in[15];
  const float* vhw  = (const float*)d_in[16];
  const float* vhb  = (const float*)d_in[17];
  const float* thw  = (const float*)d_in[18];
  const float* thb  = (const float*)d_in[19];
  float* out = (float*)d_out;

  char* ws = (char*)d_ws;
  float*          als_v    = (float*)(ws);                         //    320,000
  float*          ald_v    = (float*)(ws + 320000);                //    320,000
  float*          als_t    = (float*)(ws + 640000);                //    320,000
  float*          ald_t    = (float*)(ws + 960000);                //    320,000
  int*            row_ptr  = (int*)  (ws + 1280000);               //     80,016
  int*            deg      = (int*)  (ws + 1360016);               //     80,000
  int*            edge_src = (int*)  (ws + 1440016);               //  1,360,000
  unsigned short* bt       = (unsigned short*)(ws + 2800016);      //    884,736
  float*          pvec     = (float*)(ws + 3684752);               //     16,384
  unsigned short* hb_v     = (unsigned short*)(ws + 3701136);      //  5,120,000
  unsigned short* hb_t     = (unsigned short*)(ws + 8821136);      //  5,120,000
  // xb (46,080,000) time-shares with agg_v+agg_t (2 x 20,480,000)
  unsigned short* xb       = (unsigned short*)(ws + 13941136);
  unsigned short* agg_v    = (unsigned short*)(ws + 13941136);
  unsigned short* agg_t    = (unsigned short*)(ws + 34421136);

  unsigned short* bt_vp = bt;            // [128][768]
  unsigned short* bt_tp = bt + 98304;    // [128][384]
  unsigned short* bt_vh = bt + 147456;   // [128][128]
  unsigned short* bt_th = bt + 163840;   // [128][128]
  unsigned short* bt_og = bt + 180224;   // 4 x [128][512] (mod*2+L)

  hipMemsetAsync(deg, 0, N_NODES * sizeof(int), stream);

  k_xcvt<<<2048, 256, 0, stream>>>(x, xb);

  PrepArgs pa;
  pa.vpw = vpw; pa.tpw = tpw; pa.vhw = vhw; pa.thw = thw;
  pa.vgw = vgw; pa.tgw = tgw;
  pa.vgas = vgas; pa.vgad = vgad; pa.tgas = tgas; pa.tgad = tgad;
  pa.bt_vp = bt_vp; pa.bt_tp = bt_tp; pa.bt_vh = bt_vh; pa.bt_th = bt_th;
  pa.bt_og = bt_og; pa.pvec = pvec;
  k_prep<<<1744, 256, 0, stream>>>(pa);

  k_hist<<<(N_EDGES + 255) / 256, 256, 0, stream>>>(ei, deg);
  k_scan<<<1, 1024, 0, stream>>>(deg, row_ptr);
  k_scatter<<<(E_TOT + 255) / 256, 256, 0, stream>>>(ei, row_ptr, deg, edge_src);

  // projections + L0 logits (A = xb bf16, via global_load_lds)
  k_proj<<<dim3(MT64, 2), 256, 0, stream>>>(xb, bt_vp, bt_tp, vpb, tpb, hb_v, hb_t,
                                            pvec, als_v, ald_v, als_t, ald_t);

  // GAT layers
  for (int L = 0; L < 2; ++L) {
    AggArgs ag;
    ag.hb[0] = hb_v;   ag.hb[1] = hb_t;
    ag.als[0] = als_v; ag.als[1] = als_t;
    ag.ald[0] = ald_v; ag.ald[1] = ald_t;
    ag.agg[0] = agg_v; ag.agg[1] = agg_t;
    k_agg<<<2 * N_NODES, 64, 0, stream>>>(ag, row_ptr, edge_src);

    OutArgs oa;
    oa.agg[0] = agg_v; oa.agg[1] = agg_t;
    oa.btg[0] = bt_og + (size_t)(0 * 2 + L) * 65536;
    oa.btg[1] = bt_og + (size_t)(1 * 2 + L) * 65536;
    oa.bias[0] = vgb + L * HID;
    oa.bias[1] = tgb + L * HID;
    oa.hb[0] = hb_v;  oa.hb[1] = hb_t;
    if (L == 0) {
      oa.pv[0] = pvec + 2 * 1024;
      oa.pv[1] = pvec + 3 * 1024;
    } else {
      oa.pv[0] = nullptr; oa.pv[1] = nullptr;
    }
    oa.als[0] = als_v; oa.als[1] = als_t;
    oa.ald[0] = ald_v; oa.ald[1] = ald_t;
    k_out<<<dim3(MT64, 2), 256, 0, stream>>>(oa);
  }

  // head GEMMs + fused modal
  k_head<<<dim3(MT64, 2), 256, 0, stream>>>(hb_v, hb_t, bt_vh, bt_th, vhb, thb,
                                            mw, mb, out);
}

// Round 18
// 258.597 us; speedup vs baseline: 1.7680x; 1.0197x over previous
//
#include <hip/hip_runtime.h>
#include <math.h>

#define N_NODES 20000
#define N_EDGES 320000
#define E_TOT   (N_EDGES + N_NODES)
#define HID     128
#define NEG_SLOPE 0.2f
#define MT64    313   // ceil(20000/64)

typedef __attribute__((ext_vector_type(8))) short short8;
typedef __attribute__((ext_vector_type(4))) float f32x4;

__device__ __forceinline__ unsigned short f2b(float f) {
  unsigned u = __builtin_bit_cast(unsigned, f);
  return (unsigned short)((u + 0x7fffu + ((u >> 16) & 1u)) >> 16);
}
__device__ __forceinline__ float b2f(unsigned short h) {
  unsigned u = ((unsigned)h) << 16;
  return __builtin_bit_cast(float, u);
}
__device__ __forceinline__ unsigned pk2(float a, float b) {
  return (unsigned)f2b(a) | ((unsigned)f2b(b) << 16);
}
__device__ __forceinline__ unsigned addbf2(unsigned a, unsigned b) {
  float lo = b2f((unsigned short)(a & 0xffff)) + b2f((unsigned short)(b & 0xffff));
  float hi = b2f((unsigned short)(a >> 16)) + b2f((unsigned short)(b >> 16));
  return (unsigned)f2b(lo) | ((unsigned)f2b(hi) << 16);
}
__device__ __forceinline__ float lrelu(float x) { return x > 0.f ? x : NEG_SLOPE * x; }

// async global->LDS, 16B per lane; dst is wave-uniform base, src per-lane.
__device__ __forceinline__ void gload16(const unsigned short* g, unsigned short* l) {
  __builtin_amdgcn_global_load_lds(
      (const __attribute__((address_space(1))) unsigned int*)(const void*)g,
      (__attribute__((address_space(3))) unsigned int*)(void*)l,
      16, 0, 0);
}

// ---------------- x -> bf16 conversion (streaming) ----------------
__global__ void k_xcvt(const float* __restrict__ x, unsigned short* __restrict__ xb) {
  const int TOT = N_NODES * 1152 / 8;   // 2,880,000 groups of 8
  for (int i = blockIdx.x * blockDim.x + threadIdx.x; i < TOT;
       i += gridDim.x * blockDim.x) {
    float4 v0 = ((const float4*)x)[i * 2];
    float4 v1 = ((const float4*)x)[i * 2 + 1];
    uint4 o;
    o.x = pk2(v0.x, v0.y); o.y = pk2(v0.z, v0.w);
    o.z = pk2(v1.x, v1.y); o.w = pk2(v1.z, v1.w);
    ((uint4*)xb)[i] = o;
  }
}

// ---------------- merged prep: weight transposes + out-weights + pvec + deg-zero ----------------
struct PrepArgs {
  const float* vpw; const float* tpw; const float* vhw; const float* thw;
  const float* vgw; const float* tgw;
  const float* vgas; const float* vgad; const float* tgas; const float* tgad;
  unsigned short* bt_vp; unsigned short* bt_tp;
  unsigned short* bt_vh; unsigned short* bt_th;
  unsigned short* bt_og; float* pvec;
  int* deg;
};
// blocks [0,704): 4 transpose jobs; [704,1728): og; [1728,1744): pvec; [1744,1823): deg=0
__global__ void k_prep(PrepArgs pa) {
  int b = blockIdx.x, t = threadIdx.x;
  if (b < 704) {
    const float* src; unsigned short* dst; int K, N, base;
    if (b < 384)      { src = pa.vpw; dst = pa.bt_vp; K = 768; N = 128; base = 0; }
    else if (b < 576) { src = pa.tpw; dst = pa.bt_tp; K = 384; N = 128; base = 384; }
    else if (b < 640) { src = pa.vhw; dst = pa.bt_vh; K = 128; N = 128; base = 576; }
    else              { src = pa.thw; dst = pa.bt_th; K = 128; N = 128; base = 640; }
    int idx = (b - base) * 256 + t;
    if (idx < N * K) {
      int n = idx / K, k = idx - n * K;
      dst[idx] = f2b(src[(size_t)k * N + n]);
    }
  } else if (b < 1728) {
    int bo = b - 704;
    int seg = bo >> 8;                  // mod*2 + L
    int mod = seg >> 1, L = seg & 1;
    const float* W = (mod ? pa.tgw : pa.vgw) + (size_t)L * 65536;
    int idx = (bo & 255) * 256 + t;     // 0..65535
    int out_ch = idx >> 9;
    int rem = idx & 511;
    int h = rem >> 7, kin = rem & 127;
    pa.bt_og[(size_t)seg * 65536 + idx] = f2b(W[(size_t)kin * 512 + h * 128 + out_ch]);
  } else if (b < 1744) {
    int idx = (b - 1728) * 256 + t;     // 0..4095
    int c = idx & 127, sd = (idx >> 7) & 1, lmh = idx >> 8;
    int L = lmh >> 3, mod = (lmh >> 2) & 1, h = lmh & 3;
    const float* W = (mod ? pa.tgw : pa.vgw) + (size_t)L * 65536;
    const float* a = (mod ? (sd ? pa.tgad : pa.tgas) : (sd ? pa.vgad : pa.vgas)) + L * 512 + h * 128;
    const float* wr = W + (size_t)c * 512 + h * 128;
    float s = 0.f;
    #pragma unroll 8
    for (int k = 0; k < 128; ++k) s += wr[k] * a[k];
    pa.pvec[(size_t)(((L * 2 + mod) * 2 + sd) * 4 + h) * 128 + c] = s;
  } else {
    int idx = (b - 1744) * 256 + t;     // 0..20223
    if (idx < N_NODES) pa.deg[idx] = 0;
  }
}

// ---------------- CSR build ----------------
__global__ void k_hist(const int* __restrict__ ei, int* __restrict__ deg) {
  int e = blockIdx.x * blockDim.x + threadIdx.x;
  if (e < N_EDGES) atomicAdd(&deg[ei[N_EDGES + e]], 1);
}

__global__ __launch_bounds__(1024) void k_scan(int* __restrict__ deg,
                                               int* __restrict__ row_ptr) {
  __shared__ int sums[1024];
  int t = threadIdx.x;
  const int CH = 20;
  int begin = t * CH;
  int end = begin + CH; if (end > N_NODES) end = N_NODES;
  int loc = 0;
  for (int i = begin; i < end; ++i) loc += deg[i] + 1;
  sums[t] = loc;
  __syncthreads();
  for (int off = 1; off < 1024; off <<= 1) {
    int v = (t >= off) ? sums[t - off] : 0;
    __syncthreads();
    sums[t] += v;
    __syncthreads();
  }
  int run = (t > 0) ? sums[t - 1] : 0;
  for (int i = begin; i < end; ++i) {
    int d = deg[i] + 1;
    row_ptr[i] = run;
    run += d;
    deg[i] = 0;      // becomes the scatter cursor
  }
  if (t == 1023) row_ptr[N_NODES] = sums[1023];
}

__global__ void k_scatter(const int* __restrict__ ei, const int* __restrict__ row_ptr,
                          int* __restrict__ cursor, int* __restrict__ edge_src) {
  int t = blockIdx.x * blockDim.x + threadIdx.x;
  if (t < N_EDGES) {
    int s = ei[t], d = ei[N_EDGES + t];
    int pos = row_ptr[d] + atomicAdd(&cursor[d], 1);
    edge_src[pos] = s;
  } else if (t < E_TOT) {
    int i = t - N_EDGES;
    int pos = row_ptr[i] + atomicAdd(&cursor[i], 1);
    edge_src[pos] = i;
  }
}

// ---------------- GEMM core: 64x128 tile, BK=128, 4 waves (2x2) ----------------
// A bf16 [M x lda]; staging via global_load_lds with pre-swizzled global source.
// MODE 0: f32 out + bias + relu (Cf); optional fused modal gate (mw != null).
// MODE 3: bf16 out + bias + relu (Cb); optional fused attn logits (pvg != null).
// MODE 2: bf16 in-place: Cb = bf16(elu(0.25*acc + bias)) + Cb_old; optional logits.
template<int MODE>
__device__ __forceinline__ void gemm_core(
    const unsigned short* __restrict__ Ab, int lda, int c0,
    const unsigned short* __restrict__ Bt,
    const float* __restrict__ bias,
    float* __restrict__ Cf, unsigned short* __restrict__ Cb, int ldc,
    int M, int K, int m0, int n0,
    const float* __restrict__ pvg, float* __restrict__ als, float* __restrict__ ald,
    const unsigned short* __restrict__ mhv, const unsigned short* __restrict__ mht,
    const float* __restrict__ mw, const float* __restrict__ mb,
    float* __restrict__ out1) {
  __shared__ unsigned short sAB[64 * 128 + 128 * 128];  // As(16KB) | Bs(32KB)
  unsigned short* As = sAB;
  unsigned short* Bs = sAB + 64 * 128;

  int t = threadIdx.x;
  int w = t >> 6, l = t & 63;
  int wr = w >> 1, wc = w & 1;
  int lr = l & 15, lhi = l >> 4;

  const unsigned short* agp[4];
  unsigned short* alp[4];
  #pragma unroll
  for (int i = 0; i < 4; ++i) {
    int slot = (w * 4 + i) * 64 + l;
    int row = slot >> 4, cbp = slot & 15;
    int cb = cbp ^ (row & 15);
    int gm = m0 + row; if (gm > M - 1) gm = M - 1;
    agp[i] = Ab + (size_t)gm * lda + c0 + cb * 8;
    alp[i] = As + (w * 4 + i) * 512;
  }
  const unsigned short* bgp[8];
  unsigned short* blp[8];
  #pragma unroll
  for (int i = 0; i < 8; ++i) {
    int slot = (w * 8 + i) * 64 + l;
    int row = slot >> 4, cbp = slot & 15;
    int cb = cbp ^ (row & 15);
    bgp[i] = Bt + (size_t)(n0 + row) * K + cb * 8;
    blp[i] = Bs + (w * 8 + i) * 512;
  }

  f32x4 acc[2][4];
  #pragma unroll
  for (int i = 0; i < 2; ++i)
    #pragma unroll
    for (int j = 0; j < 4; ++j) acc[i][j] = (f32x4){0.f, 0.f, 0.f, 0.f};

  for (int k0 = 0; k0 < K; k0 += 128) {
    #pragma unroll
    for (int i = 0; i < 4; ++i) gload16(agp[i] + k0, alp[i]);
    #pragma unroll
    for (int i = 0; i < 8; ++i) gload16(bgp[i] + k0, blp[i]);
    __syncthreads();
    #pragma unroll
    for (int kk = 0; kk < 4; ++kk) {
      short8 af[2], bfr[4];
      int cbf = lhi + kk * 4;
      #pragma unroll
      for (int i = 0; i < 2; ++i) {
        int row = wr * 32 + i * 16 + lr;
        af[i] = *(const short8*)&As[row * 128 + ((cbf ^ (row & 15)) << 3)];
      }
      #pragma unroll
      for (int j = 0; j < 4; ++j) {
        int nn = wc * 64 + j * 16 + lr;
        bfr[j] = *(const short8*)&Bs[nn * 128 + ((cbf ^ (nn & 15)) << 3)];
      }
      #pragma unroll
      for (int i = 0; i < 2; ++i)
        #pragma unroll
        for (int j = 0; j < 4; ++j)
          acc[i][j] = __builtin_amdgcn_mfma_f32_16x16x32_bf16(af[i], bfr[j], acc[i][j], 0, 0, 0);
    }
    __syncthreads();
  }

  if (MODE == 0) {
    float* Ctf = (float*)sAB;   // [64][128] f32
    #pragma unroll
    for (int i = 0; i < 2; ++i)
      #pragma unroll
      for (int j = 0; j < 4; ++j) {
        int col = wc * 64 + j * 16 + lr;
        float bsv = bias[col];
        #pragma unroll
        for (int rr = 0; rr < 4; ++rr) {
          int row = wr * 32 + i * 16 + lhi * 4 + rr;
          Ctf[row * 128 + col] = fmaxf(acc[i][j][rr] + bsv, 0.f);
        }
      }
    __syncthreads();
    float mb0 = mw ? mb[0] : 0.f;
    #pragma unroll
    for (int p = 0; p < 8; ++p) {
      int ci = (p << 8) + t;
      int row = ci >> 5, ch = ci & 31;
      int gr = m0 + row;
      int cg = gr < M ? gr : M - 1;
      float4 v = *(const float4*)&Ctf[row * 128 + (ch << 2)];
      if (gr < M) ((float4*)(Cf + (size_t)gr * ldc))[ch] = v;
      if (mw) {
        uint2 a2 = *(const uint2*)&mhv[(size_t)cg * 128 + (ch << 2)];
        uint2 b2 = *(const uint2*)&mht[(size_t)cg * 128 + (ch << 2)];
        float4 wv = ((const float4*)mw)[ch];
        float4 wt = ((const float4*)(mw + 128))[ch];
        float a0 = b2f((unsigned short)(a2.x & 0xffff)), a1 = b2f((unsigned short)(a2.x >> 16));
        float a2f = b2f((unsigned short)(a2.y & 0xffff)), a3 = b2f((unsigned short)(a2.y >> 16));
        float b0 = b2f((unsigned short)(b2.x & 0xffff)), b1 = b2f((unsigned short)(b2.x >> 16));
        float b2v = b2f((unsigned short)(b2.y & 0xffff)), b3 = b2f((unsigned short)(b2.y >> 16));
        float ps = a0 * wv.x + a1 * wv.y + a2f * wv.z + a3 * wv.w
                 + b0 * wt.x + b1 * wt.y + b2v * wt.z + b3 * wt.w;
        #pragma unroll
        for (int off = 1; off < 32; off <<= 1) ps += __shfl_xor(ps, off);
        float beta = 1.f / (1.f + __expf(-(ps + mb0)));
        float4 o;
        o.x = beta * a0 + (1.f - beta) * b0;
        o.y = beta * a1 + (1.f - beta) * b1;
        o.z = beta * a2f + (1.f - beta) * b2v;
        o.w = beta * a3 + (1.f - beta) * b3;
        if (gr < M) ((float4*)(out1 + (size_t)gr * 128))[ch] = o;
      }
    }
  } else {
    unsigned short* Ct = sAB;   // [64][128] bf16 (16 KB)
    float* pvL = (float*)(sAB + 8192);  // 4 KB, dead Bs region
    #pragma unroll
    for (int i = 0; i < 2; ++i)
      #pragma unroll
      for (int j = 0; j < 4; ++j) {
        int col = wc * 64 + j * 16 + lr;
        float bsv = bias[col];
        #pragma unroll
        for (int rr = 0; rr < 4; ++rr) {
          int row = wr * 32 + i * 16 + lhi * 4 + rr;
          float v;
          if (MODE == 3) {
            v = fmaxf(acc[i][j][rr] + bsv, 0.f);
          } else {
            v = 0.25f * acc[i][j][rr] + bsv;
            v = v > 0.f ? v : __expf(v) - 1.f;
          }
          Ct[row * 128 + col] = f2b(v);
        }
      }
    __syncthreads();
    if (pvg) ((float4*)pvL)[t] = ((const float4*)pvg)[t];   // 1024 floats
    __syncthreads();
    #pragma unroll
    for (int p = 0; p < 4; ++p) {
      int ci = (p << 8) + t;
      int row = ci >> 4, ch = ci & 15;
      int gr = m0 + row;
      int cg = gr < M ? gr : M - 1;
      uint4 cv = *(const uint4*)&Ct[row * 128 + (ch << 3)];
      uint4* gptr = (uint4*)(Cb + (size_t)cg * ldc) + ch;
      if (MODE == 2) {
        uint4 hv = *gptr;
        cv.x = addbf2(cv.x, hv.x); cv.y = addbf2(cv.y, hv.y);
        cv.z = addbf2(cv.z, hv.z); cv.w = addbf2(cv.w, hv.w);
      }
      if (gr < M) *gptr = cv;
      if (pvg) {
        float v0 = b2f((unsigned short)(cv.x & 0xffff)), v1 = b2f((unsigned short)(cv.x >> 16));
        float v2 = b2f((unsigned short)(cv.y & 0xffff)), v3 = b2f((unsigned short)(cv.y >> 16));
        float v4 = b2f((unsigned short)(cv.z & 0xffff)), v5 = b2f((unsigned short)(cv.z >> 16));
        float v6 = b2f((unsigned short)(cv.w & 0xffff)), v7 = b2f((unsigned short)(cv.w >> 16));
        float s0, s1, s2, s3, s4, s5, s6, s7;
        {
          const float4* pr;
          pr = (const float4*)&pvL[0 * 128 + (ch << 3)];
          s0 = v0*pr[0].x + v1*pr[0].y + v2*pr[0].z + v3*pr[0].w + v4*pr[1].x + v5*pr[1].y + v6*pr[1].z + v7*pr[1].w;
          pr = (const float4*)&pvL[1 * 128 + (ch << 3)];
          s1 = v0*pr[0].x + v1*pr[0].y + v2*pr[0].z + v3*pr[0].w + v4*pr[1].x + v5*pr[1].y + v6*pr[1].z + v7*pr[1].w;
          pr = (const float4*)&pvL[2 * 128 + (ch << 3)];
          s2 = v0*pr[0].x + v1*pr[0].y + v2*pr[0].z + v3*pr[0].w + v4*pr[1].x + v5*pr[1].y + v6*pr[1].z + v7*pr[1].w;
          pr = (const float4*)&pvL[3 * 128 + (ch << 3)];
          s3 = v0*pr[0].x + v1*pr[0].y + v2*pr[0].z + v3*pr[0].w + v4*pr[1].x + v5*pr[1].y + v6*pr[1].z + v7*pr[1].w;
          pr = (const float4*)&pvL[4 * 128 + (ch << 3)];
          s4 = v0*pr[0].x + v1*pr[0].y + v2*pr[0].z + v3*pr[0].w + v4*pr[1].x + v5*pr[1].y + v6*pr[1].z + v7*pr[1].w;
          pr = (const float4*)&pvL[5 * 128 + (ch << 3)];
          s5 = v0*pr[0].x + v1*pr[0].y + v2*pr[0].z + v3*pr[0].w + v4*pr[1].x + v5*pr[1].y + v6*pr[1].z + v7*pr[1].w;
          pr = (const float4*)&pvL[6 * 128 + (ch << 3)];
          s6 = v0*pr[0].x + v1*pr[0].y + v2*pr[0].z + v3*pr[0].w + v4*pr[1].x + v5*pr[1].y + v6*pr[1].z + v7*pr[1].w;
          pr = (const float4*)&pvL[7 * 128 + (ch << 3)];
          s7 = v0*pr[0].x + v1*pr[0].y + v2*pr[0].z + v3*pr[0].w + v4*pr[1].x + v5*pr[1].y + v6*pr[1].z + v7*pr[1].w;
        }
        #pragma unroll
        for (int off = 1; off < 16; off <<= 1) {
          s0 += __shfl_xor(s0, off); s1 += __shfl_xor(s1, off);
          s2 += __shfl_xor(s2, off); s3 += __shfl_xor(s3, off);
          s4 += __shfl_xor(s4, off); s5 += __shfl_xor(s5, off);
          s6 += __shfl_xor(s6, off); s7 += __shfl_xor(s7, off);
        }
        if ((t & 15) == 0 && gr < M) {
          als[gr * 4 + 0] = s0; als[gr * 4 + 1] = s1;
          als[gr * 4 + 2] = s2; als[gr * 4 + 3] = s3;
          ald[gr * 4 + 0] = s4; ald[gr * 4 + 1] = s5;
          ald[gr * 4 + 2] = s6; ald[gr * 4 + 3] = s7;
        }
      }
    }
  }
}

// projections + fused L0 logits: y = modality; A = xb (bf16)
__global__ __launch_bounds__(256) void k_proj(
    const unsigned short* __restrict__ xb,
    const unsigned short* __restrict__ btv, const unsigned short* __restrict__ btt,
    const float* __restrict__ vb, const float* __restrict__ tb,
    unsigned short* __restrict__ hbv, unsigned short* __restrict__ hbt,
    const float* __restrict__ pvec,
    float* __restrict__ alsv, float* __restrict__ aldv,
    float* __restrict__ alst, float* __restrict__ aldt) {
  int m0 = blockIdx.x * 64;
  int mod = blockIdx.y;
  int c0, K;
  const unsigned short* Bt;
  const float* bias;
  unsigned short* Cb;
  if (mod == 0) { c0 = 0;   K = 768; Bt = btv; bias = vb; Cb = hbv; }
  else          { c0 = 768; K = 384; Bt = btt; bias = tb; Cb = hbt; }
  gemm_core<3>(xb, 1152, c0, Bt, bias, nullptr, Cb, 128, N_NODES, K, m0, 0,
               pvec + (size_t)mod * 1024,
               mod ? alst : alsv, mod ? aldt : aldv,
               nullptr, nullptr, nullptr, nullptr, nullptr);
}

// ---------------- GAT aggregation: ONE WAVE per node ----------------
struct AggArgs {
  const unsigned short* hb[2];
  const float* als[2];
  const float* ald[2];
  unsigned short* agg[2];
};
__global__ __launch_bounds__(64) void k_agg(AggArgs ag,
                                            const int* __restrict__ row_ptr,
                                            const int* __restrict__ edge_src) {
  int b = blockIdx.x;
  int mod = b >= N_NODES;
  int node = b - mod * N_NODES;
  const unsigned short* __restrict__ hbm = ag.hb[mod];
  const float* __restrict__ als = ag.als[mod];
  const float* __restrict__ ald = ag.ald[mod];
  unsigned* __restrict__ arow_ = (unsigned*)(ag.agg[mod] + (size_t)node * 512);

  int lane = threadIdx.x;   // 0..63
  __shared__ float sp[128][4];
  __shared__ int   ssrc[128];
  int begin = row_ptr[node], end = row_ptr[node + 1];
  int deg = end - begin;
  float4 ad4 = *(const float4*)(ald + (size_t)node * 4);

  if (deg <= 128) {
    float eA0 = -1e30f, eA1 = -1e30f, eA2 = -1e30f, eA3 = -1e30f;
    float eB0 = -1e30f, eB1 = -1e30f, eB2 = -1e30f, eB3 = -1e30f;
    if (lane < deg) {
      int s = edge_src[begin + lane];
      ssrc[lane] = s;
      float4 a4 = *(const float4*)(als + (size_t)s * 4);
      eA0 = lrelu(a4.x + ad4.x); eA1 = lrelu(a4.y + ad4.y);
      eA2 = lrelu(a4.z + ad4.z); eA3 = lrelu(a4.w + ad4.w);
    }
    if (lane + 64 < deg) {
      int s = edge_src[begin + lane + 64];
      ssrc[lane + 64] = s;
      float4 a4 = *(const float4*)(als + (size_t)s * 4);
      eB0 = lrelu(a4.x + ad4.x); eB1 = lrelu(a4.y + ad4.y);
      eB2 = lrelu(a4.z + ad4.z); eB3 = lrelu(a4.w + ad4.w);
    }
    float m0 = fmaxf(eA0, eB0), m1 = fmaxf(eA1, eB1);
    float m2 = fmaxf(eA2, eB2), m3 = fmaxf(eA3, eB3);
    #pragma unroll
    for (int off = 32; off > 0; off >>= 1) {
      m0 = fmaxf(m0, __shfl_xor(m0, off));
      m1 = fmaxf(m1, __shfl_xor(m1, off));
      m2 = fmaxf(m2, __shfl_xor(m2, off));
      m3 = fmaxf(m3, __shfl_xor(m3, off));
    }
    float pA0 = 0.f, pA1 = 0.f, pA2 = 0.f, pA3 = 0.f;
    float pB0 = 0.f, pB1 = 0.f, pB2 = 0.f, pB3 = 0.f;
    if (lane < deg) {
      pA0 = __expf(eA0 - m0); pA1 = __expf(eA1 - m1);
      pA2 = __expf(eA2 - m2); pA3 = __expf(eA3 - m3);
      *(float4*)&sp[lane][0] = make_float4(pA0, pA1, pA2, pA3);
    }
    if (lane + 64 < deg) {
      pB0 = __expf(eB0 - m0); pB1 = __expf(eB1 - m1);
      pB2 = __expf(eB2 - m2); pB3 = __expf(eB3 - m3);
      *(float4*)&sp[lane + 64][0] = make_float4(pB0, pB1, pB2, pB3);
    }
    float s0 = pA0 + pB0, s1 = pA1 + pB1, s2 = pA2 + pB2, s3 = pA3 + pB3;
    #pragma unroll
    for (int off = 32; off > 0; off >>= 1) {
      s0 += __shfl_xor(s0, off); s1 += __shfl_xor(s1, off);
      s2 += __shfl_xor(s2, off); s3 += __shfl_xor(s3, off);
    }
    float inv0 = 1.f / (s0 + 1e-16f);
    float inv1 = 1.f / (s1 + 1e-16f);
    float inv2 = 1.f / (s2 + 1e-16f);
    float inv3 = 1.f / (s3 + 1e-16f);
    __syncthreads();

    int c2 = lane << 1;
    const unsigned short* hb0 = hbm + c2;
    float a00 = 0.f, a01 = 0.f, a10 = 0.f, a11 = 0.f;
    float a20 = 0.f, a21 = 0.f, a30 = 0.f, a31 = 0.f;
    for (int k = 0; k < deg; ++k) {
      int s = ssrc[k];
      float4 pk = *(const float4*)&sp[k][0];
      unsigned xv = *(const unsigned*)(hb0 + (size_t)s * 128);
      float x0 = b2f((unsigned short)(xv & 0xffff));
      float x1 = b2f((unsigned short)(xv >> 16));
      a00 += pk.x * x0; a01 += pk.x * x1;
      a10 += pk.y * x0; a11 += pk.y * x1;
      a20 += pk.z * x0; a21 += pk.z * x1;
      a30 += pk.w * x0; a31 += pk.w * x1;
    }
    arow_[0 * 64 + lane] = pk2(a00 * inv0, a01 * inv0);
    arow_[1 * 64 + lane] = pk2(a10 * inv1, a11 * inv1);
    arow_[2 * 64 + lane] = pk2(a20 * inv2, a21 * inv2);
    arow_[3 * 64 + lane] = pk2(a30 * inv3, a31 * inv3);
    return;
  }

  // ---- generic fallback (deg > 128; statistically never) ----
  float lm0 = -1e30f, lm1 = -1e30f, lm2 = -1e30f, lm3 = -1e30f;
  for (int idx = begin + lane; idx < end; idx += 64) {
    int s = edge_src[idx];
    float4 a4 = *(const float4*)(als + (size_t)s * 4);
    lm0 = fmaxf(lm0, lrelu(a4.x + ad4.x));
    lm1 = fmaxf(lm1, lrelu(a4.y + ad4.y));
    lm2 = fmaxf(lm2, lrelu(a4.z + ad4.z));
    lm3 = fmaxf(lm3, lrelu(a4.w + ad4.w));
  }
  #pragma unroll
  for (int off = 32; off > 0; off >>= 1) {
    lm0 = fmaxf(lm0, __shfl_xor(lm0, off));
    lm1 = fmaxf(lm1, __shfl_xor(lm1, off));
    lm2 = fmaxf(lm2, __shfl_xor(lm2, off));
    lm3 = fmaxf(lm3, __shfl_xor(lm3, off));
  }
  float ls0 = 0.f, ls1 = 0.f, ls2 = 0.f, ls3 = 0.f;
  for (int idx = begin + lane; idx < end; idx += 64) {
    int s = edge_src[idx];
    float4 a4 = *(const float4*)(als + (size_t)s * 4);
    ls0 += __expf(lrelu(a4.x + ad4.x) - lm0);
    ls1 += __expf(lrelu(a4.y + ad4.y) - lm1);
    ls2 += __expf(lrelu(a4.z + ad4.z) - lm2);
    ls3 += __expf(lrelu(a4.w + ad4.w) - lm3);
  }
  #pragma unroll
  for (int off = 32; off > 0; off >>= 1) {
    ls0 += __shfl_xor(ls0, off); ls1 += __shfl_xor(ls1, off);
    ls2 += __shfl_xor(ls2, off); ls3 += __shfl_xor(ls3, off);
  }
  float inv0 = 1.f / (ls0 + 1e-16f);
  float inv1 = 1.f / (ls1 + 1e-16f);
  float inv2 = 1.f / (ls2 + 1e-16f);
  float inv3 = 1.f / (ls3 + 1e-16f);
  int c2 = lane << 1;
  const unsigned short* hb0 = hbm + c2;
  float a00 = 0.f, a01 = 0.f, a10 = 0.f, a11 = 0.f;
  float a20 = 0.f, a21 = 0.f, a30 = 0.f, a31 = 0.f;
  for (int idx = begin; idx < end; ++idx) {
    int s = edge_src[idx];
    float4 a4 = *(const float4*)(als + (size_t)s * 4);
    float al0 = __expf(lrelu(a4.x + ad4.x) - lm0);
    float al1 = __expf(lrelu(a4.y + ad4.y) - lm1);
    float al2 = __expf(lrelu(a4.z + ad4.z) - lm2);
    float al3 = __expf(lrelu(a4.w + ad4.w) - lm3);
    unsigned xv = *(const unsigned*)(hb0 + (size_t)s * 128);
    float x0 = b2f((unsigned short)(xv & 0xffff));
    float x1 = b2f((unsigned short)(xv >> 16));
    a00 += al0 * x0; a01 += al0 * x1;
    a10 += al1 * x0; a11 += al1 * x1;
    a20 += al2 * x0; a21 += al2 * x1;
    a30 += al3 * x0; a31 += al3 * x1;
  }
  arow_[0 * 64 + lane] = pk2(a00 * inv0, a01 * inv0);
  arow_[1 * 64 + lane] = pk2(a10 * inv1, a11 * inv1);
  arow_[2 * 64 + lane] = pk2(a20 * inv2, a21 * inv2);
  arow_[3 * 64 + lane] = pk2(a30 * inv3, a31 * inv3);
}

// out-transform + residual + optional fused next-layer logits
struct OutArgs {
  const unsigned short* agg[2];
  const unsigned short* btg[2];
  const float* bias[2];
  unsigned short* hb[2];
  const float* pv[2];
  float* als[2];
  float* ald[2];
};
__global__ __launch_bounds__(256) void k_out(OutArgs oa) {
  int m0 = blockIdx.x * 64;
  int mod = blockIdx.y;
  gemm_core<2>(oa.agg[mod], 512, 0, oa.btg[mod], oa.bias[mod],
               nullptr, oa.hb[mod], 128, N_NODES, 512, m0, 0,
               oa.pv[mod], oa.als[mod], oa.ald[mod],
               nullptr, nullptr, nullptr, nullptr, nullptr);
}

// head GEMMs + fused modal (y=0 computes final_emb too)
__global__ __launch_bounds__(256) void k_head(
    const unsigned short* __restrict__ hbv, const unsigned short* __restrict__ hbt,
    const unsigned short* __restrict__ btvh, const unsigned short* __restrict__ btth,
    const float* __restrict__ vhb, const float* __restrict__ thb,
    const float* __restrict__ mw, const float* __restrict__ mb,
    float* __restrict__ out) {
  int m0 = blockIdx.x * 64;
  if (blockIdx.y == 0) {
    gemm_core<0>(hbv, 128, 0, btvh, vhb, out + 2560000, nullptr, 128,
                 N_NODES, 128, m0, 0,
                 nullptr, nullptr, nullptr, hbv, hbt, mw, mb, out);
  } else {
    gemm_core<0>(hbt, 128, 0, btth, thb, out + 5120000, nullptr, 128,
                 N_NODES, 128, m0, 0,
                 nullptr, nullptr, nullptr, nullptr, nullptr, nullptr, nullptr, nullptr);
  }
}

extern "C" void kernel_launch(void* const* d_in, const int* in_sizes, int n_in,
                              void* d_out, int out_size, void* d_ws, size_t ws_size,
                              hipStream_t stream) {
  const float* x    = (const float*)d_in[0];
  const int*   ei   = (const int*)d_in[1];
  const float* vpw  = (const float*)d_in[2];
  const float* vpb  = (const float*)d_in[3];
  const float* tpw  = (const float*)d_in[4];
  const float* tpb  = (const float*)d_in[5];
  const float* vgw  = (const float*)d_in[6];
  const float* vgas = (const float*)d_in[7];
  const float* vgad = (const float*)d_in[8];
  const float* vgb  = (const float*)d_in[9];
  const float* tgw  = (const float*)d_in[10];
  const float* tgas = (const float*)d_in[11];
  const float* tgad = (const float*)d_in[12];
  const float* tgb  = (const float*)d_in[13];
  const float* mw   = (const float*)d_in[14];
  const float* mb   = (const float*)d_in[15];
  const float* vhw  = (const float*)d_in[16];
  const float* vhb  = (const float*)d_in[17];
  const float* thw  = (const float*)d_in[18];
  const float* thb  = (const float*)d_in[19];
  float* out = (float*)d_out;

  char* ws = (char*)d_ws;
  float*          als_v    = (float*)(ws);                         //    320,000
  float*          ald_v    = (float*)(ws + 320000);                //    320,000
  float*          als_t    = (float*)(ws + 640000);                //    320,000
  float*          ald_t    = (float*)(ws + 960000);                //    320,000
  int*            row_ptr  = (int*)  (ws + 1280000);               //     80,016
  int*            deg      = (int*)  (ws + 1360016);               //     80,000
  int*            edge_src = (int*)  (ws + 1440016);               //  1,360,000
  unsigned short* bt       = (unsigned short*)(ws + 2800016);      //    884,736
  float*          pvec     = (float*)(ws + 3684752);               //     16,384
  unsigned short* hb_v     = (unsigned short*)(ws + 3701136);      //  5,120,000
  unsigned short* hb_t     = (unsigned short*)(ws + 8821136);      //  5,120,000
  // xb (46,080,000) time-shares with agg_v+agg_t (2 x 20,480,000)
  unsigned short* xb       = (unsigned short*)(ws + 13941136);
  unsigned short* agg_v    = (unsigned short*)(ws + 13941136);
  unsigned short* agg_t    = (unsigned short*)(ws + 34421136);

  unsigned short* bt_vp = bt;            // [128][768]
  unsigned short* bt_tp = bt + 98304;    // [128][384]
  unsigned short* bt_vh = bt + 147456;   // [128][128]
  unsigned short* bt_th = bt + 163840;   // [128][128]
  unsigned short* bt_og = bt + 180224;   // 4 x [128][512] (mod*2+L)

  k_xcvt<<<2048, 256, 0, stream>>>(x, xb);

  PrepArgs pa;
  pa.vpw = vpw; pa.tpw = tpw; pa.vhw = vhw; pa.thw = thw;
  pa.vgw = vgw; pa.tgw = tgw;
  pa.vgas = vgas; pa.vgad = vgad; pa.tgas = tgas; pa.tgad = tgad;
  pa.bt_vp = bt_vp; pa.bt_tp = bt_tp; pa.bt_vh = bt_vh; pa.bt_th = bt_th;
  pa.bt_og = bt_og; pa.pvec = pvec;
  pa.deg = deg;
  k_prep<<<1823, 256, 0, stream>>>(pa);

  k_hist<<<(N_EDGES + 255) / 256, 256, 0, stream>>>(ei, deg);
  k_scan<<<1, 1024, 0, stream>>>(deg, row_ptr);
  k_scatter<<<(E_TOT + 255) / 256, 256, 0, stream>>>(ei, row_ptr, deg, edge_src);

  // projections + L0 logits (A = xb bf16, via global_load_lds)
  k_proj<<<dim3(MT64, 2), 256, 0, stream>>>(xb, bt_vp, bt_tp, vpb, tpb, hb_v, hb_t,
                                            pvec, als_v, ald_v, als_t, ald_t);

  // GAT layers
  for (int L = 0; L < 2; ++L) {
    AggArgs ag;
    ag.hb[0] = hb_v;   ag.hb[1] = hb_t;
    ag.als[0] = als_v; ag.als[1] = als_t;
    ag.ald[0] = ald_v; ag.ald[1] = ald_t;
    ag.agg[0] = agg_v; ag.agg[1] = agg_t;
    k_agg<<<2 * N_NODES, 64, 0, stream>>>(ag, row_ptr, edge_src);

    OutArgs oa;
    oa.agg[0] = agg_v; oa.agg[1] = agg_t;
    oa.btg[0] = bt_og + (size_t)(0 * 2 + L) * 65536;
    oa.btg[1] = bt_og + (size_t)(1 * 2 + L) * 65536;
    oa.bias[0] = vgb + L * HID;
    oa.bias[1] = tgb + L * HID;
    oa.hb[0] = hb_v;  oa.hb[1] = hb_t;
    if (L == 0) {
      oa.pv[0] = pvec + 2 * 1024;
      oa.pv[1] = pvec + 3 * 1024;
    } else {
      oa.pv[0] = nullptr; oa.pv[1] = nullptr;
    }
    oa.als[0] = als_v; oa.als[1] = als_t;
    oa.ald[0] = ald_v; oa.ald[1] = ald_t;
    k_out<<<dim3(MT64, 2), 256, 0, stream>>>(oa);
  }

  // head GEMMs + fused modal
  k_head<<<dim3(MT64, 2), 256, 0, stream>>>(hb_v, hb_t, bt_vh, bt_th, vhb, thb,
                                            mw, mb, out);
}

// Round 19
// 255.590 us; speedup vs baseline: 1.7888x; 1.0118x over previous
//
#include <hip/hip_runtime.h>
#include <math.h>

#define N_NODES 20000
#define N_EDGES 320000
#define E_TOT   (N_EDGES + N_NODES)
#define HID     128
#define NEG_SLOPE 0.2f
#define MT64    313   // ceil(20000/64)

typedef __attribute__((ext_vector_type(8))) short short8;
typedef __attribute__((ext_vector_type(4))) float f32x4;

__device__ __forceinline__ unsigned short f2b(float f) {
  unsigned u = __builtin_bit_cast(unsigned, f);
  return (unsigned short)((u + 0x7fffu + ((u >> 16) & 1u)) >> 16);
}
__device__ __forceinline__ float b2f(unsigned short h) {
  unsigned u = ((unsigned)h) << 16;
  return __builtin_bit_cast(float, u);
}
__device__ __forceinline__ unsigned pk2(float a, float b) {
  return (unsigned)f2b(a) | ((unsigned)f2b(b) << 16);
}
__device__ __forceinline__ unsigned addbf2(unsigned a, unsigned b) {
  float lo = b2f((unsigned short)(a & 0xffff)) + b2f((unsigned short)(b & 0xffff));
  float hi = b2f((unsigned short)(a >> 16)) + b2f((unsigned short)(b >> 16));
  return (unsigned)f2b(lo) | ((unsigned)f2b(hi) << 16);
}
__device__ __forceinline__ float lrelu(float x) { return x > 0.f ? x : NEG_SLOPE * x; }

// async global->LDS, 16B per lane; dst is wave-uniform base, src per-lane.
__device__ __forceinline__ void gload16(const unsigned short* g, unsigned short* l) {
  __builtin_amdgcn_global_load_lds(
      (const __attribute__((address_space(1))) unsigned int*)(const void*)g,
      (__attribute__((address_space(3))) unsigned int*)(void*)l,
      16, 0, 0);
}

// ---------------- merged prep: weight transposes + out-weights + pvec + deg-zero + x->bf16 ----------------
struct PrepArgs {
  const float* vpw; const float* tpw; const float* vhw; const float* thw;
  const float* vgw; const float* tgw;
  const float* vgas; const float* vgad; const float* tgas; const float* tgad;
  unsigned short* bt_vp; unsigned short* bt_tp;
  unsigned short* bt_vh; unsigned short* bt_th;
  unsigned short* bt_og; float* pvec;
  int* deg;
  const float* x; unsigned short* xb;
};
// blocks [0,704): 4 transpose jobs; [704,1728): og; [1728,1744): pvec;
// [1744,1823): deg=0; [1823,3871): x->bf16 grid-stride (2048 blocks)
__global__ void k_prep(PrepArgs pa) {
  int b = blockIdx.x, t = threadIdx.x;
  if (b < 704) {
    const float* src; unsigned short* dst; int K, N, base;
    if (b < 384)      { src = pa.vpw; dst = pa.bt_vp; K = 768; N = 128; base = 0; }
    else if (b < 576) { src = pa.tpw; dst = pa.bt_tp; K = 384; N = 128; base = 384; }
    else if (b < 640) { src = pa.vhw; dst = pa.bt_vh; K = 128; N = 128; base = 576; }
    else              { src = pa.thw; dst = pa.bt_th; K = 128; N = 128; base = 640; }
    int idx = (b - base) * 256 + t;
    if (idx < N * K) {
      int n = idx / K, k = idx - n * K;
      dst[idx] = f2b(src[(size_t)k * N + n]);
    }
  } else if (b < 1728) {
    int bo = b - 704;
    int seg = bo >> 8;                  // mod*2 + L
    int mod = seg >> 1, L = seg & 1;
    const float* W = (mod ? pa.tgw : pa.vgw) + (size_t)L * 65536;
    int idx = (bo & 255) * 256 + t;     // 0..65535
    int out_ch = idx >> 9;
    int rem = idx & 511;
    int h = rem >> 7, kin = rem & 127;
    pa.bt_og[(size_t)seg * 65536 + idx] = f2b(W[(size_t)kin * 512 + h * 128 + out_ch]);
  } else if (b < 1744) {
    int idx = (b - 1728) * 256 + t;     // 0..4095
    int c = idx & 127, sd = (idx >> 7) & 1, lmh = idx >> 8;
    int L = lmh >> 3, mod = (lmh >> 2) & 1, h = lmh & 3;
    const float* W = (mod ? pa.tgw : pa.vgw) + (size_t)L * 65536;
    const float* a = (mod ? (sd ? pa.tgad : pa.tgas) : (sd ? pa.vgad : pa.vgas)) + L * 512 + h * 128;
    const float* wr = W + (size_t)c * 512 + h * 128;
    float s = 0.f;
    #pragma unroll 8
    for (int k = 0; k < 128; ++k) s += wr[k] * a[k];
    pa.pvec[(size_t)(((L * 2 + mod) * 2 + sd) * 4 + h) * 128 + c] = s;
  } else if (b < 1823) {
    int idx = (b - 1744) * 256 + t;     // 0..20223
    if (idx < N_NODES) pa.deg[idx] = 0;
  } else {
    const int TOT = N_NODES * 1152 / 8;   // 2,880,000 groups of 8
    for (int i = (b - 1823) * 256 + t; i < TOT; i += 2048 * 256) {
      float4 v0 = ((const float4*)pa.x)[i * 2];
      float4 v1 = ((const float4*)pa.x)[i * 2 + 1];
      uint4 o;
      o.x = pk2(v0.x, v0.y); o.y = pk2(v0.z, v0.w);
      o.z = pk2(v1.x, v1.y); o.w = pk2(v1.z, v1.w);
      ((uint4*)pa.xb)[i] = o;
    }
  }
}

// ---------------- CSR build ----------------
__global__ void k_hist(const int* __restrict__ ei, int* __restrict__ deg) {
  int e = blockIdx.x * blockDim.x + threadIdx.x;
  if (e < N_EDGES) atomicAdd(&deg[ei[N_EDGES + e]], 1);
}

__global__ __launch_bounds__(1024) void k_scan(int* __restrict__ deg,
                                               int* __restrict__ row_ptr) {
  __shared__ int sums[1024];
  int t = threadIdx.x;
  const int CH = 20;
  int begin = t * CH;
  int end = begin + CH; if (end > N_NODES) end = N_NODES;
  int loc = 0;
  for (int i = begin; i < end; ++i) loc += deg[i] + 1;
  sums[t] = loc;
  __syncthreads();
  for (int off = 1; off < 1024; off <<= 1) {
    int v = (t >= off) ? sums[t - off] : 0;
    __syncthreads();
    sums[t] += v;
    __syncthreads();
  }
  int run = (t > 0) ? sums[t - 1] : 0;
  for (int i = begin; i < end; ++i) {
    int d = deg[i] + 1;
    row_ptr[i] = run;
    run += d;
    deg[i] = 0;      // becomes the scatter cursor
  }
  if (t == 1023) row_ptr[N_NODES] = sums[1023];
}

__global__ void k_scatter(const int* __restrict__ ei, const int* __restrict__ row_ptr,
                          int* __restrict__ cursor, int* __restrict__ edge_src) {
  int t = blockIdx.x * blockDim.x + threadIdx.x;
  if (t < N_EDGES) {
    int s = ei[t], d = ei[N_EDGES + t];
    int pos = row_ptr[d] + atomicAdd(&cursor[d], 1);
    edge_src[pos] = s;
  } else if (t < E_TOT) {
    int i = t - N_EDGES;
    int pos = row_ptr[i] + atomicAdd(&cursor[i], 1);
    edge_src[pos] = i;
  }
}

// ---------------- GEMM core: 64x128 tile, BK=128, 4 waves (2x2) ----------------
// A bf16 [M x lda]; staging via global_load_lds with pre-swizzled global source.
// MODE 0: f32 out + bias + relu (Cf); optional fused modal gate (mw != null).
// MODE 3: bf16 out + bias + relu (Cb); optional fused attn logits (pvg != null).
// MODE 2: bf16 in-place: Cb = bf16(elu(0.25*acc + bias)) + Cb_old; optional logits.
template<int MODE>
__device__ __forceinline__ void gemm_core(
    const unsigned short* __restrict__ Ab, int lda, int c0,
    const unsigned short* __restrict__ Bt,
    const float* __restrict__ bias,
    float* __restrict__ Cf, unsigned short* __restrict__ Cb, int ldc,
    int M, int K, int m0, int n0,
    const float* __restrict__ pvg, float* __restrict__ als, float* __restrict__ ald,
    const unsigned short* __restrict__ mhv, const unsigned short* __restrict__ mht,
    const float* __restrict__ mw, const float* __restrict__ mb,
    float* __restrict__ out1) {
  __shared__ unsigned short sAB[64 * 128 + 128 * 128];  // As(16KB) | Bs(32KB)
  unsigned short* As = sAB;
  unsigned short* Bs = sAB + 64 * 128;

  int t = threadIdx.x;
  int w = t >> 6, l = t & 63;
  int wr = w >> 1, wc = w & 1;
  int lr = l & 15, lhi = l >> 4;

  const unsigned short* agp[4];
  unsigned short* alp[4];
  #pragma unroll
  for (int i = 0; i < 4; ++i) {
    int slot = (w * 4 + i) * 64 + l;
    int row = slot >> 4, cbp = slot & 15;
    int cb = cbp ^ (row & 15);
    int gm = m0 + row; if (gm > M - 1) gm = M - 1;
    agp[i] = Ab + (size_t)gm * lda + c0 + cb * 8;
    alp[i] = As + (w * 4 + i) * 512;
  }
  const unsigned short* bgp[8];
  unsigned short* blp[8];
  #pragma unroll
  for (int i = 0; i < 8; ++i) {
    int slot = (w * 8 + i) * 64 + l;
    int row = slot >> 4, cbp = slot & 15;
    int cb = cbp ^ (row & 15);
    bgp[i] = Bt + (size_t)(n0 + row) * K + cb * 8;
    blp[i] = Bs + (w * 8 + i) * 512;
  }

  f32x4 acc[2][4];
  #pragma unroll
  for (int i = 0; i < 2; ++i)
    #pragma unroll
    for (int j = 0; j < 4; ++j) acc[i][j] = (f32x4){0.f, 0.f, 0.f, 0.f};

  for (int k0 = 0; k0 < K; k0 += 128) {
    #pragma unroll
    for (int i = 0; i < 4; ++i) gload16(agp[i] + k0, alp[i]);
    #pragma unroll
    for (int i = 0; i < 8; ++i) gload16(bgp[i] + k0, blp[i]);
    __syncthreads();
    #pragma unroll
    for (int kk = 0; kk < 4; ++kk) {
      short8 af[2], bfr[4];
      int cbf = lhi + kk * 4;
      #pragma unroll
      for (int i = 0; i < 2; ++i) {
        int row = wr * 32 + i * 16 + lr;
        af[i] = *(const short8*)&As[row * 128 + ((cbf ^ (row & 15)) << 3)];
      }
      #pragma unroll
      for (int j = 0; j < 4; ++j) {
        int nn = wc * 64 + j * 16 + lr;
        bfr[j] = *(const short8*)&Bs[nn * 128 + ((cbf ^ (nn & 15)) << 3)];
      }
      #pragma unroll
      for (int i = 0; i < 2; ++i)
        #pragma unroll
        for (int j = 0; j < 4; ++j)
          acc[i][j] = __builtin_amdgcn_mfma_f32_16x16x32_bf16(af[i], bfr[j], acc[i][j], 0, 0, 0);
    }
    __syncthreads();
  }

  if (MODE == 0) {
    float* Ctf = (float*)sAB;   // [64][128] f32
    #pragma unroll
    for (int i = 0; i < 2; ++i)
      #pragma unroll
      for (int j = 0; j < 4; ++j) {
        int col = wc * 64 + j * 16 + lr;
        float bsv = bias[col];
        #pragma unroll
        for (int rr = 0; rr < 4; ++rr) {
          int row = wr * 32 + i * 16 + lhi * 4 + rr;
          Ctf[row * 128 + col] = fmaxf(acc[i][j][rr] + bsv, 0.f);
        }
      }
    __syncthreads();
    float mb0 = mw ? mb[0] : 0.f;
    #pragma unroll
    for (int p = 0; p < 8; ++p) {
      int ci = (p << 8) + t;
      int row = ci >> 5, ch = ci & 31;
      int gr = m0 + row;
      int cg = gr < M ? gr : M - 1;
      float4 v = *(const float4*)&Ctf[row * 128 + (ch << 2)];
      if (gr < M) ((float4*)(Cf + (size_t)gr * ldc))[ch] = v;
      if (mw) {
        uint2 a2 = *(const uint2*)&mhv[(size_t)cg * 128 + (ch << 2)];
        uint2 b2 = *(const uint2*)&mht[(size_t)cg * 128 + (ch << 2)];
        float4 wv = ((const float4*)mw)[ch];
        float4 wt = ((const float4*)(mw + 128))[ch];
        float a0 = b2f((unsigned short)(a2.x & 0xffff)), a1 = b2f((unsigned short)(a2.x >> 16));
        float a2f = b2f((unsigned short)(a2.y & 0xffff)), a3 = b2f((unsigned short)(a2.y >> 16));
        float b0 = b2f((unsigned short)(b2.x & 0xffff)), b1 = b2f((unsigned short)(b2.x >> 16));
        float b2v = b2f((unsigned short)(b2.y & 0xffff)), b3 = b2f((unsigned short)(b2.y >> 16));
        float ps = a0 * wv.x + a1 * wv.y + a2f * wv.z + a3 * wv.w
                 + b0 * wt.x + b1 * wt.y + b2v * wt.z + b3 * wt.w;
        #pragma unroll
        for (int off = 1; off < 32; off <<= 1) ps += __shfl_xor(ps, off);
        float beta = 1.f / (1.f + __expf(-(ps + mb0)));
        float4 o;
        o.x = beta * a0 + (1.f - beta) * b0;
        o.y = beta * a1 + (1.f - beta) * b1;
        o.z = beta * a2f + (1.f - beta) * b2v;
        o.w = beta * a3 + (1.f - beta) * b3;
        if (gr < M) ((float4*)(out1 + (size_t)gr * 128))[ch] = o;
      }
    }
  } else {
    unsigned short* Ct = sAB;   // [64][128] bf16 (16 KB)
    float* pvL = (float*)(sAB + 8192);  // 4 KB, dead Bs region
    #pragma unroll
    for (int i = 0; i < 2; ++i)
      #pragma unroll
      for (int j = 0; j < 4; ++j) {
        int col = wc * 64 + j * 16 + lr;
        float bsv = bias[col];
        #pragma unroll
        for (int rr = 0; rr < 4; ++rr) {
          int row = wr * 32 + i * 16 + lhi * 4 + rr;
          float v;
          if (MODE == 3) {
            v = fmaxf(acc[i][j][rr] + bsv, 0.f);
          } else {
            v = 0.25f * acc[i][j][rr] + bsv;
            v = v > 0.f ? v : __expf(v) - 1.f;
          }
          Ct[row * 128 + col] = f2b(v);
        }
      }
    __syncthreads();
    if (pvg) ((float4*)pvL)[t] = ((const float4*)pvg)[t];   // 1024 floats
    __syncthreads();
    #pragma unroll
    for (int p = 0; p < 4; ++p) {
      int ci = (p << 8) + t;
      int row = ci >> 4, ch = ci & 15;
      int gr = m0 + row;
      int cg = gr < M ? gr : M - 1;
      uint4 cv = *(const uint4*)&Ct[row * 128 + (ch << 3)];
      uint4* gptr = (uint4*)(Cb + (size_t)cg * ldc) + ch;
      if (MODE == 2) {
        uint4 hv = *gptr;
        cv.x = addbf2(cv.x, hv.x); cv.y = addbf2(cv.y, hv.y);
        cv.z = addbf2(cv.z, hv.z); cv.w = addbf2(cv.w, hv.w);
      }
      if (gr < M) *gptr = cv;
      if (pvg) {
        float v0 = b2f((unsigned short)(cv.x & 0xffff)), v1 = b2f((unsigned short)(cv.x >> 16));
        float v2 = b2f((unsigned short)(cv.y & 0xffff)), v3 = b2f((unsigned short)(cv.y >> 16));
        float v4 = b2f((unsigned short)(cv.z & 0xffff)), v5 = b2f((unsigned short)(cv.z >> 16));
        float v6 = b2f((unsigned short)(cv.w & 0xffff)), v7 = b2f((unsigned short)(cv.w >> 16));
        float s0, s1, s2, s3, s4, s5, s6, s7;
        {
          const float4* pr;
          pr = (const float4*)&pvL[0 * 128 + (ch << 3)];
          s0 = v0*pr[0].x + v1*pr[0].y + v2*pr[0].z + v3*pr[0].w + v4*pr[1].x + v5*pr[1].y + v6*pr[1].z + v7*pr[1].w;
          pr = (const float4*)&pvL[1 * 128 + (ch << 3)];
          s1 = v0*pr[0].x + v1*pr[0].y + v2*pr[0].z + v3*pr[0].w + v4*pr[1].x + v5*pr[1].y + v6*pr[1].z + v7*pr[1].w;
          pr = (const float4*)&pvL[2 * 128 + (ch << 3)];
          s2 = v0*pr[0].x + v1*pr[0].y + v2*pr[0].z + v3*pr[0].w + v4*pr[1].x + v5*pr[1].y + v6*pr[1].z + v7*pr[1].w;
          pr = (const float4*)&pvL[3 * 128 + (ch << 3)];
          s3 = v0*pr[0].x + v1*pr[0].y + v2*pr[0].z + v3*pr[0].w + v4*pr[1].x + v5*pr[1].y + v6*pr[1].z + v7*pr[1].w;
          pr = (const float4*)&pvL[4 * 128 + (ch << 3)];
          s4 = v0*pr[0].x + v1*pr[0].y + v2*pr[0].z + v3*pr[0].w + v4*pr[1].x + v5*pr[1].y + v6*pr[1].z + v7*pr[1].w;
          pr = (const float4*)&pvL[5 * 128 + (ch << 3)];
          s5 = v0*pr[0].x + v1*pr[0].y + v2*pr[0].z + v3*pr[0].w + v4*pr[1].x + v5*pr[1].y + v6*pr[1].z + v7*pr[1].w;
          pr = (const float4*)&pvL[6 * 128 + (ch << 3)];
          s6 = v0*pr[0].x + v1*pr[0].y + v2*pr[0].z + v3*pr[0].w + v4*pr[1].x + v5*pr[1].y + v6*pr[1].z + v7*pr[1].w;
          pr = (const float4*)&pvL[7 * 128 + (ch << 3)];
          s7 = v0*pr[0].x + v1*pr[0].y + v2*pr[0].z + v3*pr[0].w + v4*pr[1].x + v5*pr[1].y + v6*pr[1].z + v7*pr[1].w;
        }
        #pragma unroll
        for (int off = 1; off < 16; off <<= 1) {
          s0 += __shfl_xor(s0, off); s1 += __shfl_xor(s1, off);
          s2 += __shfl_xor(s2, off); s3 += __shfl_xor(s3, off);
          s4 += __shfl_xor(s4, off); s5 += __shfl_xor(s5, off);
          s6 += __shfl_xor(s6, off); s7 += __shfl_xor(s7, off);
        }
        if ((t & 15) == 0 && gr < M) {
          als[gr * 4 + 0] = s0; als[gr * 4 + 1] = s1;
          als[gr * 4 + 2] = s2; als[gr * 4 + 3] = s3;
          ald[gr * 4 + 0] = s4; ald[gr * 4 + 1] = s5;
          ald[gr * 4 + 2] = s6; ald[gr * 4 + 3] = s7;
        }
      }
    }
  }
}

// projections + fused L0 logits: y = modality; A = xb (bf16)
__global__ __launch_bounds__(256) void k_proj(
    const unsigned short* __restrict__ xb,
    const unsigned short* __restrict__ btv, const unsigned short* __restrict__ btt,
    const float* __restrict__ vb, const float* __restrict__ tb,
    unsigned short* __restrict__ hbv, unsigned short* __restrict__ hbt,
    const float* __restrict__ pvec,
    float* __restrict__ alsv, float* __restrict__ aldv,
    float* __restrict__ alst, float* __restrict__ aldt) {
  int m0 = blockIdx.x * 64;
  int mod = blockIdx.y;
  int c0, K;
  const unsigned short* Bt;
  const float* bias;
  unsigned short* Cb;
  if (mod == 0) { c0 = 0;   K = 768; Bt = btv; bias = vb; Cb = hbv; }
  else          { c0 = 768; K = 384; Bt = btt; bias = tb; Cb = hbt; }
  gemm_core<3>(xb, 1152, c0, Bt, bias, nullptr, Cb, 128, N_NODES, K, m0, 0,
               pvec + (size_t)mod * 1024,
               mod ? alst : alsv, mod ? aldt : aldv,
               nullptr, nullptr, nullptr, nullptr, nullptr);
}

// ---------------- GAT aggregation: ONE WAVE per node ----------------
struct AggArgs {
  const unsigned short* hb[2];
  const float* als[2];
  const float* ald[2];
  unsigned short* agg[2];
};
__global__ __launch_bounds__(64) void k_agg(AggArgs ag,
                                            const int* __restrict__ row_ptr,
                                            const int* __restrict__ edge_src) {
  int b = blockIdx.x;
  int mod = b >= N_NODES;
  int node = b - mod * N_NODES;
  const unsigned short* __restrict__ hbm = ag.hb[mod];
  const float* __restrict__ als = ag.als[mod];
  const float* __restrict__ ald = ag.ald[mod];
  unsigned* __restrict__ arow_ = (unsigned*)(ag.agg[mod] + (size_t)node * 512);

  int lane = threadIdx.x;   // 0..63
  __shared__ float sp[128][4];
  __shared__ int   ssrc[128];
  int begin = row_ptr[node], end = row_ptr[node + 1];
  int deg = end - begin;
  float4 ad4 = *(const float4*)(ald + (size_t)node * 4);

  if (deg <= 128) {
    float eA0 = -1e30f, eA1 = -1e30f, eA2 = -1e30f, eA3 = -1e30f;
    float eB0 = -1e30f, eB1 = -1e30f, eB2 = -1e30f, eB3 = -1e30f;
    if (lane < deg) {
      int s = edge_src[begin + lane];
      ssrc[lane] = s;
      float4 a4 = *(const float4*)(als + (size_t)s * 4);
      eA0 = lrelu(a4.x + ad4.x); eA1 = lrelu(a4.y + ad4.y);
      eA2 = lrelu(a4.z + ad4.z); eA3 = lrelu(a4.w + ad4.w);
    }
    if (lane + 64 < deg) {
      int s = edge_src[begin + lane + 64];
      ssrc[lane + 64] = s;
      float4 a4 = *(const float4*)(als + (size_t)s * 4);
      eB0 = lrelu(a4.x + ad4.x); eB1 = lrelu(a4.y + ad4.y);
      eB2 = lrelu(a4.z + ad4.z); eB3 = lrelu(a4.w + ad4.w);
    }
    float m0 = fmaxf(eA0, eB0), m1 = fmaxf(eA1, eB1);
    float m2 = fmaxf(eA2, eB2), m3 = fmaxf(eA3, eB3);
    #pragma unroll
    for (int off = 32; off > 0; off >>= 1) {
      m0 = fmaxf(m0, __shfl_xor(m0, off));
      m1 = fmaxf(m1, __shfl_xor(m1, off));
      m2 = fmaxf(m2, __shfl_xor(m2, off));
      m3 = fmaxf(m3, __shfl_xor(m3, off));
    }
    float pA0 = 0.f, pA1 = 0.f, pA2 = 0.f, pA3 = 0.f;
    float pB0 = 0.f, pB1 = 0.f, pB2 = 0.f, pB3 = 0.f;
    if (lane < deg) {
      pA0 = __expf(eA0 - m0); pA1 = __expf(eA1 - m1);
      pA2 = __expf(eA2 - m2); pA3 = __expf(eA3 - m3);
      *(float4*)&sp[lane][0] = make_float4(pA0, pA1, pA2, pA3);
    }
    if (lane + 64 < deg) {
      pB0 = __expf(eB0 - m0); pB1 = __expf(eB1 - m1);
      pB2 = __expf(eB2 - m2); pB3 = __expf(eB3 - m3);
      *(float4*)&sp[lane + 64][0] = make_float4(pB0, pB1, pB2, pB3);
    }
    float s0 = pA0 + pB0, s1 = pA1 + pB1, s2 = pA2 + pB2, s3 = pA3 + pB3;
    #pragma unroll
    for (int off = 32; off > 0; off >>= 1) {
      s0 += __shfl_xor(s0, off); s1 += __shfl_xor(s1, off);
      s2 += __shfl_xor(s2, off); s3 += __shfl_xor(s3, off);
    }
    float inv0 = 1.f / (s0 + 1e-16f);
    float inv1 = 1.f / (s1 + 1e-16f);
    float inv2 = 1.f / (s2 + 1e-16f);
    float inv3 = 1.f / (s3 + 1e-16f);
    __syncthreads();

    int c2 = lane << 1;
    const unsigned short* hb0 = hbm + c2;
    float a00 = 0.f, a01 = 0.f, a10 = 0.f, a11 = 0.f;
    float a20 = 0.f, a21 = 0.f, a30 = 0.f, a31 = 0.f;
    for (int k = 0; k < deg; ++k) {
      int s = ssrc[k];
      float4 pk = *(const float4*)&sp[k][0];
      unsigned xv = *(const unsigned*)(hb0 + (size_t)s * 128);
      float x0 = b2f((unsigned short)(xv & 0xffff));
      float x1 = b2f((unsigned short)(xv >> 16));
      a00 += pk.x * x0; a01 += pk.x * x1;
      a10 += pk.y * x0; a11 += pk.y * x1;
      a20 += pk.z * x0; a21 += pk.z * x1;
      a30 += pk.w * x0; a31 += pk.w * x1;
    }
    arow_[0 * 64 + lane] = pk2(a00 * inv0, a01 * inv0);
    arow_[1 * 64 + lane] = pk2(a10 * inv1, a11 * inv1);
    arow_[2 * 64 + lane] = pk2(a20 * inv2, a21 * inv2);
    arow_[3 * 64 + lane] = pk2(a30 * inv3, a31 * inv3);
    return;
  }

  // ---- generic fallback (deg > 128; statistically never) ----
  float lm0 = -1e30f, lm1 = -1e30f, lm2 = -1e30f, lm3 = -1e30f;
  for (int idx = begin + lane; idx < end; idx += 64) {
    int s = edge_src[idx];
    float4 a4 = *(const float4*)(als + (size_t)s * 4);
    lm0 = fmaxf(lm0, lrelu(a4.x + ad4.x));
    lm1 = fmaxf(lm1, lrelu(a4.y + ad4.y));
    lm2 = fmaxf(lm2, lrelu(a4.z + ad4.z));
    lm3 = fmaxf(lm3, lrelu(a4.w + ad4.w));
  }
  #pragma unroll
  for (int off = 32; off > 0; off >>= 1) {
    lm0 = fmaxf(lm0, __shfl_xor(lm0, off));
    lm1 = fmaxf(lm1, __shfl_xor(lm1, off));
    lm2 = fmaxf(lm2, __shfl_xor(lm2, off));
    lm3 = fmaxf(lm3, __shfl_xor(lm3, off));
  }
  float ls0 = 0.f, ls1 = 0.f, ls2 = 0.f, ls3 = 0.f;
  for (int idx = begin + lane; idx < end; idx += 64) {
    int s = edge_src[idx];
    float4 a4 = *(const float4*)(als + (size_t)s * 4);
    ls0 += __expf(lrelu(a4.x + ad4.x) - lm0);
    ls1 += __expf(lrelu(a4.y + ad4.y) - lm1);
    ls2 += __expf(lrelu(a4.z + ad4.z) - lm2);
    ls3 += __expf(lrelu(a4.w + ad4.w) - lm3);
  }
  #pragma unroll
  for (int off = 32; off > 0; off >>= 1) {
    ls0 += __shfl_xor(ls0, off); ls1 += __shfl_xor(ls1, off);
    ls2 += __shfl_xor(ls2, off); ls3 += __shfl_xor(ls3, off);
  }
  float inv0 = 1.f / (ls0 + 1e-16f);
  float inv1 = 1.f / (ls1 + 1e-16f);
  float inv2 = 1.f / (ls2 + 1e-16f);
  float inv3 = 1.f / (ls3 + 1e-16f);
  int c2 = lane << 1;
  const unsigned short* hb0 = hbm + c2;
  float a00 = 0.f, a01 = 0.f, a10 = 0.f, a11 = 0.f;
  float a20 = 0.f, a21 = 0.f, a30 = 0.f, a31 = 0.f;
  for (int idx = begin; idx < end; ++idx) {
    int s = edge_src[idx];
    float4 a4 = *(const float4*)(als + (size_t)s * 4);
    float al0 = __expf(lrelu(a4.x + ad4.x) - lm0);
    float al1 = __expf(lrelu(a4.y + ad4.y) - lm1);
    float al2 = __expf(lrelu(a4.z + ad4.z) - lm2);
    float al3 = __expf(lrelu(a4.w + ad4.w) - lm3);
    unsigned xv = *(const unsigned*)(hb0 + (size_t)s * 128);
    float x0 = b2f((unsigned short)(xv & 0xffff));
    float x1 = b2f((unsigned short)(xv >> 16));
    a00 += al0 * x0; a01 += al0 * x1;
    a10 += al1 * x0; a11 += al1 * x1;
    a20 += al2 * x0; a21 += al2 * x1;
    a30 += al3 * x0; a31 += al3 * x1;
  }
  arow_[0 * 64 + lane] = pk2(a00 * inv0, a01 * inv0);
  arow_[1 * 64 + lane] = pk2(a10 * inv1, a11 * inv1);
  arow_[2 * 64 + lane] = pk2(a20 * inv2, a21 * inv2);
  arow_[3 * 64 + lane] = pk2(a30 * inv3, a31 * inv3);
}

// out-transform + residual + optional fused next-layer logits
struct OutArgs {
  const unsigned short* agg[2];
  const unsigned short* btg[2];
  const float* bias[2];
  unsigned short* hb[2];
  const float* pv[2];
  float* als[2];
  float* ald[2];
};
__global__ __launch_bounds__(256) void k_out(OutArgs oa) {
  int m0 = blockIdx.x * 64;
  int mod = blockIdx.y;
  gemm_core<2>(oa.agg[mod], 512, 0, oa.btg[mod], oa.bias[mod],
               nullptr, oa.hb[mod], 128, N_NODES, 512, m0, 0,
               oa.pv[mod], oa.als[mod], oa.ald[mod],
               nullptr, nullptr, nullptr, nullptr, nullptr);
}

// head GEMMs + fused modal (y=0 computes final_emb too)
__global__ __launch_bounds__(256) void k_head(
    const unsigned short* __restrict__ hbv, const unsigned short* __restrict__ hbt,
    const unsigned short* __restrict__ btvh, const unsigned short* __restrict__ btth,
    const float* __restrict__ vhb, const float* __restrict__ thb,
    const float* __restrict__ mw, const float* __restrict__ mb,
    float* __restrict__ out) {
  int m0 = blockIdx.x * 64;
  if (blockIdx.y == 0) {
    gemm_core<0>(hbv, 128, 0, btvh, vhb, out + 2560000, nullptr, 128,
                 N_NODES, 128, m0, 0,
                 nullptr, nullptr, nullptr, hbv, hbt, mw, mb, out);
  } else {
    gemm_core<0>(hbt, 128, 0, btth, thb, out + 5120000, nullptr, 128,
                 N_NODES, 128, m0, 0,
                 nullptr, nullptr, nullptr, nullptr, nullptr, nullptr, nullptr, nullptr);
  }
}

extern "C" void kernel_launch(void* const* d_in, const int* in_sizes, int n_in,
                              void* d_out, int out_size, void* d_ws, size_t ws_size,
                              hipStream_t stream) {
  const float* x    = (const float*)d_in[0];
  const int*   ei   = (const int*)d_in[1];
  const float* vpw  = (const float*)d_in[2];
  const float* vpb  = (const float*)d_in[3];
  const float* tpw  = (const float*)d_in[4];
  const float* tpb  = (const float*)d_in[5];
  const float* vgw  = (const float*)d_in[6];
  const float* vgas = (const float*)d_in[7];
  const float* vgad = (const float*)d_in[8];
  const float* vgb  = (const float*)d_in[9];
  const float* tgw  = (const float*)d_in[10];
  const float* tgas = (const float*)d_in[11];
  const float* tgad = (const float*)d_in[12];
  const float* tgb  = (const float*)d_in[13];
  const float* mw   = (const float*)d_in[14];
  const float* mb   = (const float*)d_in[15];
  const float* vhw  = (const float*)d_in[16];
  const float* vhb  = (const float*)d_in[17];
  const float* thw  = (const float*)d_in[18];
  const float* thb  = (const float*)d_in[19];
  float* out = (float*)d_out;

  char* ws = (char*)d_ws;
  float*          als_v    = (float*)(ws);                         //    320,000
  float*          ald_v    = (float*)(ws + 320000);                //    320,000
  float*          als_t    = (float*)(ws + 640000);                //    320,000
  float*          ald_t    = (float*)(ws + 960000);                //    320,000
  int*            row_ptr  = (int*)  (ws + 1280000);               //     80,016
  int*            deg      = (int*)  (ws + 1360016);               //     80,000
  int*            edge_src = (int*)  (ws + 1440016);               //  1,360,000
  unsigned short* bt       = (unsigned short*)(ws + 2800016);      //    884,736
  float*          pvec     = (float*)(ws + 3684752);               //     16,384
  unsigned short* hb_v     = (unsigned short*)(ws + 3701136);      //  5,120,000
  unsigned short* hb_t     = (unsigned short*)(ws + 8821136);      //  5,120,000
  // xb (46,080,000) time-shares with agg_v+agg_t (2 x 20,480,000)
  unsigned short* xb       = (unsigned short*)(ws + 13941136);
  unsigned short* agg_v    = (unsigned short*)(ws + 13941136);
  unsigned short* agg_t    = (unsigned short*)(ws + 34421136);

  unsigned short* bt_vp = bt;            // [128][768]
  unsigned short* bt_tp = bt + 98304;    // [128][384]
  unsigned short* bt_vh = bt + 147456;   // [128][128]
  unsigned short* bt_th = bt + 163840;   // [128][128]
  unsigned short* bt_og = bt + 180224;   // 4 x [128][512] (mod*2+L)

  PrepArgs pa;
  pa.vpw = vpw; pa.tpw = tpw; pa.vhw = vhw; pa.thw = thw;
  pa.vgw = vgw; pa.tgw = tgw;
  pa.vgas = vgas; pa.vgad = vgad; pa.tgas = tgas; pa.tgad = tgad;
  pa.bt_vp = bt_vp; pa.bt_tp = bt_tp; pa.bt_vh = bt_vh; pa.bt_th = bt_th;
  pa.bt_og = bt_og; pa.pvec = pvec;
  pa.deg = deg;
  pa.x = x; pa.xb = xb;
  k_prep<<<3871, 256, 0, stream>>>(pa);

  k_hist<<<(N_EDGES + 255) / 256, 256, 0, stream>>>(ei, deg);
  k_scan<<<1, 1024, 0, stream>>>(deg, row_ptr);
  k_scatter<<<(E_TOT + 255) / 256, 256, 0, stream>>>(ei, row_ptr, deg, edge_src);

  // projections + L0 logits (A = xb bf16, via global_load_lds)
  k_proj<<<dim3(MT64, 2), 256, 0, stream>>>(xb, bt_vp, bt_tp, vpb, tpb, hb_v, hb_t,
                                            pvec, als_v, ald_v, als_t, ald_t);

  // GAT layers
  for (int L = 0; L < 2; ++L) {
    AggArgs ag;
    ag.hb[0] = hb_v;   ag.hb[1] = hb_t;
    ag.als[0] = als_v; ag.als[1] = als_t;
    ag.ald[0] = ald_v; ag.ald[1] = ald_t;
    ag.agg[0] = agg_v; ag.agg[1] = agg_t;
    k_agg<<<2 * N_NODES, 64, 0, stream>>>(ag, row_ptr, edge_src);

    OutArgs oa;
    oa.agg[0] = agg_v; oa.agg[1] = agg_t;
    oa.btg[0] = bt_og + (size_t)(0 * 2 + L) * 65536;
    oa.btg[1] = bt_og + (size_t)(1 * 2 + L) * 65536;
    oa.bias[0] = vgb + L * HID;
    oa.bias[1] = tgb + L * HID;
    oa.hb[0] = hb_v;  oa.hb[1] = hb_t;
    if (L == 0) {
      oa.pv[0] = pvec + 2 * 1024;
      oa.pv[1] = pvec + 3 * 1024;
    } else {
      oa.pv[0] = nullptr; oa.pv[1] = nullptr;
    }
    oa.als[0] = als_v; oa.als[1] = als_t;
    oa.ald[0] = ald_v; oa.ald[1] = ald_t;
    k_out<<<dim3(MT64, 2), 256, 0, stream>>>(oa);
  }

  // head GEMMs + fused modal
  k_head<<<dim3(MT64, 2), 256, 0, stream>>>(hb_v, hb_t, bt_vh, bt_th, vhb, thb,
                                            mw, mb, out);
}